// Round 1
// baseline (15724.922 us; speedup 1.0000x reference)
//
#include <hip/hip_runtime.h>

#define NB 8
#define NN 1024
#define NC 32
#define NT 20
#define NTI 10
#define NM 32     // iteration block size (16 wanted + 16 guard)
#define NK 16     // K_SPACE
#define NMT 4     // M_TIME
#define WE 64     // ELL width
#define NQ 128
#define GC 4      // columns per workgroup in Chebyshev filter
#define LST 5     // LDS row stride (pad 4->5 to spread banks)

__device__ __forceinline__ float gelu_f(float x){
  return 0.5f * x * (1.0f + erff(x * 0.70710678118654752f));
}
__device__ __forceinline__ unsigned wanghash(unsigned s){
  s = (s ^ 61u) ^ (s >> 16); s *= 9u; s ^= s >> 4; s *= 0x27d4eb2du; s ^= s >> 15;
  return s;
}

// ---------------- initial lift: h[b][n][t][c] = concat(x,pos,t) @ Wp + bp ----
__global__ void k_build_h0(const float* __restrict__ x, const float* __restrict__ pos,
                           const float* __restrict__ Wp, const float* __restrict__ bp,
                           float* __restrict__ h){
  int idx = blockIdx.x*256 + threadIdx.x;
  if (idx >= NB*NN*NT*NC) return;
  int c = idx & (NC-1);
  int t = (idx/NC) % NT;
  int n = (idx/(NC*NT)) & (NN-1);
  int b = idx/(NC*NT*NN);
  const float* xr = x + (b*NN + n)*NTI;
  float acc = bp[c];
  #pragma unroll
  for (int i=0;i<NTI;i++) acc += xr[i]*Wp[i*NC+c];
  acc += pos[(b*NN+n)*2+0]*Wp[10*NC+c];
  acc += pos[(b*NN+n)*2+1]*Wp[11*NC+c];
  float tv = (float)(10+t) * (1.0f/29.0f);
  acc += tv*Wp[12*NC+c];
  h[idx] = acc;
}

// ---------------- fused pairwise distance + top-8 kNN + sigma sum ------------
// one wave per row; feat = h[b][n][0][:]
__global__ __launch_bounds__(256) void k_dist_knn(const float* __restrict__ h,
                           float* __restrict__ knnd, int* __restrict__ knni,
                           double* __restrict__ sig, int* __restrict__ cnt){
  __shared__ float fr_s[4][NC];
  int wave = threadIdx.x >> 6;
  int lane = threadIdx.x & 63;
  int row = blockIdx.x*4 + wave;       // global row over NB*NN
  int b = row >> 10;
  if (threadIdx.x < 4*NC){
    int w = threadIdx.x >> 5, c = threadIdx.x & 31;
    int rr = blockIdx.x*4 + w;
    fr_s[w][c] = h[((size_t)rr*NT)*NC + c];
  }
  __syncthreads();
  float fr[NC];
  #pragma unroll
  for (int c=0;c<NC;c++) fr[c] = fr_s[wave][c];
  float d8[8]; int i8[8];
  #pragma unroll
  for (int j=0;j<8;j++){ d8[j]=1e30f; i8[j]=0x3fffffff; }
  double ssum = 0.0;
  const float* fb = h + (size_t)b*NN*NT*NC;
  for (int m=lane; m<NN; m+=64){
    const float* fm = fb + (size_t)m*NT*NC;
    float d2 = 0.f;
    #pragma unroll
    for (int c=0;c<NC;c++){ float df = fr[c]-fm[c]; d2 += df*df; }
    float d = sqrtf(d2);
    ssum += (double)d;
    if (d < d8[7] || (d == d8[7] && m < i8[7])){
      d8[7] = d; i8[7] = m;
      #pragma unroll
      for (int j=6;j>=0;j--){
        bool sw = (d8[j+1] < d8[j]) || (d8[j+1]==d8[j] && i8[j+1]<i8[j]);
        if (sw){ float td=d8[j]; d8[j]=d8[j+1]; d8[j+1]=td;
                 int ti=i8[j]; i8[j]=i8[j+1]; i8[j+1]=ti; }
      }
    }
  }
  #pragma unroll
  for (int off=32; off>0; off>>=1) ssum += __shfl_down(ssum, off);
  if (lane==0){ atomicAdd(&sig[b], ssum); cnt[row] = 8; }
  // merge per-lane sorted top-8 lists: 8x wave-argmin extraction
  int ptr = 0;
  for (int sel=0; sel<8; sel++){
    float dv = 1e30f; int iv = 0x3fffffff;
    #pragma unroll
    for (int j=0;j<8;j++) if (j==ptr){ dv=d8[j]; iv=i8[j]; }
    float bd = dv; int bi = iv;
    #pragma unroll
    for (int off=32; off>0; off>>=1){
      float od = __shfl_xor(bd, off);
      int oi = __shfl_xor(bi, off);
      if (od < bd || (od == bd && oi < bi)){ bd = od; bi = oi; }
    }
    if (dv == bd && iv == bi) ptr++;
    if (lane == sel){ knnd[row*8+sel] = bd; knni[row*8+sel] = bi; }
  }
}

// ---------------- symmetrized sparse A in ELL form ---------------------------
__global__ void k_build_ell(const float* __restrict__ knnd, const int* __restrict__ knni,
                            const double* __restrict__ sig, int* __restrict__ cnt,
                            int* __restrict__ ecol, float* __restrict__ evalv){
  int row = blockIdx.x*256 + threadIdx.x;
  if (row >= NB*NN) return;
  int b = row >> 10;
  float sigma = (float)(sig[b] * (1.0/((double)NN*(double)NN)));
  float s2 = sigma*sigma;
  int rloc = row & (NN-1);
  #pragma unroll
  for (int j=0;j<8;j++){
    float d = knnd[row*8+j];
    int m = knni[row*8+j];
    float v = 0.5f * expf(-d/s2);
    ecol[(size_t)row*WE + j] = m;
    evalv[(size_t)row*WE + j] = v;
    int grow = (b<<10) + m;
    int p = atomicAdd(&cnt[grow], 1);
    if (p < WE){ ecol[(size_t)grow*WE + p] = rloc; evalv[(size_t)grow*WE + p] = v; }
  }
}

__global__ void k_degnorm(const int* __restrict__ cnt, const float* __restrict__ evalv,
                          float* __restrict__ deg, float* __restrict__ dinv){
  int row = blockIdx.x*256 + threadIdx.x;
  if (row >= NB*NN) return;
  int c = cnt[row]; if (c > WE) c = WE;
  float s = 0.f;
  for (int j=0;j<c;j++) s += evalv[(size_t)row*WE + j];
  deg[row] = s;
  dinv[row] = 1.0f/sqrtf(s + 1e-6f);
}

__global__ void k_normell(const int* __restrict__ cnt, const int* __restrict__ ecol,
                          float* __restrict__ evalv, const float* __restrict__ deg,
                          const float* __restrict__ dinv, float* __restrict__ dval){
  int row = blockIdx.x*256 + threadIdx.x;
  if (row >= NB*NN) return;
  int b = row >> 10;
  const float* dv = dinv + (b<<10);
  float di = dinv[row];
  int c = cnt[row]; if (c > WE) c = WE;
  for (int j=0;j<c;j++){
    int col = ecol[(size_t)row*WE + j];
    evalv[(size_t)row*WE + j] = evalv[(size_t)row*WE + j] * (di * dv[col]);  // symmetric product order
  }
  dval[row] = di*di*deg[row];
}

// ---------------- eigensolver: init block -----------------------------------
__global__ void k_initX(const float* __restrict__ deg, float* __restrict__ X, float* __restrict__ aint){
  int idx = blockIdx.x*256+threadIdx.x;
  if (idx >= NB*NM*NN) return;
  int n = idx & (NN-1);
  int j = (idx >> 10) & (NM-1);
  int b = idx >> 15;
  float v;
  if (j == 0) v = sqrtf(deg[(b<<10)+n] + 1e-6f);   // exact 0-eigenvector of Lhat
  else {
    unsigned hsh = wanghash((unsigned)idx * 2654435761u + 12345u);
    v = ((hsh >> 8) * (1.0f/16777216.0f)) - 0.5f;
  }
  X[idx] = v;
  if (n == 0 && j == 1) aint[b] = 1.0f;
}

// ---------------- Chebyshev filter on Lhat, block columns in LDS -------------
__global__ __launch_bounds__(256) void k_cheb(const int* __restrict__ cnt, const int* __restrict__ ecol,
                        const float* __restrict__ evalv, const float* __restrict__ dval,
                        float* __restrict__ X, const float* __restrict__ aint, int ndeg){
  __shared__ float bufA[NN*LST];
  __shared__ float bufB[NN*LST];
  int b = blockIdx.x >> 3;
  int g0 = (blockIdx.x & 7) * GC;
  float a = aint[b];
  const float bhi = 2.0005f;
  float e  = 0.5f*(bhi - a);
  float cc = 0.5f*(bhi + a);
  float inv_e = 1.0f/e;
  const int rowbase = b << 10;
  float* Xb = X + ((size_t)b*NM + g0)*NN;
  for (int g=0; g<GC; g++)
    for (int n=threadIdx.x; n<NN; n+=256)
      bufA[n*LST+g] = Xb[(size_t)g*NN + n];
  __syncthreads();
  float* cur = bufA; float* prv = bufB;
  for (int k=0;k<ndeg;k++){
    float f = (k==0)? inv_e : 2.0f*inv_e;
    #pragma unroll
    for (int rr=0; rr<NN/256; rr++){
      int r = threadIdx.x + rr*256;
      int cN = cnt[rowbase+r]; if (cN > WE) cN = WE;
      float dvv = dval[rowbase+r];
      float x0 = cur[r*LST+0], x1 = cur[r*LST+1], x2 = cur[r*LST+2], x3 = cur[r*LST+3];
      float acc0 = dvv*x0, acc1 = dvv*x1, acc2 = dvv*x2, acc3 = dvv*x3;
      const int*   ec = ecol  + (size_t)(rowbase+r)*WE;
      const float* ev = evalv + (size_t)(rowbase+r)*WE;
      for (int j=0;j<cN;j++){
        int col = ec[j]; float w = ev[j];
        acc0 -= w*cur[col*LST+0];
        acc1 -= w*cur[col*LST+1];
        acc2 -= w*cur[col*LST+2];
        acc3 -= w*cur[col*LST+3];
      }
      float n0 = f*(acc0 - cc*x0), n1 = f*(acc1 - cc*x1);
      float n2 = f*(acc2 - cc*x2), n3 = f*(acc3 - cc*x3);
      if (k > 0){ n0 -= prv[r*LST+0]; n1 -= prv[r*LST+1]; n2 -= prv[r*LST+2]; n3 -= prv[r*LST+3]; }
      prv[r*LST+0]=n0; prv[r*LST+1]=n1; prv[r*LST+2]=n2; prv[r*LST+3]=n3;
    }
    float* t_ = cur; cur = prv; prv = t_;
    __syncthreads();
  }
  for (int g=0; g<GC; g++)
    for (int n=threadIdx.x; n<NN; n+=256)
      Xb[(size_t)g*NN + n] = cur[n*LST+g];
}

// ---------------- Y = Lhat * X (one column per workgroup) --------------------
__global__ void k_spmv(const int* __restrict__ cnt, const int* __restrict__ ecol,
                       const float* __restrict__ evalv, const float* __restrict__ dval,
                       const float* __restrict__ X, float* __restrict__ Y){
  __shared__ float xc[NN];
  int b = blockIdx.x >> 5, j = blockIdx.x & 31;
  const float* Xc = X + ((size_t)b*NM + j)*NN;
  for (int n=threadIdx.x; n<NN; n+=256) xc[n] = Xc[n];
  __syncthreads();
  int rowbase = b << 10;
  for (int r=threadIdx.x; r<NN; r+=256){
    int c = cnt[rowbase+r]; if (c > WE) c = WE;
    float acc = dval[rowbase+r]*xc[r];
    const int*   ec = ecol  + (size_t)(rowbase+r)*WE;
    const float* ev = evalv + (size_t)(rowbase+r)*WE;
    for (int jj=0;jj<c;jj++) acc -= ev[jj]*xc[ec[jj]];
    Y[((size_t)b*NM + j)*NN + r] = acc;
  }
}

// ---------------- G = A^T B (f64 accumulate), one row of G per wg ------------
__global__ void k_gram(const float* __restrict__ A, const float* __restrict__ Bm,
                       double* __restrict__ G){
  __shared__ float ai[NN];
  __shared__ double pd[NM][8];
  int b = blockIdx.x >> 5, i = blockIdx.x & 31;
  const float* Ac = A + ((size_t)b*NM + i)*NN;
  for (int n=threadIdx.x; n<NN; n+=256) ai[n] = Ac[n];
  __syncthreads();
  int j = threadIdx.x & 31, seg = threadIdx.x >> 5;
  const float* Bc = Bm + ((size_t)b*NM + j)*NN + seg*128;
  const float* as = ai + seg*128;
  double s = 0.0;
  for (int n=0;n<128;n++) s += (double)as[n]*(double)Bc[n];
  pd[j][seg] = s;
  __syncthreads();
  if (threadIdx.x < NM){
    double t = 0.0;
    #pragma unroll
    for (int q=0;q<8;q++) t += pd[threadIdx.x][q];
    G[((size_t)b*NM + i)*NM + threadIdx.x] = t;
  }
}

// ---------------- chol(G) -> R^{-1} (f64), upper triangular ------------------
__global__ __launch_bounds__(64) void k_cholinv(const double* __restrict__ G, double* __restrict__ Rd){
  __shared__ double L[NM][NM];
  __shared__ double Ri[NM][NM];
  int b = blockIdx.x, l = threadIdx.x;
  for (int idx=l; idx<NM*NM; idx+=64) L[idx>>5][idx&31] = G[(size_t)b*NM*NM + idx];
  __syncthreads();
  for (int k=0;k<NM;k++){
    if (l == 0){
      double orig = L[k][k];
      double s = orig;
      for (int p=0;p<k;p++) s -= L[k][p]*L[k][p];
      double floorv = orig*1e-15; if (floorv < 1e-30) floorv = 1e-30;
      if (s < floorv) s = floorv;
      L[k][k] = sqrt(s);
    }
    __syncthreads();
    if (l > k && l < NM){
      double s = L[l][k];
      for (int p=0;p<k;p++) s -= L[l][p]*L[k][p];
      L[l][k] = s / L[k][k];
    }
    __syncthreads();
  }
  if (l < NM){
    int j = l;
    Ri[j][j] = 1.0 / L[j][j];
    for (int i=j-1;i>=0;i--){
      double s = 0.0;
      for (int k2=i+1;k2<=j;k2++) s += L[k2][i]*Ri[k2][j];   // R[i][k2] = L[k2][i]
      Ri[i][j] = -s / L[i][i];
    }
  }
  __syncthreads();
  for (int idx=l; idx<NM*NM; idx+=64){
    int i = idx>>5, j = idx&31;
    Rd[(size_t)b*NM*NM + idx] = (i<=j)? Ri[i][j] : 0.0;
  }
}

// ---------------- Xout = Xin * M (f64 accumulate) ---------------------------
__global__ void k_applyd(const float* __restrict__ Xin, const double* __restrict__ Md,
                         float* __restrict__ Xout){
  __shared__ double Ms[NM*NM];
  int b = blockIdx.x >> 2;
  int n = (blockIdx.x & 3)*256 + threadIdx.x;
  for (int idx=threadIdx.x; idx<NM*NM; idx+=256) Ms[idx] = Md[(size_t)b*NM*NM + idx];
  __syncthreads();
  float xv[NM];
  #pragma unroll
  for (int j=0;j<NM;j++) xv[j] = Xin[((size_t)b*NM + j)*NN + n];
  #pragma unroll
  for (int jn=0;jn<NM;jn++){
    double acc = 0.0;
    #pragma unroll
    for (int j=0;j<NM;j++) acc += (double)xv[j] * Ms[j*NM + jn];
    Xout[((size_t)b*NM + jn)*NN + n] = (float)acc;
  }
}

// ---------------- 32x32 Jacobi eigensolver (parallel ordering) ---------------
__global__ __launch_bounds__(64) void k_jacobi(const double* __restrict__ Gd, double* __restrict__ Ud,
                         float* __restrict__ th, float* __restrict__ aint, int sweeps){
  __shared__ float S[NM][NM];
  __shared__ float V[NM][NM];
  __shared__ float cs_[16], sn_[16];
  __shared__ int pp_[16], qq_[16];
  __shared__ int perm[NM];
  __shared__ float evs[NM];
  int b = blockIdx.x, l = threadIdx.x;
  for (int idx=l; idx<NM*NM; idx+=64){
    int i = idx>>5, j = idx&31;
    S[i][j] = (float)(0.5*(Gd[(size_t)b*NM*NM + i*NM + j] + Gd[(size_t)b*NM*NM + j*NM + i]));
    V[i][j] = (i==j)? 1.0f : 0.0f;
  }
  __syncthreads();
  for (int sw=0; sw<sweeps; sw++){
    for (int r=0; r<31; r++){
      if (l < 16){
        int p, q;
        if (l == 0){ p = r; q = 31; }
        else { p = (r + l) % 31; q = (r + 31 - l) % 31; }
        if (p > q){ int t_=p; p=q; q=t_; }
        float apq = S[p][q];
        float c = 1.0f, s = 0.0f;
        if (fabsf(apq) > 1e-30f){
          float tau = (S[q][q] - S[p][p]) / (2.0f*apq);
          float tt = (tau >= 0.f ? 1.0f : -1.0f) / (fabsf(tau) + sqrtf(1.0f + tau*tau));
          c = 1.0f/sqrtf(1.0f + tt*tt); s = tt*c;
        }
        cs_[l]=c; sn_[l]=s; pp_[l]=p; qq_[l]=q;
      }
      __syncthreads();
      for (int tsk=l; tsk<512; tsk+=64){
        int i = tsk >> 4, kk = tsk & 15;
        int p = pp_[kk], q = qq_[kk];
        float c = cs_[kk], s = sn_[kk];
        float sp = S[i][p], sq = S[i][q];
        S[i][p] = c*sp - s*sq; S[i][q] = s*sp + c*sq;
        float vp = V[i][p], vq = V[i][q];
        V[i][p] = c*vp - s*vq; V[i][q] = s*vp + c*vq;
      }
      __syncthreads();
      for (int tsk=l; tsk<512; tsk+=64){
        int jc = tsk >> 4, kk = tsk & 15;
        int p = pp_[kk], q = qq_[kk];
        float c = cs_[kk], s = sn_[kk];
        float sp = S[p][jc], sq = S[q][jc];
        S[p][jc] = c*sp - s*sq; S[q][jc] = s*sp + c*sq;
      }
      __syncthreads();
    }
  }
  if (l == 0){
    for (int i=0;i<NM;i++){ perm[i]=i; evs[i]=S[i][i]; }
    for (int i=0;i<NM;i++){
      int mi = i;
      for (int j=i+1;j<NM;j++) if (evs[perm[j]] < evs[perm[mi]]) mi = j;
      int t_=perm[i]; perm[i]=perm[mi]; perm[mi]=t_;
    }
    for (int i=0;i<NM;i++) th[b*NM+i] = evs[perm[i]];
    float a = evs[perm[NM-1]]*1.02f + 1e-4f;
    aint[b] = fminf(fmaxf(a, 0.02f), 1.9f);
  }
  __syncthreads();
  for (int idx=l; idx<NM*NM; idx+=64){
    int i = idx>>5, j = idx&31;
    Ud[(size_t)b*NM*NM + i*NM + j] = (double)V[i][perm[j]];
  }
}

// ---------------- xs[b][k][t][c] = sum_n X[b][k][n] * h[b][n][t][c] ----------
__global__ __launch_bounds__(256) void k_project(const float* __restrict__ X, const float* __restrict__ h,
                          float* __restrict__ xs){
  __shared__ float xc[NN];
  int b = blockIdx.x >> 4, k = blockIdx.x & 15;
  const float* Xc = X + ((size_t)b*NM + k)*NN;
  for (int n=threadIdx.x; n<NN; n+=256) xc[n] = Xc[n];
  __syncthreads();
  const float* hb = h + (size_t)b*NN*NT*NC;
  int s0 = threadIdx.x, s1 = threadIdx.x + 256, s2 = threadIdx.x + 512;
  bool ok2 = (s2 < NT*NC);
  float a0=0.f, a1=0.f, a2=0.f;
  for (int n=0;n<NN;n++){
    float xv = xc[n];
    const float* hr = hb + (size_t)n*NT*NC;
    a0 += xv*hr[s0];
    a1 += xv*hr[s1];
    if (ok2) a2 += xv*hr[s2];
  }
  float* o = xs + ((size_t)b*NK + k)*NT*NC;
  o[s0] = a0; o[s1] = a1;
  if (ok2) o[s2] = a2;
}

// ---------------- rfft(:4) -> complex channel mix -> irfft -------------------
__global__ __launch_bounds__(64) void k_timefilter(const float* __restrict__ xs, const float* __restrict__ fwr,
                             const float* __restrict__ fwi, float* __restrict__ osb, int layer){
  __shared__ float xst[NT*NC];
  __shared__ float xfr[NC][NMT];
  __shared__ float xfi[NC][NMT];
  int b = blockIdx.x >> 4, k = blockIdx.x & 15;
  const float* xin = xs + ((size_t)b*NK + k)*NT*NC;
  for (int idx=threadIdx.x; idx<NT*NC; idx+=64) xst[idx] = xin[idx];
  __syncthreads();
  int l = threadIdx.x;
  if (l < NC){
    float ar0=0,ar1=0,ar2=0,ar3=0, ai1=0,ai2=0,ai3=0;
    for (int t=0;t<NT;t++){
      float v = xst[t*NC + l];
      float w1 = 0.31415926535897932f * (float)t;  // 2*pi*t/20
      ar0 += v;
      ar1 += v*cosf(w1);       ai1 -= v*sinf(w1);
      ar2 += v*cosf(2.f*w1);   ai2 -= v*sinf(2.f*w1);
      ar3 += v*cosf(3.f*w1);   ai3 -= v*sinf(3.f*w1);
    }
    xfr[l][0]=ar0; xfi[l][0]=0.f;
    xfr[l][1]=ar1; xfi[l][1]=ai1;
    xfr[l][2]=ar2; xfi[l][2]=ai2;
    xfr[l][3]=ar3; xfi[l][3]=ai3;
  }
  __syncthreads();
  if (l < NC){
    int o = l;
    float ofr[NMT], ofi[NMT];
    #pragma unroll
    for (int f=0; f<NMT; f++){ ofr[f]=0.f; ofi[f]=0.f; }
    for (int i=0;i<NC;i++){
      size_t wbase = ((((size_t)layer*NC + i)*NC + o)*NK + k)*NMT;
      #pragma unroll
      for (int f=0; f<NMT; f++){
        float wr = fwr[wbase+f], wi2 = fwi[wbase+f];
        float xr = xfr[i][f], xi = xfi[i][f];
        ofr[f] += xr*wr - xi*wi2;
        ofi[f] += xr*wi2 + xi*wr;
      }
    }
    float* outp = osb + ((size_t)b*NK + k)*NT*NC;
    for (int t=0;t<NT;t++){
      float w1 = 0.31415926535897932f * (float)t;
      float acc = ofr[0];
      acc += 2.f*(ofr[1]*cosf(w1)     - ofi[1]*sinf(w1));
      acc += 2.f*(ofr[2]*cosf(2.f*w1) - ofi[2]*sinf(2.f*w1));
      acc += 2.f*(ofr[3]*cosf(3.f*w1) - ofi[3]*sinf(3.f*w1));
      outp[t*NC + o] = acc * 0.05f;
    }
  }
}

// ---------------- h' = basis*os + cw*h + cb, gelu (layers 0..2) --------------
__global__ __launch_bounds__(256) void k_update(const float* __restrict__ X, const float* __restrict__ osb,
                         const float* __restrict__ h, const float* __restrict__ cw,
                         const float* __restrict__ cb, float* __restrict__ hout, int layer){
  __shared__ float os_s[NK*NT*NC];   // 40KB
  __shared__ float cwT[NC*NC];
  __shared__ float Xl[NK][64];
  __shared__ float cbs[NC];
  int b = blockIdx.x >> 4;
  int n0 = (blockIdx.x & 15)*64;
  for (int idx=threadIdx.x; idx<NK*NT*NC; idx+=256) os_s[idx] = osb[(size_t)b*NK*NT*NC + idx];
  for (int idx=threadIdx.x; idx<NC*NC; idx+=256){
    int o = idx/NC, i = idx%NC;
    cwT[i*NC + o] = cw[((size_t)layer*NC + o)*NC + i];
  }
  if (threadIdx.x < NC) cbs[threadIdx.x] = cb[layer*NC + threadIdx.x];
  for (int idx=threadIdx.x; idx<NK*64; idx+=256){
    int k = idx >> 6, nl = idx & 63;
    Xl[k][nl] = X[((size_t)b*NM + k)*NN + n0 + nl];
  }
  __syncthreads();
  for (int tsk=threadIdx.x; tsk<64*NT; tsk+=256){
    int t = tsk % NT, nl = tsk / NT;
    int n = n0 + nl;
    const float* hr = h + (((size_t)b*NN + n)*NT + t)*NC;
    float acc[NC];
    #pragma unroll
    for (int o=0;o<NC;o++) acc[o] = cbs[o];
    #pragma unroll
    for (int k=0;k<NK;k++){
      float xv = Xl[k][nl];
      const float* osr = os_s + (k*NT + t)*NC;
      #pragma unroll
      for (int o=0;o<NC;o++) acc[o] += xv*osr[o];
    }
    for (int i=0;i<NC;i++){
      float hv = hr[i];
      const float* cwr = cwT + i*NC;
      #pragma unroll
      for (int o=0;o<NC;o++) acc[o] += hv*cwr[o];
    }
    float* outp = hout + (((size_t)b*NN + n)*NT + t)*NC;
    if (layer < 3){
      #pragma unroll
      for (int o=0;o<NC;o++) outp[o] = gelu_f(acc[o]);
    } else {
      #pragma unroll
      for (int o=0;o<NC;o++) outp[o] = acc[o];
    }
  }
}

// ---------------- head: gelu(h@q1w+q1b)@q2w + q2b ----------------------------
__global__ __launch_bounds__(256) void k_head(const float* __restrict__ h, const float* __restrict__ q1w,
                       const float* __restrict__ q1b, const float* __restrict__ q2w,
                       const float* __restrict__ q2b, float* __restrict__ out){
  __shared__ float w1[NC*NQ];
  __shared__ float b1[NQ], w2[NQ];
  for (int idx=threadIdx.x; idx<NC*NQ; idx+=256) w1[idx] = q1w[idx];
  if (threadIdx.x < NQ){ b1[threadIdx.x] = q1b[threadIdx.x]; w2[threadIdx.x] = q2w[threadIdx.x]; }
  __syncthreads();
  int idx = blockIdx.x*256 + threadIdx.x;
  if (idx >= NB*NN*NT) return;
  const float* hr = h + (size_t)idx*NC;
  float hv[NC];
  #pragma unroll
  for (int i=0;i<NC;i++) hv[i] = hr[i];
  float res = q2b[0];
  for (int j=0;j<NQ;j++){
    float z = b1[j];
    #pragma unroll
    for (int i=0;i<NC;i++) z += hv[i]*w1[i*NQ + j];
    res += gelu_f(z)*w2[j];
  }
  out[idx] = res;
}

// ============================================================================
extern "C" void kernel_launch(void* const* d_in, const int* in_sizes, int n_in,
                              void* d_out, int out_size, void* d_ws, size_t ws_size,
                              hipStream_t stream){
  (void)in_sizes; (void)n_in; (void)out_size;
  const float* x   = (const float*)d_in[0];
  const float* pos = (const float*)d_in[1];
  const float* Wp  = (const float*)d_in[2];
  const float* bp  = (const float*)d_in[3];
  const float* fwr = (const float*)d_in[4];
  const float* fwi = (const float*)d_in[5];
  const float* cw  = (const float*)d_in[6];
  const float* cb  = (const float*)d_in[7];
  const float* q1w = (const float*)d_in[8];
  const float* q1b = (const float*)d_in[9];
  const float* q2w = (const float*)d_in[10];
  const float* q2b = (const float*)d_in[11];

  char* p = (char*)d_ws;
  auto take = [&](size_t bytes)->void*{
    void* r = (void*)p;
    p += (bytes + 255) & ~(size_t)255;
    return r;
  };
  float*  hA    = (float*) take(sizeof(float)*NB*NN*NT*NC);
  float*  hB    = (float*) take(sizeof(float)*NB*NN*NT*NC);
  float*  knnd  = (float*) take(sizeof(float)*NB*NN*8);
  int*    knni  = (int*)   take(sizeof(int)*NB*NN*8);
  double* sig   = (double*)take(sizeof(double)*NB);
  int*    cntb  = (int*)   take(sizeof(int)*NB*NN);
  int*    ecol  = (int*)   take(sizeof(int)*(size_t)NB*NN*WE);
  float*  evalv = (float*) take(sizeof(float)*(size_t)NB*NN*WE);
  float*  deg   = (float*) take(sizeof(float)*NB*NN);
  float*  dinv  = (float*) take(sizeof(float)*NB*NN);
  float*  dval  = (float*) take(sizeof(float)*NB*NN);
  float*  Xb    = (float*) take(sizeof(float)*NB*NM*NN);
  float*  Yb    = (float*) take(sizeof(float)*NB*NM*NN);
  double* Gd    = (double*)take(sizeof(double)*NB*NM*NM);
  double* Rd    = (double*)take(sizeof(double)*NB*NM*NM);
  double* Ud    = (double*)take(sizeof(double)*NB*NM*NM);
  float*  th    = (float*) take(sizeof(float)*NB*NM);
  float*  aint  = (float*) take(sizeof(float)*NB);
  float*  xs    = (float*) take(sizeof(float)*NB*NK*NT*NC);
  float*  osb   = (float*) take(sizeof(float)*NB*NK*NT*NC);
  if ((size_t)(p - (char*)d_ws) > ws_size) return;  // ws too small -> loud failure

  k_build_h0<<<(NB*NN*NT*NC+255)/256, 256, 0, stream>>>(x, pos, Wp, bp, hA);

  static const int RDEG[6] = {12, 20, 20, 20, 20, 20};
  float* hcur = hA; float* hnext = hB;
  for (int layer=0; layer<4; layer++){
    hipMemsetAsync(sig, 0, sizeof(double)*NB, stream);
    k_dist_knn<<<NB*NN/4, 256, 0, stream>>>(hcur, knnd, knni, sig, cntb);
    k_build_ell<<<NB*NN/256, 256, 0, stream>>>(knnd, knni, sig, cntb, ecol, evalv);
    k_degnorm<<<NB*NN/256, 256, 0, stream>>>(cntb, evalv, deg, dinv);
    k_normell<<<NB*NN/256, 256, 0, stream>>>(cntb, ecol, evalv, deg, dinv, dval);
    k_initX<<<NB*NM*NN/256, 256, 0, stream>>>(deg, Xb, aint);
    float* cur = Xb; float* oth = Yb;
    for (int r=0; r<6; r++){
      k_cheb<<<NB*8, 256, 0, stream>>>(cntb, ecol, evalv, dval, cur, aint, RDEG[r]);
      k_gram<<<NB*NM, 256, 0, stream>>>(cur, cur, Gd);
      k_cholinv<<<NB, 64, 0, stream>>>(Gd, Rd);
      k_applyd<<<NB*4, 256, 0, stream>>>(cur, Rd, oth);
      { float* t_ = cur; cur = oth; oth = t_; }
      if (r == 0 || r == 5){
        k_spmv<<<NB*NM, 256, 0, stream>>>(cntb, ecol, evalv, dval, cur, oth);
        k_gram<<<NB*NM, 256, 0, stream>>>(cur, oth, Gd);
        k_jacobi<<<NB, 64, 0, stream>>>(Gd, Ud, th, aint, (r==5)?6:4);
        k_applyd<<<NB*4, 256, 0, stream>>>(cur, Ud, oth);
        { float* t_ = cur; cur = oth; oth = t_; }
      }
    }
    k_project<<<NB*NK, 256, 0, stream>>>(cur, hcur, xs);
    k_timefilter<<<NB*NK, 64, 0, stream>>>(xs, fwr, fwi, osb, layer);
    k_update<<<NB*16, 256, 0, stream>>>(cur, osb, hcur, cw, cb, hnext, layer);
    { float* t_ = hcur; hcur = hnext; hnext = t_; }
  }
  k_head<<<(NB*NN*NT+255)/256, 256, 0, stream>>>(hcur, q1w, q1b, q2w, q2b, (float*)d_out);
}

// Round 2
// 12896.223 us; speedup vs baseline: 1.2193x; 1.2193x over previous
//
#include <hip/hip_runtime.h>

#define NB 8
#define NN 1024
#define NC 32
#define NT 20
#define NTI 10
#define NM 32     // iteration block size (16 wanted + 16 guard)
#define NK 16     // K_SPACE
#define NMT 4     // M_TIME
#define WE 64     // ELL width (max entries per row)
#define NQ 128
#define GNN (NB*NN)

__device__ __forceinline__ float gelu_f(float x){
  return 0.5f * x * (1.0f + erff(x * 0.70710678118654752f));
}
__device__ __forceinline__ unsigned wanghash(unsigned s){
  s = (s ^ 61u) ^ (s >> 16); s *= 9u; s ^= s >> 4; s *= 0x27d4eb2du; s ^= s >> 15;
  return s;
}

// ---------------- initial lift: h[b][n][t][c] = concat(x,pos,t) @ Wp + bp ----
__global__ void k_build_h0(const float* __restrict__ x, const float* __restrict__ pos,
                           const float* __restrict__ Wp, const float* __restrict__ bp,
                           float* __restrict__ h){
  int idx = blockIdx.x*256 + threadIdx.x;
  if (idx >= NB*NN*NT*NC) return;
  int c = idx & (NC-1);
  int t = (idx/NC) % NT;
  int n = (idx/(NC*NT)) & (NN-1);
  int b = idx/(NC*NT*NN);
  const float* xr = x + (b*NN + n)*NTI;
  float acc = bp[c];
  #pragma unroll
  for (int i=0;i<NTI;i++) acc += xr[i]*Wp[i*NC+c];
  acc += pos[(b*NN+n)*2+0]*Wp[10*NC+c];
  acc += pos[(b*NN+n)*2+1]*Wp[11*NC+c];
  float tv = (float)(10+t) * (1.0f/29.0f);
  acc += tv*Wp[12*NC+c];
  h[idx] = acc;
}

// ---------------- fused pairwise distance + top-8 kNN + sigma sum ------------
__global__ __launch_bounds__(256) void k_dist_knn(const float* __restrict__ h,
                           float* __restrict__ knnd, int* __restrict__ knni,
                           double* __restrict__ sig, int* __restrict__ cnt){
  __shared__ float fr_s[4][NC];
  int wave = threadIdx.x >> 6;
  int lane = threadIdx.x & 63;
  int row = blockIdx.x*4 + wave;       // global row over NB*NN
  int b = row >> 10;
  if (threadIdx.x < 4*NC){
    int w = threadIdx.x >> 5, c = threadIdx.x & 31;
    int rr = blockIdx.x*4 + w;
    fr_s[w][c] = h[((size_t)rr*NT)*NC + c];
  }
  __syncthreads();
  float fr[NC];
  #pragma unroll
  for (int c=0;c<NC;c++) fr[c] = fr_s[wave][c];
  float d8[8]; int i8[8];
  #pragma unroll
  for (int j=0;j<8;j++){ d8[j]=1e30f; i8[j]=0x3fffffff; }
  double ssum = 0.0;
  const float* fb = h + (size_t)b*NN*NT*NC;
  for (int m=lane; m<NN; m+=64){
    const float* fm = fb + (size_t)m*NT*NC;
    float d2 = 0.f;
    #pragma unroll
    for (int c=0;c<NC;c++){ float df = fr[c]-fm[c]; d2 += df*df; }
    float d = sqrtf(d2);
    ssum += (double)d;
    if (d < d8[7] || (d == d8[7] && m < i8[7])){
      d8[7] = d; i8[7] = m;
      #pragma unroll
      for (int j=6;j>=0;j--){
        bool sw = (d8[j+1] < d8[j]) || (d8[j+1]==d8[j] && i8[j+1]<i8[j]);
        if (sw){ float td=d8[j]; d8[j]=d8[j+1]; d8[j+1]=td;
                 int ti=i8[j]; i8[j]=i8[j+1]; i8[j+1]=ti; }
      }
    }
  }
  #pragma unroll
  for (int off=32; off>0; off>>=1) ssum += __shfl_down(ssum, off);
  if (lane==0){ atomicAdd(&sig[b], ssum); cnt[row] = 8; }
  // merge per-lane sorted top-8 lists: 8x wave-argmin extraction
  int ptr = 0;
  for (int sel=0; sel<8; sel++){
    float dv = 1e30f; int iv = 0x3fffffff;
    #pragma unroll
    for (int j=0;j<8;j++) if (j==ptr){ dv=d8[j]; iv=i8[j]; }
    float bd = dv; int bi = iv;
    #pragma unroll
    for (int off=32; off>0; off>>=1){
      float od = __shfl_xor(bd, off);
      int oi = __shfl_xor(bi, off);
      if (od < bd || (od == bd && oi < bi)){ bd = od; bi = oi; }
    }
    if (dv == bd && iv == bi) ptr++;
    if (lane == sel){ knnd[row*8+sel] = bd; knni[row*8+sel] = bi; }
  }
}

// ---------------- symmetrized sparse A in transposed ELL form ----------------
// ecolT[j*GNN + row] (u16), evalT[j*GNN + row] (f32): slot-major, coalesced by row
__global__ void k_build_ell(const float* __restrict__ knnd, const int* __restrict__ knni,
                            const double* __restrict__ sig, int* __restrict__ cnt,
                            unsigned short* __restrict__ ecolT, float* __restrict__ evalT){
  int row = blockIdx.x*256 + threadIdx.x;
  if (row >= NB*NN) return;
  int b = row >> 10;
  float sigma = (float)(sig[b] * (1.0/((double)NN*(double)NN)));
  float s2 = sigma*sigma;
  int rloc = row & (NN-1);
  #pragma unroll
  for (int j=0;j<8;j++){
    float d = knnd[row*8+j];
    int m = knni[row*8+j];
    float v = 0.5f * expf(-d/s2);
    ecolT[(size_t)j*GNN + row] = (unsigned short)m;
    evalT[(size_t)j*GNN + row] = v;
    int grow = (b<<10) + m;
    int p = atomicAdd(&cnt[grow], 1);
    if (p < WE){ ecolT[(size_t)p*GNN + grow] = (unsigned short)rloc;
                 evalT[(size_t)p*GNN + grow] = v; }
  }
}

__global__ void k_degnorm(const int* __restrict__ cnt, const float* __restrict__ evalT,
                          float* __restrict__ deg, float* __restrict__ dinv){
  int row = blockIdx.x*256 + threadIdx.x;
  if (row >= NB*NN) return;
  int c = cnt[row]; if (c > WE) c = WE;
  float s = 0.f;
  for (int j=0;j<c;j++) s += evalT[(size_t)j*GNN + row];
  deg[row] = s;
  dinv[row] = 1.0f/sqrtf(s + 1e-6f);
}

__global__ void k_normell(const int* __restrict__ cnt, const unsigned short* __restrict__ ecolT,
                          float* __restrict__ evalT, const float* __restrict__ deg,
                          const float* __restrict__ dinv, float* __restrict__ dval){
  int row = blockIdx.x*256 + threadIdx.x;
  if (row >= NB*NN) return;
  int b = row >> 10;
  const float* dv = dinv + (b<<10);
  float di = dinv[row];
  int c = cnt[row]; if (c > WE) c = WE;
  for (int j=0;j<c;j++){
    int col = ecolT[(size_t)j*GNN + row];
    evalT[(size_t)j*GNN + row] = evalT[(size_t)j*GNN + row] * (di * dv[col]);
  }
  dval[row] = di*di*deg[row];
}

// ---------------- eigensolver: init block -----------------------------------
__global__ void k_initX(const float* __restrict__ deg, float* __restrict__ X, float* __restrict__ aint){
  int idx = blockIdx.x*256+threadIdx.x;
  if (idx >= NB*NM*NN) return;
  int n = idx & (NN-1);
  int j = (idx >> 10) & (NM-1);
  int b = idx >> 15;
  float v;
  if (j == 0) v = sqrtf(deg[(b<<10)+n] + 1e-6f);   // exact 0-eigenvector of Lhat
  else {
    unsigned hsh = wanghash((unsigned)idx * 2654435761u + 12345u);
    v = ((hsh >> 8) * (1.0f/16777216.0f)) - 0.5f;
  }
  X[idx] = v;
  if (n == 0 && j == 1) aint[b] = 1.0f;
}

// ---------------- Chebyshev filter on Lhat, one column per block -------------
// 256 blocks (b,col), 512 threads, 2 rows/thread, interleaved chains.
__global__ __launch_bounds__(512) void k_cheb(const int* __restrict__ cnt,
                        const unsigned short* __restrict__ ecolT,
                        const float* __restrict__ evalT, const float* __restrict__ dval,
                        float* __restrict__ X, const float* __restrict__ aint, int ndeg){
  __shared__ float bufA[NN];
  __shared__ float bufB[NN];
  int b = blockIdx.x >> 5;
  int col = blockIdx.x & 31;
  float a = aint[b];
  const float bhi = 2.0005f;
  float e  = 0.5f*(bhi - a);
  float cc = 0.5f*(bhi + a);
  float inv_e = 1.0f/e;
  const int rowbase = b << 10;
  float* Xc = X + ((size_t)b*NM + col)*NN;
  for (int n=threadIdx.x; n<NN; n+=512) bufA[n] = Xc[n];
  int r0 = threadIdx.x, r1 = threadIdx.x + 512;
  int c0 = cnt[rowbase+r0]; if (c0 > WE) c0 = WE;
  int c1 = cnt[rowbase+r1]; if (c1 > WE) c1 = WE;
  float dv0 = dval[rowbase+r0];
  float dv1 = dval[rowbase+r1];
  int cmax = (c0 > c1)? c0 : c1;
  const unsigned short* pe0b = ecolT + rowbase + r0;
  const unsigned short* pe1b = ecolT + rowbase + r1;
  const float* pv0b = evalT + rowbase + r0;
  const float* pv1b = evalT + rowbase + r1;
  __syncthreads();
  float* cur = bufA; float* prv = bufB;
  for (int k=0;k<ndeg;k++){
    float f = (k==0)? inv_e : 2.0f*inv_e;
    float x0 = cur[r0], x1 = cur[r1];
    float acc0 = dv0*x0, acc1 = dv1*x1;
    const unsigned short* pe0 = pe0b; const unsigned short* pe1 = pe1b;
    const float* pv0 = pv0b; const float* pv1 = pv1b;
    for (int j=0;j<cmax;j++){
      if (j < c0) acc0 -= pv0[0] * cur[pe0[0]];
      if (j < c1) acc1 -= pv1[0] * cur[pe1[0]];
      pe0 += GNN; pe1 += GNN; pv0 += GNN; pv1 += GNN;
    }
    float n0 = f*(acc0 - cc*x0);
    float n1 = f*(acc1 - cc*x1);
    if (k > 0){ n0 -= prv[r0]; n1 -= prv[r1]; }
    prv[r0] = n0; prv[r1] = n1;
    float* t_ = cur; cur = prv; prv = t_;
    __syncthreads();
  }
  for (int n=threadIdx.x; n<NN; n+=512) Xc[n] = cur[n];
}

// ---------------- Y = Lhat * X (one column per workgroup) --------------------
__global__ void k_spmv(const int* __restrict__ cnt, const unsigned short* __restrict__ ecolT,
                       const float* __restrict__ evalT, const float* __restrict__ dval,
                       const float* __restrict__ X, float* __restrict__ Y){
  __shared__ float xc[NN];
  int b = blockIdx.x >> 5, j = blockIdx.x & 31;
  const float* Xc = X + ((size_t)b*NM + j)*NN;
  for (int n=threadIdx.x; n<NN; n+=256) xc[n] = Xc[n];
  __syncthreads();
  int rowbase = b << 10;
  for (int r=threadIdx.x; r<NN; r+=256){
    int c = cnt[rowbase+r]; if (c > WE) c = WE;
    float acc = dval[rowbase+r]*xc[r];
    const unsigned short* pe = ecolT + rowbase + r;
    const float* pv = evalT + rowbase + r;
    for (int jj=0;jj<c;jj++){
      acc -= pv[0]*xc[pe[0]];
      pe += GNN; pv += GNN;
    }
    Y[((size_t)b*NM + j)*NN + r] = acc;
  }
}

// ---------------- G = A^T B (f64 accumulate), one row of G per wg ------------
__global__ void k_gram(const float* __restrict__ A, const float* __restrict__ Bm,
                       double* __restrict__ G){
  __shared__ float ai[NN];
  __shared__ double pd[NM][8];
  int b = blockIdx.x >> 5, i = blockIdx.x & 31;
  const float* Ac = A + ((size_t)b*NM + i)*NN;
  for (int n=threadIdx.x; n<NN; n+=256) ai[n] = Ac[n];
  __syncthreads();
  int j = threadIdx.x & 31, seg = threadIdx.x >> 5;
  const float* Bc = Bm + ((size_t)b*NM + j)*NN + seg*128;
  const float* as = ai + seg*128;
  double s = 0.0;
  for (int n=0;n<128;n++) s += (double)as[n]*(double)Bc[n];
  pd[j][seg] = s;
  __syncthreads();
  if (threadIdx.x < NM){
    double t = 0.0;
    #pragma unroll
    for (int q=0;q<8;q++) t += pd[threadIdx.x][q];
    G[((size_t)b*NM + i)*NM + threadIdx.x] = t;
  }
}

// ---------------- fused CholQR: gram + chol-inv + apply, one block per b -----
__global__ __launch_bounds__(1024) void k_qr(float* __restrict__ X){
  __shared__ float Xs[NN][NM+1];    // 132KB, padded vs bank conflicts
  __shared__ double Ld[NM][NM];     // 8KB
  __shared__ double Ri[NM][NM];     // 8KB
  int b = blockIdx.x;
  int tid = threadIdx.x;
  for (int idx=tid; idx<NM*NN; idx+=1024){
    int j = idx >> 10, n = idx & (NN-1);
    Xs[n][j] = X[((size_t)b*NM + j)*NN + n];
  }
  __syncthreads();
  // Gram (f64): thread (j=tid>>5, seg=tid&31)
  int j = tid >> 5, seg = tid & 31;
  for (int i=0;i<NM;i++){
    double s = 0.0;
    for (int n=seg; n<NN; n+=32) s += (double)Xs[n][i] * (double)Xs[n][j];
    for (int off=16; off>0; off>>=1) s += __shfl_down(s, off, 32);
    if (seg == 0) Ld[i][j] = s;
  }
  __syncthreads();
  // Cholesky (lower L in Ld)
  for (int k=0;k<NM;k++){
    if (tid == 0){
      double orig = Ld[k][k];
      double s = orig;
      for (int p=0;p<k;p++) s -= Ld[k][p]*Ld[k][p];
      double floorv = orig*1e-15; if (floorv < 1e-30) floorv = 1e-30;
      if (s < floorv) s = floorv;
      Ld[k][k] = sqrt(s);
    }
    __syncthreads();
    if (tid > k && tid < NM){
      double s = Ld[tid][k];
      for (int p=0;p<k;p++) s -= Ld[tid][p]*Ld[k][p];
      Ld[tid][k] = s / Ld[k][k];
    }
    __syncthreads();
  }
  // R^{-1} (upper), column per thread
  if (tid < NM){
    int jc = tid;
    Ri[jc][jc] = 1.0 / Ld[jc][jc];
    for (int i=jc-1;i>=0;i--){
      double s = 0.0;
      for (int k2=i+1;k2<=jc;k2++) s += Ld[k2][i]*Ri[k2][jc];
      Ri[i][jc] = -s / Ld[i][i];
    }
  }
  __syncthreads();
  // apply: X <- X * R^{-1}; thread = node n
  int n = tid;
  float xv[NM];
  #pragma unroll
  for (int j2=0;j2<NM;j2++) xv[j2] = Xs[n][j2];
  for (int jn=0;jn<NM;jn++){
    double acc = 0.0;
    for (int j2=0;j2<=jn;j2++) acc += (double)xv[j2] * Ri[j2][jn];
    X[((size_t)b*NM + jn)*NN + n] = (float)acc;
  }
}

// ---------------- Xout = Xin * M (f64 accumulate) ---------------------------
__global__ void k_applyd(const float* __restrict__ Xin, const double* __restrict__ Md,
                         float* __restrict__ Xout){
  __shared__ double Ms[NM*NM];
  int b = blockIdx.x >> 2;
  int n = (blockIdx.x & 3)*256 + threadIdx.x;
  for (int idx=threadIdx.x; idx<NM*NM; idx+=256) Ms[idx] = Md[(size_t)b*NM*NM + idx];
  __syncthreads();
  float xv[NM];
  #pragma unroll
  for (int j=0;j<NM;j++) xv[j] = Xin[((size_t)b*NM + j)*NN + n];
  #pragma unroll
  for (int jn=0;jn<NM;jn++){
    double acc = 0.0;
    #pragma unroll
    for (int j=0;j<NM;j++) acc += (double)xv[j] * Ms[j*NM + jn];
    Xout[((size_t)b*NM + jn)*NN + n] = (float)acc;
  }
}

// ---------------- 32x32 Jacobi eigensolver (parallel ordering) ---------------
__global__ __launch_bounds__(64) void k_jacobi(const double* __restrict__ Gd, double* __restrict__ Ud,
                         float* __restrict__ th, float* __restrict__ aint, int sweeps){
  __shared__ float S[NM][NM];
  __shared__ float V[NM][NM];
  __shared__ float cs_[16], sn_[16];
  __shared__ int pp_[16], qq_[16];
  __shared__ int perm[NM];
  __shared__ float evs[NM];
  int b = blockIdx.x, l = threadIdx.x;
  for (int idx=l; idx<NM*NM; idx+=64){
    int i = idx>>5, j = idx&31;
    S[i][j] = (float)(0.5*(Gd[(size_t)b*NM*NM + i*NM + j] + Gd[(size_t)b*NM*NM + j*NM + i]));
    V[i][j] = (i==j)? 1.0f : 0.0f;
  }
  __syncthreads();
  for (int sw=0; sw<sweeps; sw++){
    for (int r=0; r<31; r++){
      if (l < 16){
        int p, q;
        if (l == 0){ p = r; q = 31; }
        else { p = (r + l) % 31; q = (r + 31 - l) % 31; }
        if (p > q){ int t_=p; p=q; q=t_; }
        float apq = S[p][q];
        float c = 1.0f, s = 0.0f;
        if (fabsf(apq) > 1e-30f){
          float tau = (S[q][q] - S[p][p]) / (2.0f*apq);
          float tt = (tau >= 0.f ? 1.0f : -1.0f) / (fabsf(tau) + sqrtf(1.0f + tau*tau));
          c = 1.0f/sqrtf(1.0f + tt*tt); s = tt*c;
        }
        cs_[l]=c; sn_[l]=s; pp_[l]=p; qq_[l]=q;
      }
      __syncthreads();
      for (int tsk=l; tsk<512; tsk+=64){
        int i = tsk >> 4, kk = tsk & 15;
        int p = pp_[kk], q = qq_[kk];
        float c = cs_[kk], s = sn_[kk];
        float sp = S[i][p], sq = S[i][q];
        S[i][p] = c*sp - s*sq; S[i][q] = s*sp + c*sq;
        float vp = V[i][p], vq = V[i][q];
        V[i][p] = c*vp - s*vq; V[i][q] = s*vp + c*vq;
      }
      __syncthreads();
      for (int tsk=l; tsk<512; tsk+=64){
        int jc = tsk >> 4, kk = tsk & 15;
        int p = pp_[kk], q = qq_[kk];
        float c = cs_[kk], s = sn_[kk];
        float sp = S[p][jc], sq = S[q][jc];
        S[p][jc] = c*sp - s*sq; S[q][jc] = s*sp + c*sq;
      }
      __syncthreads();
    }
  }
  if (l == 0){
    for (int i=0;i<NM;i++){ perm[i]=i; evs[i]=S[i][i]; }
    for (int i=0;i<NM;i++){
      int mi = i;
      for (int j=i+1;j<NM;j++) if (evs[perm[j]] < evs[perm[mi]]) mi = j;
      int t_=perm[i]; perm[i]=perm[mi]; perm[mi]=t_;
    }
    for (int i=0;i<NM;i++) th[b*NM+i] = evs[perm[i]];
    float a = evs[perm[NM-1]]*1.02f + 1e-4f;
    aint[b] = fminf(fmaxf(a, 0.02f), 1.9f);
  }
  __syncthreads();
  for (int idx=l; idx<NM*NM; idx+=64){
    int i = idx>>5, j = idx&31;
    Ud[(size_t)b*NM*NM + i*NM + j] = (double)V[i][perm[j]];
  }
}

// ---------------- xs[b][k][t][c] = sum_n X[b][k][n] * h[b][n][t][c] ----------
__global__ __launch_bounds__(256) void k_project(const float* __restrict__ X, const float* __restrict__ h,
                          float* __restrict__ xs){
  __shared__ float xc[NN];
  int b = blockIdx.x >> 4, k = blockIdx.x & 15;
  const float* Xc = X + ((size_t)b*NM + k)*NN;
  for (int n=threadIdx.x; n<NN; n+=256) xc[n] = Xc[n];
  __syncthreads();
  const float* hb = h + (size_t)b*NN*NT*NC;
  int s0 = threadIdx.x, s1 = threadIdx.x + 256, s2 = threadIdx.x + 512;
  bool ok2 = (s2 < NT*NC);
  float a0=0.f, a1=0.f, a2=0.f;
  for (int n=0;n<NN;n++){
    float xv = xc[n];
    const float* hr = hb + (size_t)n*NT*NC;
    a0 += xv*hr[s0];
    a1 += xv*hr[s1];
    if (ok2) a2 += xv*hr[s2];
  }
  float* o = xs + ((size_t)b*NK + k)*NT*NC;
  o[s0] = a0; o[s1] = a1;
  if (ok2) o[s2] = a2;
}

// ---------------- rfft(:4) -> complex channel mix -> irfft -------------------
__global__ __launch_bounds__(64) void k_timefilter(const float* __restrict__ xs, const float* __restrict__ fwr,
                             const float* __restrict__ fwi, float* __restrict__ osb, int layer){
  __shared__ float xst[NT*NC];
  __shared__ float xfr[NC][NMT];
  __shared__ float xfi[NC][NMT];
  int b = blockIdx.x >> 4, k = blockIdx.x & 15;
  const float* xin = xs + ((size_t)b*NK + k)*NT*NC;
  for (int idx=threadIdx.x; idx<NT*NC; idx+=64) xst[idx] = xin[idx];
  __syncthreads();
  int l = threadIdx.x;
  if (l < NC){
    float ar0=0,ar1=0,ar2=0,ar3=0, ai1=0,ai2=0,ai3=0;
    for (int t=0;t<NT;t++){
      float v = xst[t*NC + l];
      float w1 = 0.31415926535897932f * (float)t;  // 2*pi*t/20
      ar0 += v;
      ar1 += v*cosf(w1);       ai1 -= v*sinf(w1);
      ar2 += v*cosf(2.f*w1);   ai2 -= v*sinf(2.f*w1);
      ar3 += v*cosf(3.f*w1);   ai3 -= v*sinf(3.f*w1);
    }
    xfr[l][0]=ar0; xfi[l][0]=0.f;
    xfr[l][1]=ar1; xfi[l][1]=ai1;
    xfr[l][2]=ar2; xfi[l][2]=ai2;
    xfr[l][3]=ar3; xfi[l][3]=ai3;
  }
  __syncthreads();
  if (l < NC){
    int o = l;
    float ofr[NMT], ofi[NMT];
    #pragma unroll
    for (int f=0; f<NMT; f++){ ofr[f]=0.f; ofi[f]=0.f; }
    for (int i=0;i<NC;i++){
      size_t wbase = ((((size_t)layer*NC + i)*NC + o)*NK + k)*NMT;
      #pragma unroll
      for (int f=0; f<NMT; f++){
        float wr = fwr[wbase+f], wi2 = fwi[wbase+f];
        float xr = xfr[i][f], xi = xfi[i][f];
        ofr[f] += xr*wr - xi*wi2;
        ofi[f] += xr*wi2 + xi*wr;
      }
    }
    float* outp = osb + ((size_t)b*NK + k)*NT*NC;
    for (int t=0;t<NT;t++){
      float w1 = 0.31415926535897932f * (float)t;
      float acc = ofr[0];
      acc += 2.f*(ofr[1]*cosf(w1)     - ofi[1]*sinf(w1));
      acc += 2.f*(ofr[2]*cosf(2.f*w1) - ofi[2]*sinf(2.f*w1));
      acc += 2.f*(ofr[3]*cosf(3.f*w1) - ofi[3]*sinf(3.f*w1));
      outp[t*NC + o] = acc * 0.05f;
    }
  }
}

// ---------------- h' = basis*os + cw*h + cb, gelu (layers 0..2) --------------
__global__ __launch_bounds__(256) void k_update(const float* __restrict__ X, const float* __restrict__ osb,
                         const float* __restrict__ h, const float* __restrict__ cw,
                         const float* __restrict__ cb, float* __restrict__ hout, int layer){
  __shared__ float os_s[NK*NT*NC];   // 40KB
  __shared__ float cwT[NC*NC];
  __shared__ float Xl[NK][64];
  __shared__ float cbs[NC];
  int b = blockIdx.x >> 4;
  int n0 = (blockIdx.x & 15)*64;
  for (int idx=threadIdx.x; idx<NK*NT*NC; idx+=256) os_s[idx] = osb[(size_t)b*NK*NT*NC + idx];
  for (int idx=threadIdx.x; idx<NC*NC; idx+=256){
    int o = idx/NC, i = idx%NC;
    cwT[i*NC + o] = cw[((size_t)layer*NC + o)*NC + i];
  }
  if (threadIdx.x < NC) cbs[threadIdx.x] = cb[layer*NC + threadIdx.x];
  for (int idx=threadIdx.x; idx<NK*64; idx+=256){
    int k = idx >> 6, nl = idx & 63;
    Xl[k][nl] = X[((size_t)b*NM + k)*NN + n0 + nl];
  }
  __syncthreads();
  for (int tsk=threadIdx.x; tsk<64*NT; tsk+=256){
    int t = tsk % NT, nl = tsk / NT;
    int n = n0 + nl;
    const float* hr = h + (((size_t)b*NN + n)*NT + t)*NC;
    float acc[NC];
    #pragma unroll
    for (int o=0;o<NC;o++) acc[o] = cbs[o];
    #pragma unroll
    for (int k=0;k<NK;k++){
      float xv = Xl[k][nl];
      const float* osr = os_s + (k*NT + t)*NC;
      #pragma unroll
      for (int o=0;o<NC;o++) acc[o] += xv*osr[o];
    }
    for (int i=0;i<NC;i++){
      float hv = hr[i];
      const float* cwr = cwT + i*NC;
      #pragma unroll
      for (int o=0;o<NC;o++) acc[o] += hv*cwr[o];
    }
    float* outp = hout + (((size_t)b*NN + n)*NT + t)*NC;
    if (layer < 3){
      #pragma unroll
      for (int o=0;o<NC;o++) outp[o] = gelu_f(acc[o]);
    } else {
      #pragma unroll
      for (int o=0;o<NC;o++) outp[o] = acc[o];
    }
  }
}

// ---------------- head: gelu(h@q1w+q1b)@q2w + q2b ----------------------------
__global__ __launch_bounds__(256) void k_head(const float* __restrict__ h, const float* __restrict__ q1w,
                       const float* __restrict__ q1b, const float* __restrict__ q2w,
                       const float* __restrict__ q2b, float* __restrict__ out){
  __shared__ float w1[NC*NQ];
  __shared__ float b1[NQ], w2[NQ];
  for (int idx=threadIdx.x; idx<NC*NQ; idx+=256) w1[idx] = q1w[idx];
  if (threadIdx.x < NQ){ b1[threadIdx.x] = q1b[threadIdx.x]; w2[threadIdx.x] = q2w[threadIdx.x]; }
  __syncthreads();
  int idx = blockIdx.x*256 + threadIdx.x;
  if (idx >= NB*NN*NT) return;
  const float* hr = h + (size_t)idx*NC;
  float hv[NC];
  #pragma unroll
  for (int i=0;i<NC;i++) hv[i] = hr[i];
  float res = q2b[0];
  for (int j=0;j<NQ;j++){
    float z = b1[j];
    #pragma unroll
    for (int i=0;i<NC;i++) z += hv[i]*w1[i*NQ + j];
    res += gelu_f(z)*w2[j];
  }
  out[idx] = res;
}

// ============================================================================
extern "C" void kernel_launch(void* const* d_in, const int* in_sizes, int n_in,
                              void* d_out, int out_size, void* d_ws, size_t ws_size,
                              hipStream_t stream){
  (void)in_sizes; (void)n_in; (void)out_size;
  const float* x   = (const float*)d_in[0];
  const float* pos = (const float*)d_in[1];
  const float* Wp  = (const float*)d_in[2];
  const float* bp  = (const float*)d_in[3];
  const float* fwr = (const float*)d_in[4];
  const float* fwi = (const float*)d_in[5];
  const float* cw  = (const float*)d_in[6];
  const float* cb  = (const float*)d_in[7];
  const float* q1w = (const float*)d_in[8];
  const float* q1b = (const float*)d_in[9];
  const float* q2w = (const float*)d_in[10];
  const float* q2b = (const float*)d_in[11];

  char* p = (char*)d_ws;
  auto take = [&](size_t bytes)->void*{
    void* r = (void*)p;
    p += (bytes + 255) & ~(size_t)255;
    return r;
  };
  float*  hA    = (float*) take(sizeof(float)*NB*NN*NT*NC);
  float*  hB    = (float*) take(sizeof(float)*NB*NN*NT*NC);
  float*  knnd  = (float*) take(sizeof(float)*NB*NN*8);
  int*    knni  = (int*)   take(sizeof(int)*NB*NN*8);
  double* sig   = (double*)take(sizeof(double)*NB);
  int*    cntb  = (int*)   take(sizeof(int)*NB*NN);
  unsigned short* ecolT = (unsigned short*) take(sizeof(unsigned short)*(size_t)GNN*WE);
  float*  evalT = (float*) take(sizeof(float)*(size_t)GNN*WE);
  float*  deg   = (float*) take(sizeof(float)*NB*NN);
  float*  dinv  = (float*) take(sizeof(float)*NB*NN);
  float*  dval  = (float*) take(sizeof(float)*NB*NN);
  float*  Xb    = (float*) take(sizeof(float)*NB*NM*NN);
  float*  Yb    = (float*) take(sizeof(float)*NB*NM*NN);
  double* Gd    = (double*)take(sizeof(double)*NB*NM*NM);
  double* Ud    = (double*)take(sizeof(double)*NB*NM*NM);
  float*  th    = (float*) take(sizeof(float)*NB*NM);
  float*  aint  = (float*) take(sizeof(float)*NB);
  float*  xs    = (float*) take(sizeof(float)*NB*NK*NT*NC);
  float*  osb   = (float*) take(sizeof(float)*NB*NK*NT*NC);
  if ((size_t)(p - (char*)d_ws) > ws_size) return;  // ws too small -> loud failure

  k_build_h0<<<(NB*NN*NT*NC+255)/256, 256, 0, stream>>>(x, pos, Wp, bp, hA);

  static const int RDEG[6] = {12, 20, 20, 20, 20, 20};
  float* hcur = hA; float* hnext = hB;
  for (int layer=0; layer<4; layer++){
    hipMemsetAsync(sig, 0, sizeof(double)*NB, stream);
    k_dist_knn<<<NB*NN/4, 256, 0, stream>>>(hcur, knnd, knni, sig, cntb);
    k_build_ell<<<NB*NN/256, 256, 0, stream>>>(knnd, knni, sig, cntb, ecolT, evalT);
    k_degnorm<<<NB*NN/256, 256, 0, stream>>>(cntb, evalT, deg, dinv);
    k_normell<<<NB*NN/256, 256, 0, stream>>>(cntb, ecolT, evalT, deg, dinv, dval);
    k_initX<<<NB*NM*NN/256, 256, 0, stream>>>(deg, Xb, aint);
    float* cur = Xb; float* oth = Yb;
    for (int r=0; r<6; r++){
      k_cheb<<<NB*NM, 512, 0, stream>>>(cntb, ecolT, evalT, dval, cur, aint, RDEG[r]);
      k_qr<<<NB, 1024, 0, stream>>>(cur);
      if (r == 0 || r == 5){
        k_spmv<<<NB*NM, 256, 0, stream>>>(cntb, ecolT, evalT, dval, cur, oth);
        k_gram<<<NB*NM, 256, 0, stream>>>(cur, oth, Gd);
        k_jacobi<<<NB, 64, 0, stream>>>(Gd, Ud, th, aint, (r==5)?6:4);
        k_applyd<<<NB*4, 256, 0, stream>>>(cur, Ud, oth);
        { float* t_ = cur; cur = oth; oth = t_; }
      }
    }
    k_project<<<NB*NK, 256, 0, stream>>>(cur, hcur, xs);
    k_timefilter<<<NB*NK, 64, 0, stream>>>(xs, fwr, fwi, osb, layer);
    k_update<<<NB*16, 256, 0, stream>>>(cur, osb, hcur, cw, cb, hnext, layer);
    { float* t_ = hcur; hcur = hnext; hnext = t_; }
  }
  k_head<<<(NB*NN*NT+255)/256, 256, 0, stream>>>(hcur, q1w, q1b, q2w, q2b, (float*)d_out);
}

// Round 3
// 6756.377 us; speedup vs baseline: 2.3274x; 1.9087x over previous
//
#include <hip/hip_runtime.h>

#define NB 8
#define NN 1024
#define NC 32
#define NT 20
#define NTI 10
#define NM 32     // iteration block size (16 wanted + 16 guard)
#define NK 16     // K_SPACE
#define NMT 4     // M_TIME
#define WE 64     // ELL width (max entries per row)
#define NQ 128
#define GNN (NB*NN)
#define RSL 24    // edge slots held in registers in k_cheb

__device__ __forceinline__ float gelu_f(float x){
  return 0.5f * x * (1.0f + erff(x * 0.70710678118654752f));
}
__device__ __forceinline__ unsigned wanghash(unsigned s){
  s = (s ^ 61u) ^ (s >> 16); s *= 9u; s ^= s >> 4; s *= 0x27d4eb2du; s ^= s >> 15;
  return s;
}

// ---------------- initial lift: h[b][n][t][c] = concat(x,pos,t) @ Wp + bp ----
__global__ void k_build_h0(const float* __restrict__ x, const float* __restrict__ pos,
                           const float* __restrict__ Wp, const float* __restrict__ bp,
                           float* __restrict__ h){
  int idx = blockIdx.x*256 + threadIdx.x;
  if (idx >= NB*NN*NT*NC) return;
  int c = idx & (NC-1);
  int t = (idx/NC) % NT;
  int n = (idx/(NC*NT)) & (NN-1);
  int b = idx/(NC*NT*NN);
  const float* xr = x + (b*NN + n)*NTI;
  float acc = bp[c];
  #pragma unroll
  for (int i=0;i<NTI;i++) acc += xr[i]*Wp[i*NC+c];
  acc += pos[(b*NN+n)*2+0]*Wp[10*NC+c];
  acc += pos[(b*NN+n)*2+1]*Wp[11*NC+c];
  float tv = (float)(10+t) * (1.0f/29.0f);
  acc += tv*Wp[12*NC+c];
  h[idx] = acc;
}

// ---------------- fused pairwise distance + top-8 kNN + sigma sum ------------
__global__ __launch_bounds__(256) void k_dist_knn(const float* __restrict__ h,
                           float* __restrict__ knnd, int* __restrict__ knni,
                           double* __restrict__ sig, int* __restrict__ cnt){
  __shared__ float fr_s[4][NC];
  int wave = threadIdx.x >> 6;
  int lane = threadIdx.x & 63;
  int row = blockIdx.x*4 + wave;       // global row over NB*NN
  int b = row >> 10;
  if (threadIdx.x < 4*NC){
    int w = threadIdx.x >> 5, c = threadIdx.x & 31;
    int rr = blockIdx.x*4 + w;
    fr_s[w][c] = h[((size_t)rr*NT)*NC + c];
  }
  __syncthreads();
  float fr[NC];
  #pragma unroll
  for (int c=0;c<NC;c++) fr[c] = fr_s[wave][c];
  float d8[8]; int i8[8];
  #pragma unroll
  for (int j=0;j<8;j++){ d8[j]=1e30f; i8[j]=0x3fffffff; }
  double ssum = 0.0;
  const float* fb = h + (size_t)b*NN*NT*NC;
  for (int m=lane; m<NN; m+=64){
    const float* fm = fb + (size_t)m*NT*NC;
    float d2 = 0.f;
    #pragma unroll
    for (int c=0;c<NC;c++){ float df = fr[c]-fm[c]; d2 += df*df; }
    float d = sqrtf(d2);
    ssum += (double)d;
    if (d < d8[7] || (d == d8[7] && m < i8[7])){
      d8[7] = d; i8[7] = m;
      #pragma unroll
      for (int j=6;j>=0;j--){
        bool sw = (d8[j+1] < d8[j]) || (d8[j+1]==d8[j] && i8[j+1]<i8[j]);
        if (sw){ float td=d8[j]; d8[j]=d8[j+1]; d8[j+1]=td;
                 int ti=i8[j]; i8[j]=i8[j+1]; i8[j+1]=ti; }
      }
    }
  }
  #pragma unroll
  for (int off=32; off>0; off>>=1) ssum += __shfl_down(ssum, off);
  if (lane==0){ atomicAdd(&sig[b], ssum); cnt[row] = 8; }
  // merge per-lane sorted top-8 lists: 8x wave-argmin extraction
  int ptr = 0;
  for (int sel=0; sel<8; sel++){
    float dv = 1e30f; int iv = 0x3fffffff;
    #pragma unroll
    for (int j=0;j<8;j++) if (j==ptr){ dv=d8[j]; iv=i8[j]; }
    float bd = dv; int bi = iv;
    #pragma unroll
    for (int off=32; off>0; off>>=1){
      float od = __shfl_xor(bd, off);
      int oi = __shfl_xor(bi, off);
      if (od < bd || (od == bd && oi < bi)){ bd = od; bi = oi; }
    }
    if (dv == bd && iv == bi) ptr++;
    if (lane == sel){ knnd[row*8+sel] = bd; knni[row*8+sel] = bi; }
  }
}

// ---------------- symmetrized sparse A in transposed ELL form ----------------
__global__ void k_build_ell(const float* __restrict__ knnd, const int* __restrict__ knni,
                            const double* __restrict__ sig, int* __restrict__ cnt,
                            unsigned short* __restrict__ ecolT, float* __restrict__ evalT){
  int row = blockIdx.x*256 + threadIdx.x;
  if (row >= NB*NN) return;
  int b = row >> 10;
  float sigma = (float)(sig[b] * (1.0/((double)NN*(double)NN)));
  float s2 = sigma*sigma;
  int rloc = row & (NN-1);
  #pragma unroll
  for (int j=0;j<8;j++){
    float d = knnd[row*8+j];
    int m = knni[row*8+j];
    float v = 0.5f * expf(-d/s2);
    ecolT[(size_t)j*GNN + row] = (unsigned short)m;
    evalT[(size_t)j*GNN + row] = v;
    int grow = (b<<10) + m;
    int p = atomicAdd(&cnt[grow], 1);
    if (p < WE){ ecolT[(size_t)p*GNN + grow] = (unsigned short)rloc;
                 evalT[(size_t)p*GNN + grow] = v; }
  }
}

__global__ void k_degnorm(const int* __restrict__ cnt, const float* __restrict__ evalT,
                          float* __restrict__ deg, float* __restrict__ dinv){
  int row = blockIdx.x*256 + threadIdx.x;
  if (row >= NB*NN) return;
  int c = cnt[row]; if (c > WE) c = WE;
  float s = 0.f;
  for (int j=0;j<c;j++) s += evalT[(size_t)j*GNN + row];
  deg[row] = s;
  dinv[row] = 1.0f/sqrtf(s + 1e-6f);
}

__global__ void k_normell(const int* __restrict__ cnt, const unsigned short* __restrict__ ecolT,
                          float* __restrict__ evalT, const float* __restrict__ deg,
                          const float* __restrict__ dinv, float* __restrict__ dval){
  int row = blockIdx.x*256 + threadIdx.x;
  if (row >= NB*NN) return;
  int b = row >> 10;
  const float* dv = dinv + (b<<10);
  float di = dinv[row];
  int c = cnt[row]; if (c > WE) c = WE;
  for (int j=0;j<c;j++){
    int col = ecolT[(size_t)j*GNN + row];
    evalT[(size_t)j*GNN + row] = evalT[(size_t)j*GNN + row] * (di * dv[col]);
  }
  dval[row] = di*di*deg[row];
}

// ---------------- eigensolver: init block -----------------------------------
__global__ void k_initX(const float* __restrict__ deg, float* __restrict__ X, float* __restrict__ aint){
  int idx = blockIdx.x*256+threadIdx.x;
  if (idx >= NB*NM*NN) return;
  int n = idx & (NN-1);
  int j = (idx >> 10) & (NM-1);
  int b = idx >> 15;
  float v;
  if (j == 0) v = sqrtf(deg[(b<<10)+n] + 1e-6f);   // exact 0-eigenvector of Lhat
  else {
    unsigned hsh = wanghash((unsigned)idx * 2654435761u + 12345u);
    v = ((hsh >> 8) * (1.0f/16777216.0f)) - 0.5f;
  }
  X[idx] = v;
  if (n == 0 && j == 1) aint[b] = 1.0f;
}

// ---------------- Chebyshev filter, one column per block, edges in regs ------
// grid 256: b = bid&7 (XCD-affinity), col = bid>>3. 512 thr, 2 rows/thread.
__global__ __launch_bounds__(512) void k_cheb(const int* __restrict__ cnt,
                        const unsigned short* __restrict__ ecolT,
                        const float* __restrict__ evalT, const float* __restrict__ dval,
                        float* __restrict__ X, const float* __restrict__ aint, int ndeg){
  __shared__ float bufA[NN];
  __shared__ float bufB[NN];
  int b = blockIdx.x & 7;
  int col = blockIdx.x >> 3;
  float a = aint[b];
  const float bhi = 2.0005f;
  float e  = 0.5f*(bhi - a);
  float cc = 0.5f*(bhi + a);
  float inv_e = 1.0f/e;
  const int rowbase = b << 10;
  float* Xc = X + ((size_t)b*NM + col)*NN;
  for (int n=threadIdx.x; n<NN; n+=512) bufA[n] = Xc[n];
  int r0 = threadIdx.x, r1 = threadIdx.x + 512;
  int c0 = cnt[rowbase+r0]; if (c0 > WE) c0 = WE;
  int c1 = cnt[rowbase+r1]; if (c1 > WE) c1 = WE;
  float dv0 = dval[rowbase+r0];
  float dv1 = dval[rowbase+r1];
  // load up to RSL edge slots into registers (zero-padded -> unconditional FMA)
  float ev0[RSL], ev1[RSL];
  int   ic0[RSL], ic1[RSL];
  #pragma unroll
  for (int j=0;j<RSL;j++){
    ic0[j] = (j<c0)? (int)ecolT[(size_t)j*GNN + rowbase + r0] : 0;
    ev0[j] = (j<c0)? evalT[(size_t)j*GNN + rowbase + r0] : 0.f;
    ic1[j] = (j<c1)? (int)ecolT[(size_t)j*GNN + rowbase + r1] : 0;
    ev1[j] = (j<c1)? evalT[(size_t)j*GNN + rowbase + r1] : 0.f;
  }
  int e0 = c0 - RSL; if (e0 < 0) e0 = 0;
  int e1 = c1 - RSL; if (e1 < 0) e1 = 0;
  int emax = (e0 > e1)? e0 : e1;
  const unsigned short* pe0 = ecolT + (size_t)RSL*GNN + rowbase + r0;
  const unsigned short* pe1 = ecolT + (size_t)RSL*GNN + rowbase + r1;
  const float* pv0 = evalT + (size_t)RSL*GNN + rowbase + r0;
  const float* pv1 = evalT + (size_t)RSL*GNN + rowbase + r1;
  __syncthreads();
  float* cur = bufA; float* prv = bufB;
  for (int k=0;k<ndeg;k++){
    float f = (k==0)? inv_e : 2.0f*inv_e;
    float x0 = cur[r0], x1 = cur[r1];
    float acc0 = dv0*x0, acc1 = dv1*x1;
    #pragma unroll
    for (int j=0;j<RSL;j++){
      acc0 -= ev0[j]*cur[ic0[j]];
      acc1 -= ev1[j]*cur[ic1[j]];
    }
    for (int j=0;j<emax;j++){   // rare overflow rows
      if (j < e0) acc0 -= pv0[(size_t)j*GNN] * cur[pe0[(size_t)j*GNN]];
      if (j < e1) acc1 -= pv1[(size_t)j*GNN] * cur[pe1[(size_t)j*GNN]];
    }
    float n0 = f*(acc0 - cc*x0);
    float n1 = f*(acc1 - cc*x1);
    if (k > 0){ n0 -= prv[r0]; n1 -= prv[r1]; }
    prv[r0] = n0; prv[r1] = n1;
    float* t_ = cur; cur = prv; prv = t_;
    __syncthreads();
  }
  for (int n=threadIdx.x; n<NN; n+=512) Xc[n] = cur[n];
}

// ---------------- Y = Lhat * X (one column per workgroup) --------------------
__global__ void k_spmv(const int* __restrict__ cnt, const unsigned short* __restrict__ ecolT,
                       const float* __restrict__ evalT, const float* __restrict__ dval,
                       const float* __restrict__ X, float* __restrict__ Y){
  __shared__ float xc[NN];
  int b = blockIdx.x & 7, j = blockIdx.x >> 3;
  const float* Xc = X + ((size_t)b*NM + j)*NN;
  for (int n=threadIdx.x; n<NN; n+=256) xc[n] = Xc[n];
  __syncthreads();
  int rowbase = b << 10;
  for (int r=threadIdx.x; r<NN; r+=256){
    int c = cnt[rowbase+r]; if (c > WE) c = WE;
    float acc = dval[rowbase+r]*xc[r];
    const unsigned short* pe = ecolT + rowbase + r;
    const float* pv = evalT + rowbase + r;
    for (int jj=0;jj<c;jj++){
      acc -= pv[0]*xc[pe[0]];
      pe += GNN; pv += GNN;
    }
    Y[((size_t)b*NM + j)*NN + r] = acc;
  }
}

// ---------------- G = A^T B (f64 accumulate), one row of G per wg ------------
__global__ void k_gram(const float* __restrict__ A, const float* __restrict__ Bm,
                       double* __restrict__ G){
  __shared__ float ai[NN];
  __shared__ double pd[NM][8];
  int b = blockIdx.x & 7, i = blockIdx.x >> 3;
  const float* Ac = A + ((size_t)b*NM + i)*NN;
  for (int n=threadIdx.x; n<NN; n+=256) ai[n] = Ac[n];
  __syncthreads();
  int j = threadIdx.x & 31, seg = threadIdx.x >> 5;
  const float* Bc = Bm + ((size_t)b*NM + j)*NN + seg*128;
  const float* as = ai + seg*128;
  double s = 0.0;
  for (int n=0;n<128;n++) s += (double)as[n]*(double)Bc[n];
  pd[j][seg] = s;
  __syncthreads();
  if (threadIdx.x < NM){
    double t = 0.0;
    #pragma unroll
    for (int q=0;q<8;q++) t += pd[threadIdx.x][q];
    G[((size_t)b*NM + i)*NM + threadIdx.x] = t;
  }
}

// ---------------- chol(G) -> R^{-1} (f64), upper triangular ------------------
__global__ __launch_bounds__(64) void k_cholinv(const double* __restrict__ G, double* __restrict__ Rd){
  __shared__ double L[NM][NM];
  __shared__ double Ri[NM][NM];
  int b = blockIdx.x, l = threadIdx.x;
  for (int idx=l; idx<NM*NM; idx+=64) L[idx>>5][idx&31] = G[(size_t)b*NM*NM + idx];
  __syncthreads();
  for (int k=0;k<NM;k++){
    if (l == 0){
      double orig = L[k][k];
      double s = orig;
      for (int p=0;p<k;p++) s -= L[k][p]*L[k][p];
      double floorv = orig*1e-15; if (floorv < 1e-30) floorv = 1e-30;
      if (s < floorv) s = floorv;
      L[k][k] = sqrt(s);
    }
    __syncthreads();
    if (l > k && l < NM){
      double s = L[l][k];
      for (int p=0;p<k;p++) s -= L[l][p]*L[k][p];
      L[l][k] = s / L[k][k];
    }
    __syncthreads();
  }
  if (l < NM){
    int j = l;
    Ri[j][j] = 1.0 / L[j][j];
    for (int i=j-1;i>=0;i--){
      double s = 0.0;
      for (int k2=i+1;k2<=j;k2++) s += L[k2][i]*Ri[k2][j];   // R[i][k2] = L[k2][i]
      Ri[i][j] = -s / L[i][i];
    }
  }
  __syncthreads();
  for (int idx=l; idx<NM*NM; idx+=64){
    int i = idx>>5, j = idx&31;
    Rd[(size_t)b*NM*NM + idx] = (i<=j)? Ri[i][j] : 0.0;
  }
}

// ---------------- Xout = Xin * M (f64 accumulate) ---------------------------
__global__ void k_applyd(const float* __restrict__ Xin, const double* __restrict__ Md,
                         float* __restrict__ Xout){
  __shared__ double Ms[NM*NM];
  int b = blockIdx.x >> 2;
  int n = (blockIdx.x & 3)*256 + threadIdx.x;
  for (int idx=threadIdx.x; idx<NM*NM; idx+=256) Ms[idx] = Md[(size_t)b*NM*NM + idx];
  __syncthreads();
  float xv[NM];
  #pragma unroll
  for (int j=0;j<NM;j++) xv[j] = Xin[((size_t)b*NM + j)*NN + n];
  #pragma unroll
  for (int jn=0;jn<NM;jn++){
    double acc = 0.0;
    #pragma unroll
    for (int j=0;j<NM;j++) acc += (double)xv[j] * Ms[j*NM + jn];
    Xout[((size_t)b*NM + jn)*NN + n] = (float)acc;
  }
}

// ---------------- 32x32 Jacobi eigensolver (parallel ordering) ---------------
__global__ __launch_bounds__(256) void k_jacobi(const double* __restrict__ Gd, double* __restrict__ Ud,
                         float* __restrict__ th, float* __restrict__ aint, int sweeps){
  __shared__ float S[NM][NM];
  __shared__ float V[NM][NM];
  __shared__ float cs_[16], sn_[16];
  __shared__ int pp_[16], qq_[16];
  __shared__ int perm[NM];
  __shared__ float evs[NM];
  int b = blockIdx.x, l = threadIdx.x;
  for (int idx=l; idx<NM*NM; idx+=256){
    int i = idx>>5, j = idx&31;
    S[i][j] = (float)(0.5*(Gd[(size_t)b*NM*NM + i*NM + j] + Gd[(size_t)b*NM*NM + j*NM + i]));
    V[i][j] = (i==j)? 1.0f : 0.0f;
  }
  __syncthreads();
  for (int sw=0; sw<sweeps; sw++){
    for (int r=0; r<31; r++){
      if (l < 16){
        int p, q;
        if (l == 0){ p = r; q = 31; }
        else { p = (r + l) % 31; q = (r + 31 - l) % 31; }
        if (p > q){ int t_=p; p=q; q=t_; }
        float apq = S[p][q];
        float c = 1.0f, s = 0.0f;
        if (fabsf(apq) > 1e-30f){
          float tau = (S[q][q] - S[p][p]) / (2.0f*apq);
          float tt = (tau >= 0.f ? 1.0f : -1.0f) / (fabsf(tau) + sqrtf(1.0f + tau*tau));
          c = 1.0f/sqrtf(1.0f + tt*tt); s = tt*c;
        }
        cs_[l]=c; sn_[l]=s; pp_[l]=p; qq_[l]=q;
      }
      __syncthreads();
      for (int tsk=l; tsk<512; tsk+=256){
        int i = tsk >> 4, kk = tsk & 15;
        int p = pp_[kk], q = qq_[kk];
        float c = cs_[kk], s = sn_[kk];
        float sp = S[i][p], sq = S[i][q];
        S[i][p] = c*sp - s*sq; S[i][q] = s*sp + c*sq;
        float vp = V[i][p], vq = V[i][q];
        V[i][p] = c*vp - s*vq; V[i][q] = s*vp + c*vq;
      }
      __syncthreads();
      for (int tsk=l; tsk<512; tsk+=256){
        int jc = tsk >> 4, kk = tsk & 15;
        int p = pp_[kk], q = qq_[kk];
        float c = cs_[kk], s = sn_[kk];
        float sp = S[p][jc], sq = S[q][jc];
        S[p][jc] = c*sp - s*sq; S[q][jc] = s*sp + c*sq;
      }
      __syncthreads();
    }
  }
  if (l == 0){
    for (int i=0;i<NM;i++){ perm[i]=i; evs[i]=S[i][i]; }
    for (int i=0;i<NM;i++){
      int mi = i;
      for (int j=i+1;j<NM;j++) if (evs[perm[j]] < evs[perm[mi]]) mi = j;
      int t_=perm[i]; perm[i]=perm[mi]; perm[mi]=t_;
    }
    for (int i=0;i<NM;i++) th[b*NM+i] = evs[perm[i]];
    float a = evs[perm[NM-1]]*1.02f + 1e-4f;
    aint[b] = fminf(fmaxf(a, 0.02f), 1.5f);   // cap 1.5: keep T_24 in f32 range
  }
  __syncthreads();
  for (int idx=l; idx<NM*NM; idx+=256){
    int i = idx>>5, j = idx&31;
    Ud[(size_t)b*NM*NM + i*NM + j] = (double)V[i][perm[j]];
  }
}

// ---------------- xs[b][k][t][c] = sum_n X[b][k][n] * h[b][n][t][c] ----------
__global__ __launch_bounds__(256) void k_project(const float* __restrict__ X, const float* __restrict__ h,
                          float* __restrict__ xs){
  __shared__ float xc[NN];
  int b = blockIdx.x >> 4, k = blockIdx.x & 15;
  const float* Xc = X + ((size_t)b*NM + k)*NN;
  for (int n=threadIdx.x; n<NN; n+=256) xc[n] = Xc[n];
  __syncthreads();
  const float* hb = h + (size_t)b*NN*NT*NC;
  int s0 = threadIdx.x, s1 = threadIdx.x + 256, s2 = threadIdx.x + 512;
  bool ok2 = (s2 < NT*NC);
  float a0=0.f, a1=0.f, a2=0.f;
  for (int n=0;n<NN;n++){
    float xv = xc[n];
    const float* hr = hb + (size_t)n*NT*NC;
    a0 += xv*hr[s0];
    a1 += xv*hr[s1];
    if (ok2) a2 += xv*hr[s2];
  }
  float* o = xs + ((size_t)b*NK + k)*NT*NC;
  o[s0] = a0; o[s1] = a1;
  if (ok2) o[s2] = a2;
}

// ---------------- rfft(:4) -> complex channel mix -> irfft -------------------
__global__ __launch_bounds__(64) void k_timefilter(const float* __restrict__ xs, const float* __restrict__ fwr,
                             const float* __restrict__ fwi, float* __restrict__ osb, int layer){
  __shared__ float xst[NT*NC];
  __shared__ float xfr[NC][NMT];
  __shared__ float xfi[NC][NMT];
  int b = blockIdx.x >> 4, k = blockIdx.x & 15;
  const float* xin = xs + ((size_t)b*NK + k)*NT*NC;
  for (int idx=threadIdx.x; idx<NT*NC; idx+=64) xst[idx] = xin[idx];
  __syncthreads();
  int l = threadIdx.x;
  if (l < NC){
    float ar0=0,ar1=0,ar2=0,ar3=0, ai1=0,ai2=0,ai3=0;
    for (int t=0;t<NT;t++){
      float v = xst[t*NC + l];
      float w1 = 0.31415926535897932f * (float)t;  // 2*pi*t/20
      ar0 += v;
      ar1 += v*cosf(w1);       ai1 -= v*sinf(w1);
      ar2 += v*cosf(2.f*w1);   ai2 -= v*sinf(2.f*w1);
      ar3 += v*cosf(3.f*w1);   ai3 -= v*sinf(3.f*w1);
    }
    xfr[l][0]=ar0; xfi[l][0]=0.f;
    xfr[l][1]=ar1; xfi[l][1]=ai1;
    xfr[l][2]=ar2; xfi[l][2]=ai2;
    xfr[l][3]=ar3; xfi[l][3]=ai3;
  }
  __syncthreads();
  if (l < NC){
    int o = l;
    float ofr[NMT], ofi[NMT];
    #pragma unroll
    for (int f=0; f<NMT; f++){ ofr[f]=0.f; ofi[f]=0.f; }
    for (int i=0;i<NC;i++){
      size_t wbase = ((((size_t)layer*NC + i)*NC + o)*NK + k)*NMT;
      #pragma unroll
      for (int f=0; f<NMT; f++){
        float wr = fwr[wbase+f], wi2 = fwi[wbase+f];
        float xr = xfr[i][f], xi = xfi[i][f];
        ofr[f] += xr*wr - xi*wi2;
        ofi[f] += xr*wi2 + xi*wr;
      }
    }
    float* outp = osb + ((size_t)b*NK + k)*NT*NC;
    for (int t=0;t<NT;t++){
      float w1 = 0.31415926535897932f * (float)t;
      float acc = ofr[0];
      acc += 2.f*(ofr[1]*cosf(w1)     - ofi[1]*sinf(w1));
      acc += 2.f*(ofr[2]*cosf(2.f*w1) - ofi[2]*sinf(2.f*w1));
      acc += 2.f*(ofr[3]*cosf(3.f*w1) - ofi[3]*sinf(3.f*w1));
      outp[t*NC + o] = acc * 0.05f;
    }
  }
}

// ---------------- h' = basis*os + cw*h + cb, gelu (layers 0..2) --------------
__global__ __launch_bounds__(256) void k_update(const float* __restrict__ X, const float* __restrict__ osb,
                         const float* __restrict__ h, const float* __restrict__ cw,
                         const float* __restrict__ cb, float* __restrict__ hout, int layer){
  __shared__ float os_s[NK*NT*NC];   // 40KB
  __shared__ float cwT[NC*NC];
  __shared__ float Xl[NK][64];
  __shared__ float cbs[NC];
  int b = blockIdx.x >> 4;
  int n0 = (blockIdx.x & 15)*64;
  for (int idx=threadIdx.x; idx<NK*NT*NC; idx+=256) os_s[idx] = osb[(size_t)b*NK*NT*NC + idx];
  for (int idx=threadIdx.x; idx<NC*NC; idx+=256){
    int o = idx/NC, i = idx%NC;
    cwT[i*NC + o] = cw[((size_t)layer*NC + o)*NC + i];
  }
  if (threadIdx.x < NC) cbs[threadIdx.x] = cb[layer*NC + threadIdx.x];
  for (int idx=threadIdx.x; idx<NK*64; idx+=256){
    int k = idx >> 6, nl = idx & 63;
    Xl[k][nl] = X[((size_t)b*NM + k)*NN + n0 + nl];
  }
  __syncthreads();
  for (int tsk=threadIdx.x; tsk<64*NT; tsk+=256){
    int t = tsk % NT, nl = tsk / NT;
    int n = n0 + nl;
    const float* hr = h + (((size_t)b*NN + n)*NT + t)*NC;
    float acc[NC];
    #pragma unroll
    for (int o=0;o<NC;o++) acc[o] = cbs[o];
    #pragma unroll
    for (int k=0;k<NK;k++){
      float xv = Xl[k][nl];
      const float* osr = os_s + (k*NT + t)*NC;
      #pragma unroll
      for (int o=0;o<NC;o++) acc[o] += xv*osr[o];
    }
    for (int i=0;i<NC;i++){
      float hv = hr[i];
      const float* cwr = cwT + i*NC;
      #pragma unroll
      for (int o=0;o<NC;o++) acc[o] += hv*cwr[o];
    }
    float* outp = hout + (((size_t)b*NN + n)*NT + t)*NC;
    if (layer < 3){
      #pragma unroll
      for (int o=0;o<NC;o++) outp[o] = gelu_f(acc[o]);
    } else {
      #pragma unroll
      for (int o=0;o<NC;o++) outp[o] = acc[o];
    }
  }
}

// ---------------- head: gelu(h@q1w+q1b)@q2w + q2b ----------------------------
__global__ __launch_bounds__(256) void k_head(const float* __restrict__ h, const float* __restrict__ q1w,
                       const float* __restrict__ q1b, const float* __restrict__ q2w,
                       const float* __restrict__ q2b, float* __restrict__ out){
  __shared__ float w1[NC*NQ];
  __shared__ float b1[NQ], w2[NQ];
  for (int idx=threadIdx.x; idx<NC*NQ; idx+=256) w1[idx] = q1w[idx];
  if (threadIdx.x < NQ){ b1[threadIdx.x] = q1b[threadIdx.x]; w2[threadIdx.x] = q2w[threadIdx.x]; }
  __syncthreads();
  int idx = blockIdx.x*256 + threadIdx.x;
  if (idx >= NB*NN*NT) return;
  const float* hr = h + (size_t)idx*NC;
  float hv[NC];
  #pragma unroll
  for (int i=0;i<NC;i++) hv[i] = hr[i];
  float res = q2b[0];
  for (int j=0;j<NQ;j++){
    float z = b1[j];
    #pragma unroll
    for (int i=0;i<NC;i++) z += hv[i]*w1[i*NQ + j];
    res += gelu_f(z)*w2[j];
  }
  out[idx] = res;
}

// ============================================================================
extern "C" void kernel_launch(void* const* d_in, const int* in_sizes, int n_in,
                              void* d_out, int out_size, void* d_ws, size_t ws_size,
                              hipStream_t stream){
  (void)in_sizes; (void)n_in; (void)out_size;
  const float* x   = (const float*)d_in[0];
  const float* pos = (const float*)d_in[1];
  const float* Wp  = (const float*)d_in[2];
  const float* bp  = (const float*)d_in[3];
  const float* fwr = (const float*)d_in[4];
  const float* fwi = (const float*)d_in[5];
  const float* cw  = (const float*)d_in[6];
  const float* cb  = (const float*)d_in[7];
  const float* q1w = (const float*)d_in[8];
  const float* q1b = (const float*)d_in[9];
  const float* q2w = (const float*)d_in[10];
  const float* q2b = (const float*)d_in[11];

  char* p = (char*)d_ws;
  auto take = [&](size_t bytes)->void*{
    void* r = (void*)p;
    p += (bytes + 255) & ~(size_t)255;
    return r;
  };
  float*  hA    = (float*) take(sizeof(float)*NB*NN*NT*NC);
  float*  hB    = (float*) take(sizeof(float)*NB*NN*NT*NC);
  float*  knnd  = (float*) take(sizeof(float)*NB*NN*8);
  int*    knni  = (int*)   take(sizeof(int)*NB*NN*8);
  double* sig   = (double*)take(sizeof(double)*NB);
  int*    cntb  = (int*)   take(sizeof(int)*NB*NN);
  unsigned short* ecolT = (unsigned short*) take(sizeof(unsigned short)*(size_t)GNN*WE);
  float*  evalT = (float*) take(sizeof(float)*(size_t)GNN*WE);
  float*  deg   = (float*) take(sizeof(float)*NB*NN);
  float*  dinv  = (float*) take(sizeof(float)*NB*NN);
  float*  dval  = (float*) take(sizeof(float)*NB*NN);
  float*  Xb    = (float*) take(sizeof(float)*NB*NM*NN);
  float*  Yb    = (float*) take(sizeof(float)*NB*NM*NN);
  double* Gd    = (double*)take(sizeof(double)*NB*NM*NM);
  double* Rd    = (double*)take(sizeof(double)*NB*NM*NM);
  double* Ud    = (double*)take(sizeof(double)*NB*NM*NM);
  float*  th    = (float*) take(sizeof(float)*NB*NM);
  float*  aint  = (float*) take(sizeof(float)*NB);
  float*  xs    = (float*) take(sizeof(float)*NB*NK*NT*NC);
  float*  osb   = (float*) take(sizeof(float)*NB*NK*NT*NC);
  if ((size_t)(p - (char*)d_ws) > ws_size) return;  // ws too small -> loud failure

  k_build_h0<<<(NB*NN*NT*NC+255)/256, 256, 0, stream>>>(x, pos, Wp, bp, hA);

  static const int RDEG[5] = {12, 24, 24, 24, 24};
  float* hcur = hA; float* hnext = hB;
  for (int layer=0; layer<4; layer++){
    hipMemsetAsync(sig, 0, sizeof(double)*NB, stream);
    k_dist_knn<<<NB*NN/4, 256, 0, stream>>>(hcur, knnd, knni, sig, cntb);
    k_build_ell<<<NB*NN/256, 256, 0, stream>>>(knnd, knni, sig, cntb, ecolT, evalT);
    k_degnorm<<<NB*NN/256, 256, 0, stream>>>(cntb, evalT, deg, dinv);
    k_normell<<<NB*NN/256, 256, 0, stream>>>(cntb, ecolT, evalT, deg, dinv, dval);
    k_initX<<<NB*NM*NN/256, 256, 0, stream>>>(deg, Xb, aint);
    float* cur = Xb; float* oth = Yb;
    for (int r=0; r<5; r++){
      k_cheb<<<NB*NM, 512, 0, stream>>>(cntb, ecolT, evalT, dval, cur, aint, RDEG[r]);
      k_gram<<<NB*NM, 256, 0, stream>>>(cur, cur, Gd);
      k_cholinv<<<NB, 64, 0, stream>>>(Gd, Rd);
      k_applyd<<<NB*4, 256, 0, stream>>>(cur, Rd, oth);
      { float* t_ = cur; cur = oth; oth = t_; }
      if (r == 0 || r == 4){
        k_spmv<<<NB*NM, 256, 0, stream>>>(cntb, ecolT, evalT, dval, cur, oth);
        k_gram<<<NB*NM, 256, 0, stream>>>(cur, oth, Gd);
        k_jacobi<<<NB, 256, 0, stream>>>(Gd, Ud, th, aint, (r==4)?2:4);
        k_applyd<<<NB*4, 256, 0, stream>>>(cur, Ud, oth);
        { float* t_ = cur; cur = oth; oth = t_; }
      }
    }
    k_project<<<NB*NK, 256, 0, stream>>>(cur, hcur, xs);
    k_timefilter<<<NB*NK, 64, 0, stream>>>(xs, fwr, fwi, osb, layer);
    k_update<<<NB*16, 256, 0, stream>>>(cur, osb, hcur, cw, cb, hnext, layer);
    { float* t_ = hcur; hcur = hnext; hnext = t_; }
  }
  k_head<<<(NB*NN*NT+255)/256, 256, 0, stream>>>(hcur, q1w, q1b, q2w, q2b, (float*)d_out);
}

// Round 4
// 4631.907 us; speedup vs baseline: 3.3949x; 1.4587x over previous
//
#include <hip/hip_runtime.h>

#define NB 8
#define NN 1024
#define NC 32
#define NT 20
#define NTI 10
#define NM 32     // iteration block size (16 wanted + 16 guard)
#define NK 16     // K_SPACE
#define NMT 4     // M_TIME
#define WE 64     // ELL width (max entries per row)
#define NQ 128
#define GNN (NB*NN)
#define RSL 24    // edge slots held in registers in k_cheb
#define PTC 16    // tc per block in k_project
#define PSEG 16   // n-segments in k_project

__device__ __forceinline__ float gelu_f(float x){
  return 0.5f * x * (1.0f + erff(x * 0.70710678118654752f));
}
__device__ __forceinline__ unsigned wanghash(unsigned s){
  s = (s ^ 61u) ^ (s >> 16); s *= 9u; s ^= s >> 4; s *= 0x27d4eb2du; s ^= s >> 15;
  return s;
}

// ---------------- initial lift: h[b][n][t][c] = concat(x,pos,t) @ Wp + bp ----
__global__ void k_build_h0(const float* __restrict__ x, const float* __restrict__ pos,
                           const float* __restrict__ Wp, const float* __restrict__ bp,
                           float* __restrict__ h){
  int idx = blockIdx.x*256 + threadIdx.x;
  if (idx >= NB*NN*NT*NC) return;
  int c = idx & (NC-1);
  int t = (idx/NC) % NT;
  int n = (idx/(NC*NT)) & (NN-1);
  int b = idx/(NC*NT*NN);
  const float* xr = x + (b*NN + n)*NTI;
  float acc = bp[c];
  #pragma unroll
  for (int i=0;i<NTI;i++) acc += xr[i]*Wp[i*NC+c];
  acc += pos[(b*NN+n)*2+0]*Wp[10*NC+c];
  acc += pos[(b*NN+n)*2+1]*Wp[11*NC+c];
  float tv = (float)(10+t) * (1.0f/29.0f);
  acc += tv*Wp[12*NC+c];
  h[idx] = acc;
}

// ---------------- fused pairwise distance + top-8 kNN + sigma sum ------------
__global__ __launch_bounds__(256) void k_dist_knn(const float* __restrict__ h,
                           float* __restrict__ knnd, int* __restrict__ knni,
                           double* __restrict__ sig, int* __restrict__ cnt){
  __shared__ float fr_s[4][NC];
  int wave = threadIdx.x >> 6;
  int lane = threadIdx.x & 63;
  int row = blockIdx.x*4 + wave;       // global row over NB*NN
  int b = row >> 10;
  if (threadIdx.x < 4*NC){
    int w = threadIdx.x >> 5, c = threadIdx.x & 31;
    int rr = blockIdx.x*4 + w;
    fr_s[w][c] = h[((size_t)rr*NT)*NC + c];
  }
  __syncthreads();
  float fr[NC];
  #pragma unroll
  for (int c=0;c<NC;c++) fr[c] = fr_s[wave][c];
  float d8[8]; int i8[8];
  #pragma unroll
  for (int j=0;j<8;j++){ d8[j]=1e30f; i8[j]=0x3fffffff; }
  double ssum = 0.0;
  const float* fb = h + (size_t)b*NN*NT*NC;
  for (int m=lane; m<NN; m+=64){
    const float* fm = fb + (size_t)m*NT*NC;
    float d2 = 0.f;
    #pragma unroll
    for (int c=0;c<NC;c++){ float df = fr[c]-fm[c]; d2 += df*df; }
    float d = sqrtf(d2);
    ssum += (double)d;
    if (d < d8[7] || (d == d8[7] && m < i8[7])){
      d8[7] = d; i8[7] = m;
      #pragma unroll
      for (int j=6;j>=0;j--){
        bool sw = (d8[j+1] < d8[j]) || (d8[j+1]==d8[j] && i8[j+1]<i8[j]);
        if (sw){ float td=d8[j]; d8[j]=d8[j+1]; d8[j+1]=td;
                 int ti=i8[j]; i8[j]=i8[j+1]; i8[j+1]=ti; }
      }
    }
  }
  #pragma unroll
  for (int off=32; off>0; off>>=1) ssum += __shfl_down(ssum, off);
  if (lane==0){ atomicAdd(&sig[b], ssum); cnt[row] = 8; }
  // merge per-lane sorted top-8 lists: 8x wave-argmin extraction
  int ptr = 0;
  for (int sel=0; sel<8; sel++){
    float dv = 1e30f; int iv = 0x3fffffff;
    #pragma unroll
    for (int j=0;j<8;j++) if (j==ptr){ dv=d8[j]; iv=i8[j]; }
    float bd = dv; int bi = iv;
    #pragma unroll
    for (int off=32; off>0; off>>=1){
      float od = __shfl_xor(bd, off);
      int oi = __shfl_xor(bi, off);
      if (od < bd || (od == bd && oi < bi)){ bd = od; bi = oi; }
    }
    if (dv == bd && iv == bi) ptr++;
    if (lane == sel){ knnd[row*8+sel] = bd; knni[row*8+sel] = bi; }
  }
}

// ---------------- symmetrized sparse A in transposed ELL form ----------------
__global__ void k_build_ell(const float* __restrict__ knnd, const int* __restrict__ knni,
                            const double* __restrict__ sig, int* __restrict__ cnt,
                            unsigned short* __restrict__ ecolT, float* __restrict__ evalT){
  int row = blockIdx.x*256 + threadIdx.x;
  if (row >= NB*NN) return;
  int b = row >> 10;
  float sigma = (float)(sig[b] * (1.0/((double)NN*(double)NN)));
  float s2 = sigma*sigma;
  int rloc = row & (NN-1);
  #pragma unroll
  for (int j=0;j<8;j++){
    float d = knnd[row*8+j];
    int m = knni[row*8+j];
    float v = 0.5f * expf(-d/s2);
    ecolT[(size_t)j*GNN + row] = (unsigned short)m;
    evalT[(size_t)j*GNN + row] = v;
    int grow = (b<<10) + m;
    int p = atomicAdd(&cnt[grow], 1);
    if (p < WE){ ecolT[(size_t)p*GNN + grow] = (unsigned short)rloc;
                 evalT[(size_t)p*GNN + grow] = v; }
  }
}

__global__ void k_degnorm(const int* __restrict__ cnt, const float* __restrict__ evalT,
                          float* __restrict__ deg, float* __restrict__ dinv){
  int row = blockIdx.x*256 + threadIdx.x;
  if (row >= NB*NN) return;
  int c = cnt[row]; if (c > WE) c = WE;
  float s = 0.f;
  for (int j=0;j<c;j++) s += evalT[(size_t)j*GNN + row];
  deg[row] = s;
  dinv[row] = 1.0f/sqrtf(s + 1e-6f);
}

__global__ void k_normell(const int* __restrict__ cnt, const unsigned short* __restrict__ ecolT,
                          float* __restrict__ evalT, const float* __restrict__ deg,
                          const float* __restrict__ dinv, float* __restrict__ dval){
  int row = blockIdx.x*256 + threadIdx.x;
  if (row >= NB*NN) return;
  int b = row >> 10;
  const float* dv = dinv + (b<<10);
  float di = dinv[row];
  int c = cnt[row]; if (c > WE) c = WE;
  for (int j=0;j<c;j++){
    int col = ecolT[(size_t)j*GNN + row];
    evalT[(size_t)j*GNN + row] = evalT[(size_t)j*GNN + row] * (di * dv[col]);
  }
  dval[row] = di*di*deg[row];
}

// ---------------- eigensolver: init block -----------------------------------
__global__ void k_initX(const float* __restrict__ deg, float* __restrict__ X, float* __restrict__ aint){
  int idx = blockIdx.x*256+threadIdx.x;
  if (idx >= NB*NM*NN) return;
  int n = idx & (NN-1);
  int j = (idx >> 10) & (NM-1);
  int b = idx >> 15;
  float v;
  if (j == 0) v = sqrtf(deg[(b<<10)+n] + 1e-6f);   // exact 0-eigenvector of Lhat
  else {
    unsigned hsh = wanghash((unsigned)idx * 2654435761u + 12345u);
    v = ((hsh >> 8) * (1.0f/16777216.0f)) - 0.5f;
  }
  X[idx] = v;
  if (n == 0 && j == 1) aint[b] = 1.0f;
}

// ---------------- Chebyshev filter, one column per block, edges in regs ------
// grid 256: b = bid&7 (XCD-affinity), col = bid>>3. 512 thr, 2 rows/thread.
__global__ __launch_bounds__(512) void k_cheb(const int* __restrict__ cnt,
                        const unsigned short* __restrict__ ecolT,
                        const float* __restrict__ evalT, const float* __restrict__ dval,
                        float* __restrict__ X, const float* __restrict__ aint, int ndeg){
  __shared__ float bufA[NN];
  __shared__ float bufB[NN];
  int b = blockIdx.x & 7;
  int col = blockIdx.x >> 3;
  float a = aint[b];
  const float bhi = 2.0005f;
  float e  = 0.5f*(bhi - a);
  float cc = 0.5f*(bhi + a);
  float inv_e = 1.0f/e;
  const int rowbase = b << 10;
  float* Xc = X + ((size_t)b*NM + col)*NN;
  for (int n=threadIdx.x; n<NN; n+=512) bufA[n] = Xc[n];
  int r0 = threadIdx.x, r1 = threadIdx.x + 512;
  int c0 = cnt[rowbase+r0]; if (c0 > WE) c0 = WE;
  int c1 = cnt[rowbase+r1]; if (c1 > WE) c1 = WE;
  float dv0 = dval[rowbase+r0];
  float dv1 = dval[rowbase+r1];
  // load up to RSL edge slots into registers (zero-padded -> unconditional FMA)
  float ev0[RSL], ev1[RSL];
  int   ic0[RSL], ic1[RSL];
  #pragma unroll
  for (int j=0;j<RSL;j++){
    ic0[j] = (j<c0)? (int)ecolT[(size_t)j*GNN + rowbase + r0] : 0;
    ev0[j] = (j<c0)? evalT[(size_t)j*GNN + rowbase + r0] : 0.f;
    ic1[j] = (j<c1)? (int)ecolT[(size_t)j*GNN + rowbase + r1] : 0;
    ev1[j] = (j<c1)? evalT[(size_t)j*GNN + rowbase + r1] : 0.f;
  }
  int e0 = c0 - RSL; if (e0 < 0) e0 = 0;
  int e1 = c1 - RSL; if (e1 < 0) e1 = 0;
  int emax = (e0 > e1)? e0 : e1;
  const unsigned short* pe0 = ecolT + (size_t)RSL*GNN + rowbase + r0;
  const unsigned short* pe1 = ecolT + (size_t)RSL*GNN + rowbase + r1;
  const float* pv0 = evalT + (size_t)RSL*GNN + rowbase + r0;
  const float* pv1 = evalT + (size_t)RSL*GNN + rowbase + r1;
  __syncthreads();
  float* cur = bufA; float* prv = bufB;
  for (int k=0;k<ndeg;k++){
    float f = (k==0)? inv_e : 2.0f*inv_e;
    float x0 = cur[r0], x1 = cur[r1];
    float acc0 = dv0*x0, acc1 = dv1*x1;
    #pragma unroll
    for (int j=0;j<RSL;j++){
      acc0 -= ev0[j]*cur[ic0[j]];
      acc1 -= ev1[j]*cur[ic1[j]];
    }
    for (int j=0;j<emax;j++){   // rare overflow rows
      if (j < e0) acc0 -= pv0[(size_t)j*GNN] * cur[pe0[(size_t)j*GNN]];
      if (j < e1) acc1 -= pv1[(size_t)j*GNN] * cur[pe1[(size_t)j*GNN]];
    }
    float n0 = f*(acc0 - cc*x0);
    float n1 = f*(acc1 - cc*x1);
    if (k > 0){ n0 -= prv[r0]; n1 -= prv[r1]; }
    prv[r0] = n0; prv[r1] = n1;
    float* t_ = cur; cur = prv; prv = t_;
    __syncthreads();
  }
  for (int n=threadIdx.x; n<NN; n+=512) Xc[n] = cur[n];
}

// ---------------- Y = Lhat * X (one column per workgroup) --------------------
__global__ void k_spmv(const int* __restrict__ cnt, const unsigned short* __restrict__ ecolT,
                       const float* __restrict__ evalT, const float* __restrict__ dval,
                       const float* __restrict__ X, float* __restrict__ Y){
  __shared__ float xc[NN];
  int b = blockIdx.x & 7, j = blockIdx.x >> 3;
  const float* Xc = X + ((size_t)b*NM + j)*NN;
  for (int n=threadIdx.x; n<NN; n+=256) xc[n] = Xc[n];
  __syncthreads();
  int rowbase = b << 10;
  for (int r=threadIdx.x; r<NN; r+=256){
    int c = cnt[rowbase+r]; if (c > WE) c = WE;
    float acc = dval[rowbase+r]*xc[r];
    const unsigned short* pe = ecolT + rowbase + r;
    const float* pv = evalT + rowbase + r;
    for (int jj=0;jj<c;jj++){
      acc -= pv[0]*xc[pe[0]];
      pe += GNN; pv += GNN;
    }
    Y[((size_t)b*NM + j)*NN + r] = acc;
  }
}

// ---------------- G = A^T B (f64 accumulate), one row of G per wg ------------
__global__ void k_gram(const float* __restrict__ A, const float* __restrict__ Bm,
                       double* __restrict__ G){
  __shared__ float ai[NN];
  __shared__ double pd[NM][8];
  int b = blockIdx.x & 7, i = blockIdx.x >> 3;
  const float* Ac = A + ((size_t)b*NM + i)*NN;
  for (int n=threadIdx.x; n<NN; n+=256) ai[n] = Ac[n];
  __syncthreads();
  int j = threadIdx.x & 31, seg = threadIdx.x >> 5;
  const float* Bc = Bm + ((size_t)b*NM + j)*NN + seg*128;
  const float* as = ai + seg*128;
  double s = 0.0;
  for (int n=0;n<128;n++) s += (double)as[n]*(double)Bc[n];
  pd[j][seg] = s;
  __syncthreads();
  if (threadIdx.x < NM){
    double t = 0.0;
    #pragma unroll
    for (int q=0;q<8;q++) t += pd[threadIdx.x][q];
    G[((size_t)b*NM + i)*NM + threadIdx.x] = t;
  }
}

// ---------------- chol(G) -> R^{-1} (f64), upper triangular ------------------
__global__ __launch_bounds__(64) void k_cholinv(const double* __restrict__ G, double* __restrict__ Rd){
  __shared__ double L[NM][NM];
  __shared__ double Ri[NM][NM];
  int b = blockIdx.x, l = threadIdx.x;
  for (int idx=l; idx<NM*NM; idx+=64) L[idx>>5][idx&31] = G[(size_t)b*NM*NM + idx];
  __syncthreads();
  for (int k=0;k<NM;k++){
    if (l == 0){
      double orig = L[k][k];
      double s = orig;
      for (int p=0;p<k;p++) s -= L[k][p]*L[k][p];
      double floorv = orig*1e-15; if (floorv < 1e-30) floorv = 1e-30;
      if (s < floorv) s = floorv;
      L[k][k] = sqrt(s);
    }
    __syncthreads();
    if (l > k && l < NM){
      double s = L[l][k];
      for (int p=0;p<k;p++) s -= L[l][p]*L[k][p];
      L[l][k] = s / L[k][k];
    }
    __syncthreads();
  }
  if (l < NM){
    int j = l;
    Ri[j][j] = 1.0 / L[j][j];
    for (int i=j-1;i>=0;i--){
      double s = 0.0;
      for (int k2=i+1;k2<=j;k2++) s += L[k2][i]*Ri[k2][j];   // R[i][k2] = L[k2][i]
      Ri[i][j] = -s / L[i][i];
    }
  }
  __syncthreads();
  for (int idx=l; idx<NM*NM; idx+=64){
    int i = idx>>5, j = idx&31;
    Rd[(size_t)b*NM*NM + idx] = (i<=j)? Ri[i][j] : 0.0;
  }
}

// ---------------- Xout = Xin * M (f64 accumulate) ---------------------------
__global__ void k_applyd(const float* __restrict__ Xin, const double* __restrict__ Md,
                         float* __restrict__ Xout){
  __shared__ double Ms[NM*NM];
  int b = blockIdx.x >> 2;
  int n = (blockIdx.x & 3)*256 + threadIdx.x;
  for (int idx=threadIdx.x; idx<NM*NM; idx+=256) Ms[idx] = Md[(size_t)b*NM*NM + idx];
  __syncthreads();
  float xv[NM];
  #pragma unroll
  for (int j=0;j<NM;j++) xv[j] = Xin[((size_t)b*NM + j)*NN + n];
  #pragma unroll
  for (int jn=0;jn<NM;jn++){
    double acc = 0.0;
    #pragma unroll
    for (int j=0;j<NM;j++) acc += (double)xv[j] * Ms[j*NM + jn];
    Xout[((size_t)b*NM + jn)*NN + n] = (float)acc;
  }
}

// ---------------- 32x32 Jacobi eigensolver (parallel ordering) ---------------
__global__ __launch_bounds__(256) void k_jacobi(const double* __restrict__ Gd, double* __restrict__ Ud,
                         float* __restrict__ th, float* __restrict__ aint, int sweeps){
  __shared__ float S[NM][NM];
  __shared__ float V[NM][NM];
  __shared__ float cs_[16], sn_[16];
  __shared__ int pp_[16], qq_[16];
  __shared__ int perm[NM];
  __shared__ float evs[NM];
  int b = blockIdx.x, l = threadIdx.x;
  for (int idx=l; idx<NM*NM; idx+=256){
    int i = idx>>5, j = idx&31;
    S[i][j] = (float)(0.5*(Gd[(size_t)b*NM*NM + i*NM + j] + Gd[(size_t)b*NM*NM + j*NM + i]));
    V[i][j] = (i==j)? 1.0f : 0.0f;
  }
  __syncthreads();
  for (int sw=0; sw<sweeps; sw++){
    for (int r=0; r<31; r++){
      if (l < 16){
        int p, q;
        if (l == 0){ p = r; q = 31; }
        else { p = (r + l) % 31; q = (r + 31 - l) % 31; }
        if (p > q){ int t_=p; p=q; q=t_; }
        float apq = S[p][q];
        float c = 1.0f, s = 0.0f;
        if (fabsf(apq) > 1e-30f){
          float tau = (S[q][q] - S[p][p]) / (2.0f*apq);
          float tt = (tau >= 0.f ? 1.0f : -1.0f) / (fabsf(tau) + sqrtf(1.0f + tau*tau));
          c = 1.0f/sqrtf(1.0f + tt*tt); s = tt*c;
        }
        cs_[l]=c; sn_[l]=s; pp_[l]=p; qq_[l]=q;
      }
      __syncthreads();
      for (int tsk=l; tsk<512; tsk+=256){
        int i = tsk >> 4, kk = tsk & 15;
        int p = pp_[kk], q = qq_[kk];
        float c = cs_[kk], s = sn_[kk];
        float sp = S[i][p], sq = S[i][q];
        S[i][p] = c*sp - s*sq; S[i][q] = s*sp + c*sq;
        float vp = V[i][p], vq = V[i][q];
        V[i][p] = c*vp - s*vq; V[i][q] = s*vp + c*vq;
      }
      __syncthreads();
      for (int tsk=l; tsk<512; tsk+=256){
        int jc = tsk >> 4, kk = tsk & 15;
        int p = pp_[kk], q = qq_[kk];
        float c = cs_[kk], s = sn_[kk];
        float sp = S[p][jc], sq = S[q][jc];
        S[p][jc] = c*sp - s*sq; S[q][jc] = s*sp + c*sq;
      }
      __syncthreads();
    }
  }
  if (l == 0){
    for (int i=0;i<NM;i++){ perm[i]=i; evs[i]=S[i][i]; }
    for (int i=0;i<NM;i++){
      int mi = i;
      for (int j=i+1;j<NM;j++) if (evs[perm[j]] < evs[perm[mi]]) mi = j;
      int t_=perm[i]; perm[i]=perm[mi]; perm[mi]=t_;
    }
    for (int i=0;i<NM;i++) th[b*NM+i] = evs[perm[i]];
    float a = evs[perm[NM-1]]*1.02f + 1e-4f;
    aint[b] = fminf(fmaxf(a, 0.02f), 1.5f);   // cap 1.5: keep T_24 in f32 range
  }
  __syncthreads();
  for (int idx=l; idx<NM*NM; idx+=256){
    int i = idx>>5, j = idx&31;
    Ud[(size_t)b*NM*NM + i*NM + j] = (double)V[i][perm[j]];
  }
}

// ---------------- xs[b][k][tc] = sum_n X[b][k][n] * h[b][n][tc] --------------
// grid NB*40: b=bid&7, chunk=bid>>3 (16 tc each). h read exactly once overall.
__global__ __launch_bounds__(256) void k_project(const float* __restrict__ X, const float* __restrict__ h,
                          float* __restrict__ xs){
  __shared__ float Xs[NK][NN];             // 64KB
  __shared__ float red[PSEG][NK][PTC+1];   // ~17KB
  int b = blockIdx.x & 7;
  int chunk = blockIdx.x >> 3;             // 0..39
  int tc0 = chunk * PTC;
  for (int idx=threadIdx.x; idx<NK*NN; idx+=256){
    int k = idx >> 10, n = idx & (NN-1);
    Xs[k][n] = X[((size_t)b*NM + k)*NN + n];
  }
  __syncthreads();
  int tcl = threadIdx.x & (PTC-1);
  int seg = threadIdx.x >> 4;              // 0..15
  const float* hb = h + (size_t)b*NN*NT*NC + tc0 + tcl;
  float acc[NK];
  #pragma unroll
  for (int k=0;k<NK;k++) acc[k]=0.f;
  int n0 = seg*(NN/PSEG);
  for (int n=n0; n<n0+(NN/PSEG); n++){
    float v = hb[(size_t)n*NT*NC];
    #pragma unroll
    for (int k=0;k<NK;k++) acc[k] += Xs[k][n]*v;
  }
  #pragma unroll
  for (int k=0;k<NK;k++) red[seg][k][tcl] = acc[k];
  __syncthreads();
  int k = threadIdx.x >> 4;
  int t2 = threadIdx.x & (PTC-1);
  float s = 0.f;
  #pragma unroll
  for (int q=0;q<PSEG;q++) s += red[q][k][t2];
  xs[((size_t)b*NK + k)*NT*NC + tc0 + t2] = s;
}

// ---------------- rfft(:4) -> complex channel mix -> irfft -------------------
__global__ __launch_bounds__(64) void k_timefilter(const float* __restrict__ xs, const float* __restrict__ fwr,
                             const float* __restrict__ fwi, float* __restrict__ osb, int layer){
  __shared__ float xst[NT*NC];
  __shared__ float xfr[NC][NMT];
  __shared__ float xfi[NC][NMT];
  int b = blockIdx.x >> 4, k = blockIdx.x & 15;
  const float* xin = xs + ((size_t)b*NK + k)*NT*NC;
  for (int idx=threadIdx.x; idx<NT*NC; idx+=64) xst[idx] = xin[idx];
  __syncthreads();
  int l = threadIdx.x;
  if (l < NC){
    float ar0=0,ar1=0,ar2=0,ar3=0, ai1=0,ai2=0,ai3=0;
    for (int t=0;t<NT;t++){
      float v = xst[t*NC + l];
      float w1 = 0.31415926535897932f * (float)t;  // 2*pi*t/20
      ar0 += v;
      ar1 += v*cosf(w1);       ai1 -= v*sinf(w1);
      ar2 += v*cosf(2.f*w1);   ai2 -= v*sinf(2.f*w1);
      ar3 += v*cosf(3.f*w1);   ai3 -= v*sinf(3.f*w1);
    }
    xfr[l][0]=ar0; xfi[l][0]=0.f;
    xfr[l][1]=ar1; xfi[l][1]=ai1;
    xfr[l][2]=ar2; xfi[l][2]=ai2;
    xfr[l][3]=ar3; xfi[l][3]=ai3;
  }
  __syncthreads();
  if (l < NC){
    int o = l;
    float ofr[NMT], ofi[NMT];
    #pragma unroll
    for (int f=0; f<NMT; f++){ ofr[f]=0.f; ofi[f]=0.f; }
    for (int i=0;i<NC;i++){
      size_t wbase = ((((size_t)layer*NC + i)*NC + o)*NK + k)*NMT;
      #pragma unroll
      for (int f=0; f<NMT; f++){
        float wr = fwr[wbase+f], wi2 = fwi[wbase+f];
        float xr = xfr[i][f], xi = xfi[i][f];
        ofr[f] += xr*wr - xi*wi2;
        ofi[f] += xr*wi2 + xi*wr;
      }
    }
    float* outp = osb + ((size_t)b*NK + k)*NT*NC;
    for (int t=0;t<NT;t++){
      float w1 = 0.31415926535897932f * (float)t;
      float acc = ofr[0];
      acc += 2.f*(ofr[1]*cosf(w1)     - ofi[1]*sinf(w1));
      acc += 2.f*(ofr[2]*cosf(2.f*w1) - ofi[2]*sinf(2.f*w1));
      acc += 2.f*(ofr[3]*cosf(3.f*w1) - ofi[3]*sinf(3.f*w1));
      outp[t*NC + o] = acc * 0.05f;
    }
  }
}

// ---------------- h' = basis*os + cw*h + cb, gelu (layers 0..2) --------------
// grid NB*32: b=bid&7, chunk=bid>>3, 32 nodes per chunk
__global__ __launch_bounds__(256) void k_update(const float* __restrict__ X, const float* __restrict__ osb,
                         const float* __restrict__ h, const float* __restrict__ cw,
                         const float* __restrict__ cb, float* __restrict__ hout, int layer){
  __shared__ float os_s[NK*NT*NC];   // 40KB
  __shared__ float cwT[NC*NC];
  __shared__ float Xl[NK][32];
  __shared__ float cbs[NC];
  int b = blockIdx.x & 7;
  int n0 = (blockIdx.x >> 3)*32;
  for (int idx=threadIdx.x; idx<NK*NT*NC; idx+=256) os_s[idx] = osb[(size_t)b*NK*NT*NC + idx];
  for (int idx=threadIdx.x; idx<NC*NC; idx+=256){
    int o = idx/NC, i = idx%NC;
    cwT[i*NC + o] = cw[((size_t)layer*NC + o)*NC + i];
  }
  if (threadIdx.x < NC) cbs[threadIdx.x] = cb[layer*NC + threadIdx.x];
  for (int idx=threadIdx.x; idx<NK*32; idx+=256){
    int k = idx >> 5, nl = idx & 31;
    Xl[k][nl] = X[((size_t)b*NM + k)*NN + n0 + nl];
  }
  __syncthreads();
  for (int tsk=threadIdx.x; tsk<32*NT; tsk+=256){
    int t = tsk % NT, nl = tsk / NT;
    int n = n0 + nl;
    const float* hr = h + (((size_t)b*NN + n)*NT + t)*NC;
    float acc[NC];
    #pragma unroll
    for (int o=0;o<NC;o++) acc[o] = cbs[o];
    #pragma unroll
    for (int k=0;k<NK;k++){
      float xv = Xl[k][nl];
      const float* osr = os_s + (k*NT + t)*NC;
      #pragma unroll
      for (int o=0;o<NC;o++) acc[o] += xv*osr[o];
    }
    for (int i=0;i<NC;i++){
      float hv = hr[i];
      const float* cwr = cwT + i*NC;
      #pragma unroll
      for (int o=0;o<NC;o++) acc[o] += hv*cwr[o];
    }
    float* outp = hout + (((size_t)b*NN + n)*NT + t)*NC;
    if (layer < 3){
      #pragma unroll
      for (int o=0;o<NC;o++) outp[o] = gelu_f(acc[o]);
    } else {
      #pragma unroll
      for (int o=0;o<NC;o++) outp[o] = acc[o];
    }
  }
}

// ---------------- head: gelu(h@q1w+q1b)@q2w + q2b ----------------------------
__global__ __launch_bounds__(256) void k_head(const float* __restrict__ h, const float* __restrict__ q1w,
                       const float* __restrict__ q1b, const float* __restrict__ q2w,
                       const float* __restrict__ q2b, float* __restrict__ out){
  __shared__ float w1[NC*NQ];
  __shared__ float b1[NQ], w2[NQ];
  for (int idx=threadIdx.x; idx<NC*NQ; idx+=256) w1[idx] = q1w[idx];
  if (threadIdx.x < NQ){ b1[threadIdx.x] = q1b[threadIdx.x]; w2[threadIdx.x] = q2w[threadIdx.x]; }
  __syncthreads();
  int idx = blockIdx.x*256 + threadIdx.x;
  if (idx >= NB*NN*NT) return;
  const float* hr = h + (size_t)idx*NC;
  float hv[NC];
  #pragma unroll
  for (int i=0;i<NC;i++) hv[i] = hr[i];
  float res = q2b[0];
  for (int j=0;j<NQ;j++){
    float z = b1[j];
    #pragma unroll
    for (int i=0;i<NC;i++) z += hv[i]*w1[i*NQ + j];
    res += gelu_f(z)*w2[j];
  }
  out[idx] = res;
}

// ============================================================================
extern "C" void kernel_launch(void* const* d_in, const int* in_sizes, int n_in,
                              void* d_out, int out_size, void* d_ws, size_t ws_size,
                              hipStream_t stream){
  (void)in_sizes; (void)n_in; (void)out_size;
  const float* x   = (const float*)d_in[0];
  const float* pos = (const float*)d_in[1];
  const float* Wp  = (const float*)d_in[2];
  const float* bp  = (const float*)d_in[3];
  const float* fwr = (const float*)d_in[4];
  const float* fwi = (const float*)d_in[5];
  const float* cw  = (const float*)d_in[6];
  const float* cb  = (const float*)d_in[7];
  const float* q1w = (const float*)d_in[8];
  const float* q1b = (const float*)d_in[9];
  const float* q2w = (const float*)d_in[10];
  const float* q2b = (const float*)d_in[11];

  char* p = (char*)d_ws;
  auto take = [&](size_t bytes)->void*{
    void* r = (void*)p;
    p += (bytes + 255) & ~(size_t)255;
    return r;
  };
  float*  hA    = (float*) take(sizeof(float)*NB*NN*NT*NC);
  float*  hB    = (float*) take(sizeof(float)*NB*NN*NT*NC);
  float*  knnd  = (float*) take(sizeof(float)*NB*NN*8);
  int*    knni  = (int*)   take(sizeof(int)*NB*NN*8);
  double* sig   = (double*)take(sizeof(double)*NB);
  int*    cntb  = (int*)   take(sizeof(int)*NB*NN);
  unsigned short* ecolT = (unsigned short*) take(sizeof(unsigned short)*(size_t)GNN*WE);
  float*  evalT = (float*) take(sizeof(float)*(size_t)GNN*WE);
  float*  deg   = (float*) take(sizeof(float)*NB*NN);
  float*  dinv  = (float*) take(sizeof(float)*NB*NN);
  float*  dval  = (float*) take(sizeof(float)*NB*NN);
  float*  Xb    = (float*) take(sizeof(float)*NB*NM*NN);
  float*  Yb    = (float*) take(sizeof(float)*NB*NM*NN);
  double* Gd    = (double*)take(sizeof(double)*NB*NM*NM);
  double* Rd    = (double*)take(sizeof(double)*NB*NM*NM);
  double* Ud    = (double*)take(sizeof(double)*NB*NM*NM);
  float*  th    = (float*) take(sizeof(float)*NB*NM);
  float*  aint  = (float*) take(sizeof(float)*NB);
  float*  xs    = (float*) take(sizeof(float)*NB*NK*NT*NC);
  float*  osb   = (float*) take(sizeof(float)*NB*NK*NT*NC);
  if ((size_t)(p - (char*)d_ws) > ws_size) return;  // ws too small -> loud failure

  k_build_h0<<<(NB*NN*NT*NC+255)/256, 256, 0, stream>>>(x, pos, Wp, bp, hA);

  static const int RDEG[4] = {12, 24, 24, 24};
  float* hcur = hA; float* hnext = hB;
  for (int layer=0; layer<4; layer++){
    hipMemsetAsync(sig, 0, sizeof(double)*NB, stream);
    k_dist_knn<<<NB*NN/4, 256, 0, stream>>>(hcur, knnd, knni, sig, cntb);
    k_build_ell<<<NB*NN/256, 256, 0, stream>>>(knnd, knni, sig, cntb, ecolT, evalT);
    k_degnorm<<<NB*NN/256, 256, 0, stream>>>(cntb, evalT, deg, dinv);
    k_normell<<<NB*NN/256, 256, 0, stream>>>(cntb, ecolT, evalT, deg, dinv, dval);
    k_initX<<<NB*NM*NN/256, 256, 0, stream>>>(deg, Xb, aint);
    float* cur = Xb; float* oth = Yb;
    for (int r=0; r<4; r++){
      k_cheb<<<NB*NM, 512, 0, stream>>>(cntb, ecolT, evalT, dval, cur, aint, RDEG[r]);
      k_gram<<<NB*NM, 256, 0, stream>>>(cur, cur, Gd);
      k_cholinv<<<NB, 64, 0, stream>>>(Gd, Rd);
      k_applyd<<<NB*4, 256, 0, stream>>>(cur, Rd, oth);
      { float* t_ = cur; cur = oth; oth = t_; }
      if (r == 0){
        // Ritz values only (adapt Chebyshev interval); in-span rotation skipped
        k_spmv<<<NB*NM, 256, 0, stream>>>(cntb, ecolT, evalT, dval, cur, oth);
        k_gram<<<NB*NM, 256, 0, stream>>>(cur, oth, Gd);
        k_jacobi<<<NB, 256, 0, stream>>>(Gd, Ud, th, aint, 2);
      }
      if (r == 3){
        k_spmv<<<NB*NM, 256, 0, stream>>>(cntb, ecolT, evalT, dval, cur, oth);
        k_gram<<<NB*NM, 256, 0, stream>>>(cur, oth, Gd);
        k_jacobi<<<NB, 256, 0, stream>>>(Gd, Ud, th, aint, 2);
        k_applyd<<<NB*4, 256, 0, stream>>>(cur, Ud, oth);
        { float* t_ = cur; cur = oth; oth = t_; }
      }
    }
    k_project<<<NB*40, 256, 0, stream>>>(cur, hcur, xs);
    k_timefilter<<<NB*NK, 64, 0, stream>>>(xs, fwr, fwi, osb, layer);
    k_update<<<NB*32, 256, 0, stream>>>(cur, osb, hcur, cw, cb, hnext, layer);
    { float* t_ = hcur; hcur = hnext; hnext = t_; }
  }
  k_head<<<(NB*NN*NT+255)/256, 256, 0, stream>>>(hcur, q1w, q1b, q2w, q2b, (float*)d_out);
}

// Round 5
// 4234.315 us; speedup vs baseline: 3.7137x; 1.0939x over previous
//
#include <hip/hip_runtime.h>

#define NB 8
#define NN 1024
#define NC 32
#define NT 20
#define NTI 10
#define NM 32     // iteration block size (16 wanted + 16 guard)
#define NK 16     // K_SPACE
#define NMT 4     // M_TIME
#define WE 64     // ELL width (max entries per row)
#define NQ 128
#define GNN (NB*NN)
#define RSL 24    // edge slots held in registers in k_cheb
#define PTC 16    // tc per block in k_project
#define PSEG 16   // n-segments in k_project

__device__ __forceinline__ float gelu_f(float x){
  return 0.5f * x * (1.0f + erff(x * 0.70710678118654752f));
}
__device__ __forceinline__ unsigned wanghash(unsigned s){
  s = (s ^ 61u) ^ (s >> 16); s *= 9u; s ^= s >> 4; s *= 0x27d4eb2du; s ^= s >> 15;
  return s;
}

// ---------------- initial lift: h[b][n][t][c] = concat(x,pos,t) @ Wp + bp ----
__global__ void k_build_h0(const float* __restrict__ x, const float* __restrict__ pos,
                           const float* __restrict__ Wp, const float* __restrict__ bp,
                           float* __restrict__ h){
  int idx = blockIdx.x*256 + threadIdx.x;
  if (idx >= NB*NN*NT*NC) return;
  int c = idx & (NC-1);
  int t = (idx/NC) % NT;
  int n = (idx/(NC*NT)) & (NN-1);
  int b = idx/(NC*NT*NN);
  const float* xr = x + (b*NN + n)*NTI;
  float acc = bp[c];
  #pragma unroll
  for (int i=0;i<NTI;i++) acc += xr[i]*Wp[i*NC+c];
  acc += pos[(b*NN+n)*2+0]*Wp[10*NC+c];
  acc += pos[(b*NN+n)*2+1]*Wp[11*NC+c];
  float tv = (float)(10+t) * (1.0f/29.0f);
  acc += tv*Wp[12*NC+c];
  h[idx] = acc;
}

// ---------------- fused pairwise distance + top-8 kNN + sigma sum ------------
// 4 rows per block (wave each); candidate features staged in LDS transposed.
__global__ __launch_bounds__(256) void k_dist_knn(const float* __restrict__ h,
                           float* __restrict__ knnd, int* __restrict__ knni,
                           double* __restrict__ sig, int* __restrict__ cnt){
  __shared__ float fr_s[4][NC];
  __shared__ float fT[NC][257];     // candidate tile transposed, padded
  int wave = threadIdx.x >> 6;
  int lane = threadIdx.x & 63;
  int row = blockIdx.x*4 + wave;       // global row over NB*NN
  int b = row >> 10;
  if (threadIdx.x < 4*NC){
    int w = threadIdx.x >> 5, c = threadIdx.x & 31;
    int rr = blockIdx.x*4 + w;
    fr_s[w][c] = h[((size_t)rr*NT)*NC + c];
  }
  __syncthreads();
  float fr[NC];
  #pragma unroll
  for (int c=0;c<NC;c++) fr[c] = fr_s[wave][c];
  float d8[8]; int i8[8];
  #pragma unroll
  for (int j=0;j<8;j++){ d8[j]=1e30f; i8[j]=0x3fffffff; }
  double ssum = 0.0;
  const float* fb = h + (size_t)b*NN*NT*NC;
  int cload = threadIdx.x & 31, mr = threadIdx.x >> 5;
  for (int tile=0; tile<4; tile++){
    int m0 = tile*256;
    __syncthreads();
    #pragma unroll
    for (int p=0; p<32; p++){
      int ml = p*8 + mr;
      fT[cload][ml] = fb[(size_t)(m0+ml)*NT*NC + cload];
    }
    __syncthreads();
    float d2q[4] = {0.f,0.f,0.f,0.f};
    #pragma unroll
    for (int c=0;c<NC;c++){
      float fc = fr[c];
      const float* rowp = &fT[c][lane];
      float df0 = fc - rowp[0];
      float df1 = fc - rowp[64];
      float df2 = fc - rowp[128];
      float df3 = fc - rowp[192];
      d2q[0] += df0*df0; d2q[1] += df1*df1; d2q[2] += df2*df2; d2q[3] += df3*df3;
    }
    #pragma unroll
    for (int q=0;q<4;q++){
      int m = m0 + q*64 + lane;
      float d = sqrtf(d2q[q]);
      ssum += (double)d;
      if (d < d8[7] || (d == d8[7] && m < i8[7])){
        d8[7] = d; i8[7] = m;
        #pragma unroll
        for (int j=6;j>=0;j--){
          bool sw = (d8[j+1] < d8[j]) || (d8[j+1]==d8[j] && i8[j+1]<i8[j]);
          if (sw){ float td=d8[j]; d8[j]=d8[j+1]; d8[j+1]=td;
                   int ti=i8[j]; i8[j]=i8[j+1]; i8[j+1]=ti; }
        }
      }
    }
  }
  #pragma unroll
  for (int off=32; off>0; off>>=1) ssum += __shfl_down(ssum, off);
  if (lane==0){ atomicAdd(&sig[b], ssum); cnt[row] = 8; }
  // merge per-lane sorted top-8 lists: 8x wave-argmin extraction
  int ptr = 0;
  for (int sel=0; sel<8; sel++){
    float dv = 1e30f; int iv = 0x3fffffff;
    #pragma unroll
    for (int j=0;j<8;j++) if (j==ptr){ dv=d8[j]; iv=i8[j]; }
    float bd = dv; int bi = iv;
    #pragma unroll
    for (int off=32; off>0; off>>=1){
      float od = __shfl_xor(bd, off);
      int oi = __shfl_xor(bi, off);
      if (od < bd || (od == bd && oi < bi)){ bd = od; bi = oi; }
    }
    if (dv == bd && iv == bi) ptr++;
    if (lane == sel){ knnd[row*8+sel] = bd; knni[row*8+sel] = bi; }
  }
}

// ---------------- symmetrized sparse A in transposed ELL form ----------------
__global__ void k_build_ell(const float* __restrict__ knnd, const int* __restrict__ knni,
                            const double* __restrict__ sig, int* __restrict__ cnt,
                            unsigned short* __restrict__ ecolT, float* __restrict__ evalT){
  int row = blockIdx.x*256 + threadIdx.x;
  if (row >= NB*NN) return;
  int b = row >> 10;
  float sigma = (float)(sig[b] * (1.0/((double)NN*(double)NN)));
  float s2 = sigma*sigma;
  int rloc = row & (NN-1);
  #pragma unroll
  for (int j=0;j<8;j++){
    float d = knnd[row*8+j];
    int m = knni[row*8+j];
    float v = 0.5f * expf(-d/s2);
    ecolT[(size_t)j*GNN + row] = (unsigned short)m;
    evalT[(size_t)j*GNN + row] = v;
    int grow = (b<<10) + m;
    int p = atomicAdd(&cnt[grow], 1);
    if (p < WE){ ecolT[(size_t)p*GNN + grow] = (unsigned short)rloc;
                 evalT[(size_t)p*GNN + grow] = v; }
  }
}

__global__ void k_degnorm(const int* __restrict__ cnt, const float* __restrict__ evalT,
                          float* __restrict__ deg, float* __restrict__ dinv){
  int row = blockIdx.x*256 + threadIdx.x;
  if (row >= NB*NN) return;
  int c = cnt[row]; if (c > WE) c = WE;
  float s = 0.f;
  for (int j=0;j<c;j++) s += evalT[(size_t)j*GNN + row];
  deg[row] = s;
  dinv[row] = 1.0f/sqrtf(s + 1e-6f);
}

__global__ void k_normell(const int* __restrict__ cnt, const unsigned short* __restrict__ ecolT,
                          float* __restrict__ evalT, const float* __restrict__ deg,
                          const float* __restrict__ dinv, float* __restrict__ dval){
  int row = blockIdx.x*256 + threadIdx.x;
  if (row >= NB*NN) return;
  int b = row >> 10;
  const float* dv = dinv + (b<<10);
  float di = dinv[row];
  int c = cnt[row]; if (c > WE) c = WE;
  for (int j=0;j<c;j++){
    int col = ecolT[(size_t)j*GNN + row];
    evalT[(size_t)j*GNN + row] = evalT[(size_t)j*GNN + row] * (di * dv[col]);
  }
  dval[row] = di*di*deg[row];
}

// ---------------- eigensolver: init block -----------------------------------
__global__ void k_initX(const float* __restrict__ deg, float* __restrict__ X, float* __restrict__ aint){
  int idx = blockIdx.x*256+threadIdx.x;
  if (idx >= NB*NM*NN) return;
  int n = idx & (NN-1);
  int j = (idx >> 10) & (NM-1);
  int b = idx >> 15;
  float v;
  if (j == 0) v = sqrtf(deg[(b<<10)+n] + 1e-6f);   // exact 0-eigenvector of Lhat
  else {
    unsigned hsh = wanghash((unsigned)idx * 2654435761u + 12345u);
    v = ((hsh >> 8) * (1.0f/16777216.0f)) - 0.5f;
  }
  X[idx] = v;
  if (n == 0 && j == 1) aint[b] = 1.0f;
}

// ---------------- Chebyshev filter, one column per block, edges in regs ------
__global__ __launch_bounds__(512) void k_cheb(const int* __restrict__ cnt,
                        const unsigned short* __restrict__ ecolT,
                        const float* __restrict__ evalT, const float* __restrict__ dval,
                        float* __restrict__ X, const float* __restrict__ aint, int ndeg){
  __shared__ float bufA[NN];
  __shared__ float bufB[NN];
  int b = blockIdx.x & 7;
  int col = blockIdx.x >> 3;
  float a = aint[b];
  const float bhi = 2.0005f;
  float e  = 0.5f*(bhi - a);
  float cc = 0.5f*(bhi + a);
  float inv_e = 1.0f/e;
  const int rowbase = b << 10;
  float* Xc = X + ((size_t)b*NM + col)*NN;
  for (int n=threadIdx.x; n<NN; n+=512) bufA[n] = Xc[n];
  int r0 = threadIdx.x, r1 = threadIdx.x + 512;
  int c0 = cnt[rowbase+r0]; if (c0 > WE) c0 = WE;
  int c1 = cnt[rowbase+r1]; if (c1 > WE) c1 = WE;
  float dv0 = dval[rowbase+r0];
  float dv1 = dval[rowbase+r1];
  float ev0[RSL], ev1[RSL];
  int   ic0[RSL], ic1[RSL];
  #pragma unroll
  for (int j=0;j<RSL;j++){
    ic0[j] = (j<c0)? (int)ecolT[(size_t)j*GNN + rowbase + r0] : 0;
    ev0[j] = (j<c0)? evalT[(size_t)j*GNN + rowbase + r0] : 0.f;
    ic1[j] = (j<c1)? (int)ecolT[(size_t)j*GNN + rowbase + r1] : 0;
    ev1[j] = (j<c1)? evalT[(size_t)j*GNN + rowbase + r1] : 0.f;
  }
  int e0 = c0 - RSL; if (e0 < 0) e0 = 0;
  int e1 = c1 - RSL; if (e1 < 0) e1 = 0;
  int emax = (e0 > e1)? e0 : e1;
  const unsigned short* pe0 = ecolT + (size_t)RSL*GNN + rowbase + r0;
  const unsigned short* pe1 = ecolT + (size_t)RSL*GNN + rowbase + r1;
  const float* pv0 = evalT + (size_t)RSL*GNN + rowbase + r0;
  const float* pv1 = evalT + (size_t)RSL*GNN + rowbase + r1;
  __syncthreads();
  float* cur = bufA; float* prv = bufB;
  for (int k=0;k<ndeg;k++){
    float f = (k==0)? inv_e : 2.0f*inv_e;
    float x0 = cur[r0], x1 = cur[r1];
    float acc0 = dv0*x0, acc1 = dv1*x1;
    #pragma unroll
    for (int j=0;j<RSL;j++){
      acc0 -= ev0[j]*cur[ic0[j]];
      acc1 -= ev1[j]*cur[ic1[j]];
    }
    for (int j=0;j<emax;j++){   // rare overflow rows
      if (j < e0) acc0 -= pv0[(size_t)j*GNN] * cur[pe0[(size_t)j*GNN]];
      if (j < e1) acc1 -= pv1[(size_t)j*GNN] * cur[pe1[(size_t)j*GNN]];
    }
    float n0 = f*(acc0 - cc*x0);
    float n1 = f*(acc1 - cc*x1);
    if (k > 0){ n0 -= prv[r0]; n1 -= prv[r1]; }
    prv[r0] = n0; prv[r1] = n1;
    float* t_ = cur; cur = prv; prv = t_;
    __syncthreads();
  }
  for (int n=threadIdx.x; n<NN; n+=512) Xc[n] = cur[n];
}

// ---------------- Y = Lhat * X (one column per workgroup) --------------------
__global__ void k_spmv(const int* __restrict__ cnt, const unsigned short* __restrict__ ecolT,
                       const float* __restrict__ evalT, const float* __restrict__ dval,
                       const float* __restrict__ X, float* __restrict__ Y){
  __shared__ float xc[NN];
  int b = blockIdx.x & 7, j = blockIdx.x >> 3;
  const float* Xc = X + ((size_t)b*NM + j)*NN;
  for (int n=threadIdx.x; n<NN; n+=256) xc[n] = Xc[n];
  __syncthreads();
  int rowbase = b << 10;
  for (int r=threadIdx.x; r<NN; r+=256){
    int c = cnt[rowbase+r]; if (c > WE) c = WE;
    float acc = dval[rowbase+r]*xc[r];
    const unsigned short* pe = ecolT + rowbase + r;
    const float* pv = evalT + rowbase + r;
    for (int jj=0;jj<c;jj++){
      acc -= pv[0]*xc[pe[0]];
      pe += GNN; pv += GNN;
    }
    Y[((size_t)b*NM + j)*NN + r] = acc;
  }
}

// ---------------- G = A^T B (f64 accumulate), one row of G per wg ------------
__global__ void k_gram(const float* __restrict__ A, const float* __restrict__ Bm,
                       double* __restrict__ G){
  __shared__ float ai[NN];
  __shared__ double pd[NM][8];
  int b = blockIdx.x & 7, i = blockIdx.x >> 3;
  const float* Ac = A + ((size_t)b*NM + i)*NN;
  for (int n=threadIdx.x; n<NN; n+=256) ai[n] = Ac[n];
  __syncthreads();
  int j = threadIdx.x & 31, seg = threadIdx.x >> 5;
  const float* Bc = Bm + ((size_t)b*NM + j)*NN + seg*128;
  const float* as = ai + seg*128;
  double s = 0.0;
  for (int n=0;n<128;n++) s += (double)as[n]*(double)Bc[n];
  pd[j][seg] = s;
  __syncthreads();
  if (threadIdx.x < NM){
    double t = 0.0;
    #pragma unroll
    for (int q=0;q<8;q++) t += pd[threadIdx.x][q];
    G[((size_t)b*NM + i)*NM + threadIdx.x] = t;
  }
}

// ---------------- fused chol(G)->R^{-1}->apply quarter of nodes --------------
__global__ __launch_bounds__(256) void k_cholapply(const double* __restrict__ G,
                        const float* __restrict__ Xin, float* __restrict__ Xout,
                        float* __restrict__ aint, int reset){
  __shared__ double L[NM][NM];
  __shared__ double Ri[NM][NM];
  int b = blockIdx.x >> 2;
  int quarter = blockIdx.x & 3;
  int tid = threadIdx.x;
  for (int idx=tid; idx<NM*NM; idx+=256) L[idx>>5][idx&31] = G[(size_t)b*NM*NM + idx];
  __syncthreads();
  for (int k=0;k<NM;k++){
    if (tid == 0){
      double orig = L[k][k];
      double s = orig;
      for (int p=0;p<k;p++) s -= L[k][p]*L[k][p];
      double floorv = orig*1e-15; if (floorv < 1e-30) floorv = 1e-30;
      if (s < floorv) s = floorv;
      L[k][k] = sqrt(s);
    }
    __syncthreads();
    if (tid > k && tid < NM){
      double s = L[tid][k];
      for (int p=0;p<k;p++) s -= L[tid][p]*L[k][p];
      L[tid][k] = s / L[k][k];
    }
    __syncthreads();
  }
  if (tid < NM){
    int j = tid;
    Ri[j][j] = 1.0 / L[j][j];
    for (int i=j-1;i>=0;i--){
      double s = 0.0;
      for (int k2=i+1;k2<=j;k2++) s += L[k2][i]*Ri[k2][j];
      Ri[i][j] = -s / L[i][i];
    }
  }
  __syncthreads();
  int n = quarter*256 + tid;
  float xv[NM];
  #pragma unroll
  for (int j=0;j<NM;j++) xv[j] = Xin[((size_t)b*NM + j)*NN + n];
  for (int jn=0;jn<NM;jn++){
    double acc = 0.0;
    for (int j=0;j<=jn;j++) acc += (double)xv[j] * Ri[j][jn];
    Xout[((size_t)b*NM + jn)*NN + n] = (float)acc;
  }
  if (reset && quarter==0 && tid==0) aint[b] = 0.02f;
}

// ---------------- fused spmv + Gram row + Gershgorin interval bound ----------
// one block per (b, j): y_j = Lhat x_j; G[j][i] = x_i . y_j; aint[b] = max row bound
__global__ __launch_bounds__(256) void k_spmv_gersh(const int* __restrict__ cnt,
                        const unsigned short* __restrict__ ecolT,
                        const float* __restrict__ evalT, const float* __restrict__ dval,
                        const float* __restrict__ X, float* __restrict__ aint){
  __shared__ float xc[NN];
  __shared__ float yc[NN];
  __shared__ double pd[NM][8];
  int b = blockIdx.x & 7, j = blockIdx.x >> 3;
  const float* Xc = X + ((size_t)b*NM + j)*NN;
  for (int n=threadIdx.x; n<NN; n+=256) xc[n] = Xc[n];
  __syncthreads();
  int rowbase = b << 10;
  for (int r=threadIdx.x; r<NN; r+=256){
    int c = cnt[rowbase+r]; if (c > WE) c = WE;
    float acc = dval[rowbase+r]*xc[r];
    const unsigned short* pe = ecolT + rowbase + r;
    const float* pv = evalT + rowbase + r;
    for (int jj=0;jj<c;jj++){
      acc -= pv[0]*xc[pe[0]];
      pe += GNN; pv += GNN;
    }
    yc[r] = acc;
  }
  __syncthreads();
  int i = threadIdx.x >> 3, seg = threadIdx.x & 7;
  const float* Xi = X + ((size_t)b*NM + i)*NN + seg*128;
  const float* ys = yc + seg*128;
  double s = 0.0;
  for (int k=0;k<128;k++) s += (double)Xi[k]*(double)ys[k];
  pd[i][seg] = s;
  __syncthreads();
  if (threadIdx.x < NM){
    double g = 0.0;
    #pragma unroll
    for (int q=0;q<8;q++) g += pd[threadIdx.x][q];
    double contrib = (threadIdx.x==j)? g : fabs(g);
    #pragma unroll
    for (int off=16; off>0; off>>=1) contrib += __shfl_down(contrib, off, 32);
    if (threadIdx.x == 0){
      float av = (float)contrib*1.02f + 1e-4f;
      av = fminf(fmaxf(av, 0.02f), 1.5f);
      atomicMax((unsigned int*)&aint[b], __float_as_uint(av));
    }
  }
}

// ---------------- fused 32x32 Jacobi + sorted rotation apply -----------------
__global__ __launch_bounds__(256) void k_jacobi_apply(const double* __restrict__ Gd,
                        const float* __restrict__ Xin, float* __restrict__ Xout, int sweeps){
  __shared__ float S[NM][NM];
  __shared__ float V[NM][NM];
  __shared__ float Vp[NM][NM];
  __shared__ float cs_[16], sn_[16];
  __shared__ int pp_[16], qq_[16];
  __shared__ int perm[NM];
  __shared__ float evs[NM];
  int b = blockIdx.x, l = threadIdx.x;
  for (int idx=l; idx<NM*NM; idx+=256){
    int i = idx>>5, j = idx&31;
    S[i][j] = (float)(0.5*(Gd[(size_t)b*NM*NM + i*NM + j] + Gd[(size_t)b*NM*NM + j*NM + i]));
    V[i][j] = (i==j)? 1.0f : 0.0f;
  }
  __syncthreads();
  for (int sw=0; sw<sweeps; sw++){
    for (int r=0; r<31; r++){
      if (l < 16){
        int p, q;
        if (l == 0){ p = r; q = 31; }
        else { p = (r + l) % 31; q = (r + 31 - l) % 31; }
        if (p > q){ int t_=p; p=q; q=t_; }
        float apq = S[p][q];
        float c = 1.0f, s = 0.0f;
        if (fabsf(apq) > 1e-30f){
          float tau = (S[q][q] - S[p][p]) / (2.0f*apq);
          float tt = (tau >= 0.f ? 1.0f : -1.0f) / (fabsf(tau) + sqrtf(1.0f + tau*tau));
          c = 1.0f/sqrtf(1.0f + tt*tt); s = tt*c;
        }
        cs_[l]=c; sn_[l]=s; pp_[l]=p; qq_[l]=q;
      }
      __syncthreads();
      for (int tsk=l; tsk<512; tsk+=256){
        int i = tsk >> 4, kk = tsk & 15;
        int p = pp_[kk], q = qq_[kk];
        float c = cs_[kk], s = sn_[kk];
        float sp = S[i][p], sq = S[i][q];
        S[i][p] = c*sp - s*sq; S[i][q] = s*sp + c*sq;
        float vp = V[i][p], vq = V[i][q];
        V[i][p] = c*vp - s*vq; V[i][q] = s*vp + c*vq;
      }
      __syncthreads();
      for (int tsk=l; tsk<512; tsk+=256){
        int jc = tsk >> 4, kk = tsk & 15;
        int p = pp_[kk], q = qq_[kk];
        float c = cs_[kk], s = sn_[kk];
        float sp = S[p][jc], sq = S[q][jc];
        S[p][jc] = c*sp - s*sq; S[q][jc] = s*sp + c*sq;
      }
      __syncthreads();
    }
  }
  if (l == 0){
    for (int i=0;i<NM;i++){ perm[i]=i; evs[i]=S[i][i]; }
    for (int i=0;i<NM;i++){
      int mi = i;
      for (int j=i+1;j<NM;j++) if (evs[perm[j]] < evs[perm[mi]]) mi = j;
      int t_=perm[i]; perm[i]=perm[mi]; perm[mi]=t_;
    }
  }
  __syncthreads();
  for (int idx=l; idx<NM*NM; idx+=256){
    int i = idx>>5, j = idx&31;
    Vp[i][j] = V[i][perm[j]];
  }
  __syncthreads();
  for (int nl=l; nl<NN; nl+=256){
    float xv[NM];
    #pragma unroll
    for (int j=0;j<NM;j++) xv[j] = Xin[((size_t)b*NM + j)*NN + nl];
    #pragma unroll
    for (int jn=0;jn<NM;jn++){
      float acc = 0.f;
      #pragma unroll
      for (int j=0;j<NM;j++) acc += xv[j]*Vp[j][jn];
      Xout[((size_t)b*NM + jn)*NN + nl] = acc;
    }
  }
}

// ---------------- xs[b][k][tc] = sum_n X[b][k][n] * h[b][n][tc] --------------
__global__ __launch_bounds__(256) void k_project(const float* __restrict__ X, const float* __restrict__ h,
                          float* __restrict__ xs){
  __shared__ float Xs[NK][NN];             // 64KB
  __shared__ float red[PSEG][NK][PTC+1];   // ~17KB
  int b = blockIdx.x & 7;
  int chunk = blockIdx.x >> 3;             // 0..39
  int tc0 = chunk * PTC;
  for (int idx=threadIdx.x; idx<NK*NN; idx+=256){
    int k = idx >> 10, n = idx & (NN-1);
    Xs[k][n] = X[((size_t)b*NM + k)*NN + n];
  }
  __syncthreads();
  int tcl = threadIdx.x & (PTC-1);
  int seg = threadIdx.x >> 4;              // 0..15
  const float* hb = h + (size_t)b*NN*NT*NC + tc0 + tcl;
  float acc[NK];
  #pragma unroll
  for (int k=0;k<NK;k++) acc[k]=0.f;
  int n0 = seg*(NN/PSEG);
  for (int n=n0; n<n0+(NN/PSEG); n++){
    float v = hb[(size_t)n*NT*NC];
    #pragma unroll
    for (int k=0;k<NK;k++) acc[k] += Xs[k][n]*v;
  }
  #pragma unroll
  for (int k=0;k<NK;k++) red[seg][k][tcl] = acc[k];
  __syncthreads();
  int k = threadIdx.x >> 4;
  int t2 = threadIdx.x & (PTC-1);
  float s = 0.f;
  #pragma unroll
  for (int q=0;q<PSEG;q++) s += red[q][k][t2];
  xs[((size_t)b*NK + k)*NT*NC + tc0 + t2] = s;
}

// ---------------- rfft(:4) -> complex channel mix -> irfft -------------------
__global__ __launch_bounds__(64) void k_timefilter(const float* __restrict__ xs, const float* __restrict__ fwr,
                             const float* __restrict__ fwi, float* __restrict__ osb, int layer){
  __shared__ float xst[NT*NC];
  __shared__ float xfr[NC][NMT];
  __shared__ float xfi[NC][NMT];
  int b = blockIdx.x >> 4, k = blockIdx.x & 15;
  const float* xin = xs + ((size_t)b*NK + k)*NT*NC;
  for (int idx=threadIdx.x; idx<NT*NC; idx+=64) xst[idx] = xin[idx];
  __syncthreads();
  int l = threadIdx.x;
  if (l < NC){
    float ar0=0,ar1=0,ar2=0,ar3=0, ai1=0,ai2=0,ai3=0;
    for (int t=0;t<NT;t++){
      float v = xst[t*NC + l];
      float w1 = 0.31415926535897932f * (float)t;  // 2*pi*t/20
      ar0 += v;
      ar1 += v*cosf(w1);       ai1 -= v*sinf(w1);
      ar2 += v*cosf(2.f*w1);   ai2 -= v*sinf(2.f*w1);
      ar3 += v*cosf(3.f*w1);   ai3 -= v*sinf(3.f*w1);
    }
    xfr[l][0]=ar0; xfi[l][0]=0.f;
    xfr[l][1]=ar1; xfi[l][1]=ai1;
    xfr[l][2]=ar2; xfi[l][2]=ai2;
    xfr[l][3]=ar3; xfi[l][3]=ai3;
  }
  __syncthreads();
  if (l < NC){
    int o = l;
    float ofr[NMT], ofi[NMT];
    #pragma unroll
    for (int f=0; f<NMT; f++){ ofr[f]=0.f; ofi[f]=0.f; }
    for (int i=0;i<NC;i++){
      size_t wbase = ((((size_t)layer*NC + i)*NC + o)*NK + k)*NMT;
      #pragma unroll
      for (int f=0; f<NMT; f++){
        float wr = fwr[wbase+f], wi2 = fwi[wbase+f];
        float xr = xfr[i][f], xi = xfi[i][f];
        ofr[f] += xr*wr - xi*wi2;
        ofi[f] += xr*wi2 + xi*wr;
      }
    }
    float* outp = osb + ((size_t)b*NK + k)*NT*NC;
    for (int t=0;t<NT;t++){
      float w1 = 0.31415926535897932f * (float)t;
      float acc = ofr[0];
      acc += 2.f*(ofr[1]*cosf(w1)     - ofi[1]*sinf(w1));
      acc += 2.f*(ofr[2]*cosf(2.f*w1) - ofi[2]*sinf(2.f*w1));
      acc += 2.f*(ofr[3]*cosf(3.f*w1) - ofi[3]*sinf(3.f*w1));
      outp[t*NC + o] = acc * 0.05f;
    }
  }
}

// ---------------- h' = basis*os + cw*h + cb, gelu (layers 0..2) --------------
__global__ __launch_bounds__(256) void k_update(const float* __restrict__ X, const float* __restrict__ osb,
                         const float* __restrict__ h, const float* __restrict__ cw,
                         const float* __restrict__ cb, float* __restrict__ hout, int layer){
  __shared__ float os_s[NK*NT*NC];   // 40KB
  __shared__ float cwT[NC*NC];
  __shared__ float Xl[NK][32];
  __shared__ float cbs[NC];
  int b = blockIdx.x & 7;
  int n0 = (blockIdx.x >> 3)*32;
  for (int idx=threadIdx.x; idx<NK*NT*NC; idx+=256) os_s[idx] = osb[(size_t)b*NK*NT*NC + idx];
  for (int idx=threadIdx.x; idx<NC*NC; idx+=256){
    int o = idx/NC, i = idx%NC;
    cwT[i*NC + o] = cw[((size_t)layer*NC + o)*NC + i];
  }
  if (threadIdx.x < NC) cbs[threadIdx.x] = cb[layer*NC + threadIdx.x];
  for (int idx=threadIdx.x; idx<NK*32; idx+=256){
    int k = idx >> 5, nl = idx & 31;
    Xl[k][nl] = X[((size_t)b*NM + k)*NN + n0 + nl];
  }
  __syncthreads();
  for (int tsk=threadIdx.x; tsk<32*NT; tsk+=256){
    int t = tsk % NT, nl = tsk / NT;
    int n = n0 + nl;
    const float* hr = h + (((size_t)b*NN + n)*NT + t)*NC;
    float acc[NC];
    #pragma unroll
    for (int o=0;o<NC;o++) acc[o] = cbs[o];
    #pragma unroll
    for (int k=0;k<NK;k++){
      float xv = Xl[k][nl];
      const float* osr = os_s + (k*NT + t)*NC;
      #pragma unroll
      for (int o=0;o<NC;o++) acc[o] += xv*osr[o];
    }
    for (int i=0;i<NC;i++){
      float hv = hr[i];
      const float* cwr = cwT + i*NC;
      #pragma unroll
      for (int o=0;o<NC;o++) acc[o] += hv*cwr[o];
    }
    float* outp = hout + (((size_t)b*NN + n)*NT + t)*NC;
    if (layer < 3){
      #pragma unroll
      for (int o=0;o<NC;o++) outp[o] = gelu_f(acc[o]);
    } else {
      #pragma unroll
      for (int o=0;o<NC;o++) outp[o] = acc[o];
    }
  }
}

// ---------------- head: gelu(h@q1w+q1b)@q2w + q2b ----------------------------
__global__ __launch_bounds__(256) void k_head(const float* __restrict__ h, const float* __restrict__ q1w,
                       const float* __restrict__ q1b, const float* __restrict__ q2w,
                       const float* __restrict__ q2b, float* __restrict__ out){
  __shared__ float w1[NC*NQ];
  __shared__ float b1[NQ], w2[NQ];
  for (int idx=threadIdx.x; idx<NC*NQ; idx+=256) w1[idx] = q1w[idx];
  if (threadIdx.x < NQ){ b1[threadIdx.x] = q1b[threadIdx.x]; w2[threadIdx.x] = q2w[threadIdx.x]; }
  __syncthreads();
  int idx = blockIdx.x*256 + threadIdx.x;
  if (idx >= NB*NN*NT) return;
  const float* hr = h + (size_t)idx*NC;
  float hv[NC];
  #pragma unroll
  for (int i=0;i<NC;i++) hv[i] = hr[i];
  float res = q2b[0];
  for (int j=0;j<NQ;j++){
    float z = b1[j];
    #pragma unroll
    for (int i=0;i<NC;i++) z += hv[i]*w1[i*NQ + j];
    res += gelu_f(z)*w2[j];
  }
  out[idx] = res;
}

// ============================================================================
extern "C" void kernel_launch(void* const* d_in, const int* in_sizes, int n_in,
                              void* d_out, int out_size, void* d_ws, size_t ws_size,
                              hipStream_t stream){
  (void)in_sizes; (void)n_in; (void)out_size;
  const float* x   = (const float*)d_in[0];
  const float* pos = (const float*)d_in[1];
  const float* Wp  = (const float*)d_in[2];
  const float* bp  = (const float*)d_in[3];
  const float* fwr = (const float*)d_in[4];
  const float* fwi = (const float*)d_in[5];
  const float* cw  = (const float*)d_in[6];
  const float* cb  = (const float*)d_in[7];
  const float* q1w = (const float*)d_in[8];
  const float* q1b = (const float*)d_in[9];
  const float* q2w = (const float*)d_in[10];
  const float* q2b = (const float*)d_in[11];

  char* p = (char*)d_ws;
  auto take = [&](size_t bytes)->void*{
    void* r = (void*)p;
    p += (bytes + 255) & ~(size_t)255;
    return r;
  };
  float*  hA    = (float*) take(sizeof(float)*NB*NN*NT*NC);
  float*  hB    = (float*) take(sizeof(float)*NB*NN*NT*NC);
  float*  knnd  = (float*) take(sizeof(float)*NB*NN*8);
  int*    knni  = (int*)   take(sizeof(int)*NB*NN*8);
  double* sig   = (double*)take(sizeof(double)*NB);
  int*    cntb  = (int*)   take(sizeof(int)*NB*NN);
  unsigned short* ecolT = (unsigned short*) take(sizeof(unsigned short)*(size_t)GNN*WE);
  float*  evalT = (float*) take(sizeof(float)*(size_t)GNN*WE);
  float*  deg   = (float*) take(sizeof(float)*NB*NN);
  float*  dinv  = (float*) take(sizeof(float)*NB*NN);
  float*  dval  = (float*) take(sizeof(float)*NB*NN);
  float*  Xb    = (float*) take(sizeof(float)*NB*NM*NN);
  float*  Yb    = (float*) take(sizeof(float)*NB*NM*NN);
  double* Gd    = (double*)take(sizeof(double)*NB*NM*NM);
  float*  aint  = (float*) take(sizeof(float)*NB);
  float*  xs    = (float*) take(sizeof(float)*NB*NK*NT*NC);
  float*  osb   = (float*) take(sizeof(float)*NB*NK*NT*NC);
  if ((size_t)(p - (char*)d_ws) > ws_size) return;  // ws too small -> loud failure

  k_build_h0<<<(NB*NN*NT*NC+255)/256, 256, 0, stream>>>(x, pos, Wp, bp, hA);

  static const int RDEG[3] = {16, 28, 28};
  float* hcur = hA; float* hnext = hB;
  for (int layer=0; layer<4; layer++){
    hipMemsetAsync(sig, 0, sizeof(double)*NB, stream);
    k_dist_knn<<<NB*NN/4, 256, 0, stream>>>(hcur, knnd, knni, sig, cntb);
    k_build_ell<<<NB*NN/256, 256, 0, stream>>>(knnd, knni, sig, cntb, ecolT, evalT);
    k_degnorm<<<NB*NN/256, 256, 0, stream>>>(cntb, evalT, deg, dinv);
    k_normell<<<NB*NN/256, 256, 0, stream>>>(cntb, ecolT, evalT, deg, dinv, dval);
    k_initX<<<NB*NM*NN/256, 256, 0, stream>>>(deg, Xb, aint);
    float* cur = Xb; float* oth = Yb;
    for (int r=0; r<3; r++){
      k_cheb<<<NB*NM, 512, 0, stream>>>(cntb, ecolT, evalT, dval, cur, aint, RDEG[r]);
      k_gram<<<NB*NM, 256, 0, stream>>>(cur, cur, Gd);
      k_cholapply<<<NB*4, 256, 0, stream>>>(Gd, cur, oth, aint, (r==0)?1:0);
      { float* t_ = cur; cur = oth; oth = t_; }
      if (r == 0)
        k_spmv_gersh<<<NB*NM, 256, 0, stream>>>(cntb, ecolT, evalT, dval, cur, aint);
    }
    // final Rayleigh-Ritz: Y = L X, G = X^T Y, Jacobi, apply sorted rotation
    k_spmv<<<NB*NM, 256, 0, stream>>>(cntb, ecolT, evalT, dval, cur, oth);
    k_gram<<<NB*NM, 256, 0, stream>>>(cur, oth, Gd);
    k_jacobi_apply<<<NB, 256, 0, stream>>>(Gd, cur, oth, 2);
    { float* t_ = cur; cur = oth; oth = t_; }

    k_project<<<NB*40, 256, 0, stream>>>(cur, hcur, xs);
    k_timefilter<<<NB*NK, 64, 0, stream>>>(xs, fwr, fwi, osb, layer);
    k_update<<<NB*32, 256, 0, stream>>>(cur, osb, hcur, cw, cb, hnext, layer);
    { float* t_ = hcur; hcur = hnext; hnext = t_; }
  }
  k_head<<<(NB*NN*NT+255)/256, 256, 0, stream>>>(hcur, q1w, q1b, q2w, q2b, (float*)d_out);
}

// Round 6
// 3394.689 us; speedup vs baseline: 4.6322x; 1.2473x over previous
//
#include <hip/hip_runtime.h>

#define NB 8
#define NN 1024
#define NC 32
#define NT 20
#define NTI 10
#define NM 32     // iteration block size (16 wanted + 16 guard)
#define NK 16     // K_SPACE
#define NMT 4     // M_TIME
#define WE 64     // ELL width (max entries per row)
#define NQ 128
#define GNN (NB*NN)
#define RSL 24    // edge slots held in registers in k_cheb
#define PTC 16    // tc per block in k_project
#define PSEG 16   // n-segments in k_project

__device__ __forceinline__ float gelu_f(float x){
  return 0.5f * x * (1.0f + erff(x * 0.70710678118654752f));
}
__device__ __forceinline__ unsigned wanghash(unsigned s){
  s = (s ^ 61u) ^ (s >> 16); s *= 9u; s ^= s >> 4; s *= 0x27d4eb2du; s ^= s >> 15;
  return s;
}

// ---------------- initial lift: h[b][n][t][c] = concat(x,pos,t) @ Wp + bp ----
__global__ void k_build_h0(const float* __restrict__ x, const float* __restrict__ pos,
                           const float* __restrict__ Wp, const float* __restrict__ bp,
                           float* __restrict__ h){
  int idx = blockIdx.x*256 + threadIdx.x;
  if (idx >= NB*NN*NT*NC) return;
  int c = idx & (NC-1);
  int t = (idx/NC) % NT;
  int n = (idx/(NC*NT)) & (NN-1);
  int b = idx/(NC*NT*NN);
  const float* xr = x + (b*NN + n)*NTI;
  float acc = bp[c];
  #pragma unroll
  for (int i=0;i<NTI;i++) acc += xr[i]*Wp[i*NC+c];
  acc += pos[(b*NN+n)*2+0]*Wp[10*NC+c];
  acc += pos[(b*NN+n)*2+1]*Wp[11*NC+c];
  float tv = (float)(10+t) * (1.0f/29.0f);
  acc += tv*Wp[12*NC+c];
  h[idx] = acc;
}

// ---------------- fused pairwise distance + top-8 kNN + sigma sum ------------
// R4 structure (48 VGPR) + XCD batch affinity (b=bid&7) + 2-candidate ILP.
__global__ __launch_bounds__(256) void k_dist_knn(const float* __restrict__ h,
                           float* __restrict__ knnd, int* __restrict__ knni,
                           double* __restrict__ sig, int* __restrict__ cnt){
  __shared__ float fr_s[4][NC];
  int wave = threadIdx.x >> 6;
  int lane = threadIdx.x & 63;
  int b  = blockIdx.x & 7;             // XCD-affine batch: h[b] (2.6MB) fits one L2
  int rg = blockIdx.x >> 3;            // 0..255
  int row = (b<<10) + rg*4 + wave;
  if (threadIdx.x < 4*NC){
    int w = threadIdx.x >> 5, c = threadIdx.x & 31;
    int rr = (b<<10) + rg*4 + w;
    fr_s[w][c] = h[((size_t)rr*NT)*NC + c];
  }
  __syncthreads();
  float fr[NC];
  #pragma unroll
  for (int c=0;c<NC;c++) fr[c] = fr_s[wave][c];
  float d8[8]; int i8[8];
  #pragma unroll
  for (int j=0;j<8;j++){ d8[j]=1e30f; i8[j]=0x3fffffff; }
  double ssum = 0.0;
  const float* fb = h + (size_t)b*NN*NT*NC;
  for (int m=lane; m<NN; m+=128){
    const float* fmA = fb + (size_t)m*NT*NC;
    const float* fmB = fmA + (size_t)64*NT*NC;
    float d2a = 0.f, d2b = 0.f;
    #pragma unroll
    for (int c=0;c<NC;c++){
      float dfa = fr[c]-fmA[c]; d2a += dfa*dfa;
      float dfb = fr[c]-fmB[c]; d2b += dfb*dfb;
    }
    float da = sqrtf(d2a);
    ssum += (double)da;
    if (da < d8[7] || (da == d8[7] && m < i8[7])){
      d8[7] = da; i8[7] = m;
      #pragma unroll
      for (int j=6;j>=0;j--){
        bool sw = (d8[j+1] < d8[j]) || (d8[j+1]==d8[j] && i8[j+1]<i8[j]);
        if (sw){ float td=d8[j]; d8[j]=d8[j+1]; d8[j+1]=td;
                 int ti=i8[j]; i8[j]=i8[j+1]; i8[j+1]=ti; }
      }
    }
    int m2 = m + 64;
    float db = sqrtf(d2b);
    ssum += (double)db;
    if (db < d8[7] || (db == d8[7] && m2 < i8[7])){
      d8[7] = db; i8[7] = m2;
      #pragma unroll
      for (int j=6;j>=0;j--){
        bool sw = (d8[j+1] < d8[j]) || (d8[j+1]==d8[j] && i8[j+1]<i8[j]);
        if (sw){ float td=d8[j]; d8[j]=d8[j+1]; d8[j+1]=td;
                 int ti=i8[j]; i8[j]=i8[j+1]; i8[j+1]=ti; }
      }
    }
  }
  #pragma unroll
  for (int off=32; off>0; off>>=1) ssum += __shfl_down(ssum, off);
  if (lane==0){ atomicAdd(&sig[b], ssum); cnt[row] = 8; }
  // merge per-lane sorted top-8 lists: 8x wave-argmin extraction
  int ptr = 0;
  for (int sel=0; sel<8; sel++){
    float dv = 1e30f; int iv = 0x3fffffff;
    #pragma unroll
    for (int j=0;j<8;j++) if (j==ptr){ dv=d8[j]; iv=i8[j]; }
    float bd = dv; int bi = iv;
    #pragma unroll
    for (int off=32; off>0; off>>=1){
      float od = __shfl_xor(bd, off);
      int oi = __shfl_xor(bi, off);
      if (od < bd || (od == bd && oi < bi)){ bd = od; bi = oi; }
    }
    if (dv == bd && iv == bi) ptr++;
    if (lane == sel){ knnd[row*8+sel] = bd; knni[row*8+sel] = bi; }
  }
}

// ---------------- symmetrized sparse A in transposed ELL form ----------------
__global__ void k_build_ell(const float* __restrict__ knnd, const int* __restrict__ knni,
                            const double* __restrict__ sig, int* __restrict__ cnt,
                            unsigned short* __restrict__ ecolT, float* __restrict__ evalT){
  int row = blockIdx.x*256 + threadIdx.x;
  if (row >= NB*NN) return;
  int b = row >> 10;
  float sigma = (float)(sig[b] * (1.0/((double)NN*(double)NN)));
  float s2 = sigma*sigma;
  int rloc = row & (NN-1);
  #pragma unroll
  for (int j=0;j<8;j++){
    float d = knnd[row*8+j];
    int m = knni[row*8+j];
    float v = 0.5f * expf(-d/s2);
    ecolT[(size_t)j*GNN + row] = (unsigned short)m;
    evalT[(size_t)j*GNN + row] = v;
    int grow = (b<<10) + m;
    int p = atomicAdd(&cnt[grow], 1);
    if (p < WE){ ecolT[(size_t)p*GNN + grow] = (unsigned short)rloc;
                 evalT[(size_t)p*GNN + grow] = v; }
  }
}

__global__ void k_degnorm(const int* __restrict__ cnt, const float* __restrict__ evalT,
                          float* __restrict__ deg, float* __restrict__ dinv){
  int row = blockIdx.x*256 + threadIdx.x;
  if (row >= NB*NN) return;
  int c = cnt[row]; if (c > WE) c = WE;
  float s = 0.f;
  for (int j=0;j<c;j++) s += evalT[(size_t)j*GNN + row];
  deg[row] = s;
  dinv[row] = 1.0f/sqrtf(s + 1e-6f);
}

__global__ void k_normell(const int* __restrict__ cnt, const unsigned short* __restrict__ ecolT,
                          float* __restrict__ evalT, const float* __restrict__ deg,
                          const float* __restrict__ dinv, float* __restrict__ dval){
  int row = blockIdx.x*256 + threadIdx.x;
  if (row >= NB*NN) return;
  int b = row >> 10;
  const float* dv = dinv + (b<<10);
  float di = dinv[row];
  int c = cnt[row]; if (c > WE) c = WE;
  for (int j=0;j<c;j++){
    int col = ecolT[(size_t)j*GNN + row];
    evalT[(size_t)j*GNN + row] = evalT[(size_t)j*GNN + row] * (di * dv[col]);
  }
  dval[row] = di*di*deg[row];
}

// ---------------- eigensolver: init block -----------------------------------
__global__ void k_initX(const float* __restrict__ deg, float* __restrict__ X, float* __restrict__ aint){
  int idx = blockIdx.x*256+threadIdx.x;
  if (idx >= NB*NM*NN) return;
  int n = idx & (NN-1);
  int j = (idx >> 10) & (NM-1);
  int b = idx >> 15;
  float v;
  if (j == 0) v = sqrtf(deg[(b<<10)+n] + 1e-6f);   // exact 0-eigenvector of Lhat
  else {
    unsigned hsh = wanghash((unsigned)idx * 2654435761u + 12345u);
    v = ((hsh >> 8) * (1.0f/16777216.0f)) - 0.5f;
  }
  X[idx] = v;
  if (n == 0 && j == 1) aint[b] = 1.0f;
}

// ---------------- Chebyshev filter, one column per block, edges in regs ------
__global__ __launch_bounds__(512) void k_cheb(const int* __restrict__ cnt,
                        const unsigned short* __restrict__ ecolT,
                        const float* __restrict__ evalT, const float* __restrict__ dval,
                        float* __restrict__ X, const float* __restrict__ aint, int ndeg){
  __shared__ float bufA[NN];
  __shared__ float bufB[NN];
  int b = blockIdx.x & 7;
  int col = blockIdx.x >> 3;
  float a = aint[b];
  const float bhi = 2.0005f;
  float e  = 0.5f*(bhi - a);
  float cc = 0.5f*(bhi + a);
  float inv_e = 1.0f/e;
  const int rowbase = b << 10;
  float* Xc = X + ((size_t)b*NM + col)*NN;
  for (int n=threadIdx.x; n<NN; n+=512) bufA[n] = Xc[n];
  int r0 = threadIdx.x, r1 = threadIdx.x + 512;
  int c0 = cnt[rowbase+r0]; if (c0 > WE) c0 = WE;
  int c1 = cnt[rowbase+r1]; if (c1 > WE) c1 = WE;
  float dv0 = dval[rowbase+r0];
  float dv1 = dval[rowbase+r1];
  float ev0[RSL], ev1[RSL];
  int   ic0[RSL], ic1[RSL];
  #pragma unroll
  for (int j=0;j<RSL;j++){
    ic0[j] = (j<c0)? (int)ecolT[(size_t)j*GNN + rowbase + r0] : 0;
    ev0[j] = (j<c0)? evalT[(size_t)j*GNN + rowbase + r0] : 0.f;
    ic1[j] = (j<c1)? (int)ecolT[(size_t)j*GNN + rowbase + r1] : 0;
    ev1[j] = (j<c1)? evalT[(size_t)j*GNN + rowbase + r1] : 0.f;
  }
  int e0 = c0 - RSL; if (e0 < 0) e0 = 0;
  int e1 = c1 - RSL; if (e1 < 0) e1 = 0;
  int emax = (e0 > e1)? e0 : e1;
  const unsigned short* pe0 = ecolT + (size_t)RSL*GNN + rowbase + r0;
  const unsigned short* pe1 = ecolT + (size_t)RSL*GNN + rowbase + r1;
  const float* pv0 = evalT + (size_t)RSL*GNN + rowbase + r0;
  const float* pv1 = evalT + (size_t)RSL*GNN + rowbase + r1;
  __syncthreads();
  float* cur = bufA; float* prv = bufB;
  for (int k=0;k<ndeg;k++){
    float f = (k==0)? inv_e : 2.0f*inv_e;
    float x0 = cur[r0], x1 = cur[r1];
    float acc0 = dv0*x0, acc1 = dv1*x1;
    #pragma unroll
    for (int j=0;j<RSL;j++){
      acc0 -= ev0[j]*cur[ic0[j]];
      acc1 -= ev1[j]*cur[ic1[j]];
    }
    for (int j=0;j<emax;j++){   // rare overflow rows
      if (j < e0) acc0 -= pv0[(size_t)j*GNN] * cur[pe0[(size_t)j*GNN]];
      if (j < e1) acc1 -= pv1[(size_t)j*GNN] * cur[pe1[(size_t)j*GNN]];
    }
    float n0 = f*(acc0 - cc*x0);
    float n1 = f*(acc1 - cc*x1);
    if (k > 0){ n0 -= prv[r0]; n1 -= prv[r1]; }
    prv[r0] = n0; prv[r1] = n1;
    float* t_ = cur; cur = prv; prv = t_;
    __syncthreads();
  }
  for (int n=threadIdx.x; n<NN; n+=512) Xc[n] = cur[n];
}

// ---------------- G = A^T B (f64 accumulate), one row of G per wg ------------
__global__ void k_gram(const float* __restrict__ A, const float* __restrict__ Bm,
                       double* __restrict__ G){
  __shared__ float ai[NN];
  __shared__ double pd[NM][8];
  int b = blockIdx.x & 7, i = blockIdx.x >> 3;
  const float* Ac = A + ((size_t)b*NM + i)*NN;
  for (int n=threadIdx.x; n<NN; n+=256) ai[n] = Ac[n];
  __syncthreads();
  int j = threadIdx.x & 31, seg = threadIdx.x >> 5;
  const float* Bc = Bm + ((size_t)b*NM + j)*NN + seg*128;
  const float* as = ai + seg*128;
  double s = 0.0;
  for (int n=0;n<128;n++) s += (double)as[n]*(double)Bc[n];
  pd[j][seg] = s;
  __syncthreads();
  if (threadIdx.x < NM){
    double t = 0.0;
    #pragma unroll
    for (int q=0;q<8;q++) t += pd[threadIdx.x][q];
    G[((size_t)b*NM + i)*NM + threadIdx.x] = t;
  }
}

// ---------------- fused chol(G)->R^{-1}->apply quarter of nodes --------------
__global__ __launch_bounds__(256) void k_cholapply(const double* __restrict__ G,
                        const float* __restrict__ Xin, float* __restrict__ Xout,
                        float* __restrict__ aint, int reset){
  __shared__ double L[NM][NM];
  __shared__ double Ri[NM][NM];
  int b = blockIdx.x >> 2;
  int quarter = blockIdx.x & 3;
  int tid = threadIdx.x;
  for (int idx=tid; idx<NM*NM; idx+=256) L[idx>>5][idx&31] = G[(size_t)b*NM*NM + idx];
  __syncthreads();
  for (int k=0;k<NM;k++){
    if (tid == 0){
      double orig = L[k][k];
      double s = orig;
      for (int p=0;p<k;p++) s -= L[k][p]*L[k][p];
      double floorv = orig*1e-15; if (floorv < 1e-30) floorv = 1e-30;
      if (s < floorv) s = floorv;
      L[k][k] = sqrt(s);
    }
    __syncthreads();
    if (tid > k && tid < NM){
      double s = L[tid][k];
      for (int p=0;p<k;p++) s -= L[tid][p]*L[k][p];
      L[tid][k] = s / L[k][k];
    }
    __syncthreads();
  }
  if (tid < NM){
    int j = tid;
    Ri[j][j] = 1.0 / L[j][j];
    for (int i=j-1;i>=0;i--){
      double s = 0.0;
      for (int k2=i+1;k2<=j;k2++) s += L[k2][i]*Ri[k2][j];
      Ri[i][j] = -s / L[i][i];
    }
  }
  __syncthreads();
  int n = quarter*256 + tid;
  float xv[NM];
  #pragma unroll
  for (int j=0;j<NM;j++) xv[j] = Xin[((size_t)b*NM + j)*NN + n];
  for (int jn=0;jn<NM;jn++){
    double acc = 0.0;
    for (int j=0;j<=jn;j++) acc += (double)xv[j] * Ri[j][jn];
    Xout[((size_t)b*NM + jn)*NN + n] = (float)acc;
  }
  if (reset && quarter==0 && tid==0) aint[b] = 0.02f;
}

// ---------------- fused spmv + Gram row + Gershgorin interval bound ----------
__global__ __launch_bounds__(256) void k_spmv_gersh(const int* __restrict__ cnt,
                        const unsigned short* __restrict__ ecolT,
                        const float* __restrict__ evalT, const float* __restrict__ dval,
                        const float* __restrict__ X, float* __restrict__ aint){
  __shared__ float xc[NN];
  __shared__ float yc[NN];
  __shared__ double pd[NM][8];
  int b = blockIdx.x & 7, j = blockIdx.x >> 3;
  const float* Xc = X + ((size_t)b*NM + j)*NN;
  for (int n=threadIdx.x; n<NN; n+=256) xc[n] = Xc[n];
  __syncthreads();
  int rowbase = b << 10;
  for (int r=threadIdx.x; r<NN; r+=256){
    int c = cnt[rowbase+r]; if (c > WE) c = WE;
    float acc = dval[rowbase+r]*xc[r];
    const unsigned short* pe = ecolT + rowbase + r;
    const float* pv = evalT + rowbase + r;
    for (int jj=0;jj<c;jj++){
      acc -= pv[0]*xc[pe[0]];
      pe += GNN; pv += GNN;
    }
    yc[r] = acc;
  }
  __syncthreads();
  int i = threadIdx.x >> 3, seg = threadIdx.x & 7;
  const float* Xi = X + ((size_t)b*NM + i)*NN + seg*128;
  const float* ys = yc + seg*128;
  double s = 0.0;
  for (int k=0;k<128;k++) s += (double)Xi[k]*(double)ys[k];
  pd[i][seg] = s;
  __syncthreads();
  if (threadIdx.x < NM){
    double g = 0.0;
    #pragma unroll
    for (int q=0;q<8;q++) g += pd[threadIdx.x][q];
    double contrib = (threadIdx.x==j)? g : fabs(g);
    #pragma unroll
    for (int off=16; off>0; off>>=1) contrib += __shfl_down(contrib, off, 32);
    if (threadIdx.x == 0){
      float av = (float)contrib*1.02f + 1e-4f;
      av = fminf(fmaxf(av, 0.02f), 1.5f);
      atomicMax((unsigned int*)&aint[b], __float_as_uint(av));
    }
  }
}

// ---------------- fused spmv + Gram row write (final RR) ---------------------
__global__ __launch_bounds__(256) void k_spmv_gram(const int* __restrict__ cnt,
                        const unsigned short* __restrict__ ecolT,
                        const float* __restrict__ evalT, const float* __restrict__ dval,
                        const float* __restrict__ X, double* __restrict__ G){
  __shared__ float xc[NN];
  __shared__ float yc[NN];
  __shared__ double pd[NM][8];
  int b = blockIdx.x & 7, j = blockIdx.x >> 3;
  const float* Xc = X + ((size_t)b*NM + j)*NN;
  for (int n=threadIdx.x; n<NN; n+=256) xc[n] = Xc[n];
  __syncthreads();
  int rowbase = b << 10;
  for (int r=threadIdx.x; r<NN; r+=256){
    int c = cnt[rowbase+r]; if (c > WE) c = WE;
    float acc = dval[rowbase+r]*xc[r];
    const unsigned short* pe = ecolT + rowbase + r;
    const float* pv = evalT + rowbase + r;
    for (int jj=0;jj<c;jj++){
      acc -= pv[0]*xc[pe[0]];
      pe += GNN; pv += GNN;
    }
    yc[r] = acc;
  }
  __syncthreads();
  int i = threadIdx.x >> 3, seg = threadIdx.x & 7;
  const float* Xi = X + ((size_t)b*NM + i)*NN + seg*128;
  const float* ys = yc + seg*128;
  double s = 0.0;
  for (int k=0;k<128;k++) s += (double)Xi[k]*(double)ys[k];
  pd[i][seg] = s;
  __syncthreads();
  if (threadIdx.x < NM){
    double g = 0.0;
    #pragma unroll
    for (int q=0;q<8;q++) g += pd[threadIdx.x][q];
    G[((size_t)b*NM + j)*NM + threadIdx.x] = g;   // G[j][i]; jacobi symmetrizes
  }
}

// ---------------- fused 32x32 Jacobi + sorted rotation apply -----------------
__global__ __launch_bounds__(256) void k_jacobi_apply(const double* __restrict__ Gd,
                        const float* __restrict__ Xin, float* __restrict__ Xout, int sweeps){
  __shared__ float S[NM][NM];
  __shared__ float V[NM][NM];
  __shared__ float Vp[NM][NM];
  __shared__ float cs_[16], sn_[16];
  __shared__ int pp_[16], qq_[16];
  __shared__ int perm[NM];
  __shared__ float evs[NM];
  int b = blockIdx.x, l = threadIdx.x;
  for (int idx=l; idx<NM*NM; idx+=256){
    int i = idx>>5, j = idx&31;
    S[i][j] = (float)(0.5*(Gd[(size_t)b*NM*NM + i*NM + j] + Gd[(size_t)b*NM*NM + j*NM + i]));
    V[i][j] = (i==j)? 1.0f : 0.0f;
  }
  __syncthreads();
  for (int sw=0; sw<sweeps; sw++){
    for (int r=0; r<31; r++){
      if (l < 16){
        int p, q;
        if (l == 0){ p = r; q = 31; }
        else { p = (r + l) % 31; q = (r + 31 - l) % 31; }
        if (p > q){ int t_=p; p=q; q=t_; }
        float apq = S[p][q];
        float c = 1.0f, s = 0.0f;
        if (fabsf(apq) > 1e-30f){
          float tau = (S[q][q] - S[p][p]) / (2.0f*apq);
          float tt = (tau >= 0.f ? 1.0f : -1.0f) / (fabsf(tau) + sqrtf(1.0f + tau*tau));
          c = 1.0f/sqrtf(1.0f + tt*tt); s = tt*c;
        }
        cs_[l]=c; sn_[l]=s; pp_[l]=p; qq_[l]=q;
      }
      __syncthreads();
      for (int tsk=l; tsk<512; tsk+=256){
        int i = tsk >> 4, kk = tsk & 15;
        int p = pp_[kk], q = qq_[kk];
        float c = cs_[kk], s = sn_[kk];
        float sp = S[i][p], sq = S[i][q];
        S[i][p] = c*sp - s*sq; S[i][q] = s*sp + c*sq;
        float vp = V[i][p], vq = V[i][q];
        V[i][p] = c*vp - s*vq; V[i][q] = s*vp + c*vq;
      }
      __syncthreads();
      for (int tsk=l; tsk<512; tsk+=256){
        int jc = tsk >> 4, kk = tsk & 15;
        int p = pp_[kk], q = qq_[kk];
        float c = cs_[kk], s = sn_[kk];
        float sp = S[p][jc], sq = S[q][jc];
        S[p][jc] = c*sp - s*sq; S[q][jc] = s*sp + c*sq;
      }
      __syncthreads();
    }
  }
  if (l == 0){
    for (int i=0;i<NM;i++){ perm[i]=i; evs[i]=S[i][i]; }
    for (int i=0;i<NM;i++){
      int mi = i;
      for (int j=i+1;j<NM;j++) if (evs[perm[j]] < evs[perm[mi]]) mi = j;
      int t_=perm[i]; perm[i]=perm[mi]; perm[mi]=t_;
    }
  }
  __syncthreads();
  for (int idx=l; idx<NM*NM; idx+=256){
    int i = idx>>5, j = idx&31;
    Vp[i][j] = V[i][perm[j]];
  }
  __syncthreads();
  for (int nl=l; nl<NN; nl+=256){
    float xv[NM];
    #pragma unroll
    for (int j=0;j<NM;j++) xv[j] = Xin[((size_t)b*NM + j)*NN + nl];
    #pragma unroll
    for (int jn=0;jn<NM;jn++){
      float acc = 0.f;
      #pragma unroll
      for (int j=0;j<NM;j++) acc += xv[j]*Vp[j][jn];
      Xout[((size_t)b*NM + jn)*NN + nl] = acc;
    }
  }
}

// ---------------- xs[b][k][tc] = sum_n X[b][k][n] * h[b][n][tc] --------------
__global__ __launch_bounds__(256) void k_project(const float* __restrict__ X, const float* __restrict__ h,
                          float* __restrict__ xs){
  __shared__ float Xs[NK][NN];             // 64KB
  __shared__ float red[PSEG][NK][PTC+1];   // ~17KB
  int b = blockIdx.x & 7;
  int chunk = blockIdx.x >> 3;             // 0..39
  int tc0 = chunk * PTC;
  for (int idx=threadIdx.x; idx<NK*NN; idx+=256){
    int k = idx >> 10, n = idx & (NN-1);
    Xs[k][n] = X[((size_t)b*NM + k)*NN + n];
  }
  __syncthreads();
  int tcl = threadIdx.x & (PTC-1);
  int seg = threadIdx.x >> 4;              // 0..15
  const float* hb = h + (size_t)b*NN*NT*NC + tc0 + tcl;
  float acc[NK];
  #pragma unroll
  for (int k=0;k<NK;k++) acc[k]=0.f;
  int n0 = seg*(NN/PSEG);
  for (int n=n0; n<n0+(NN/PSEG); n++){
    float v = hb[(size_t)n*NT*NC];
    #pragma unroll
    for (int k=0;k<NK;k++) acc[k] += Xs[k][n]*v;
  }
  #pragma unroll
  for (int k=0;k<NK;k++) red[seg][k][tcl] = acc[k];
  __syncthreads();
  int k = threadIdx.x >> 4;
  int t2 = threadIdx.x & (PTC-1);
  float s = 0.f;
  #pragma unroll
  for (int q=0;q<PSEG;q++) s += red[q][k][t2];
  xs[((size_t)b*NK + k)*NT*NC + tc0 + t2] = s;
}

// ---------------- rfft(:4) -> complex channel mix -> irfft -------------------
__global__ __launch_bounds__(64) void k_timefilter(const float* __restrict__ xs, const float* __restrict__ fwr,
                             const float* __restrict__ fwi, float* __restrict__ osb, int layer){
  __shared__ float xst[NT*NC];
  __shared__ float xfr[NC][NMT];
  __shared__ float xfi[NC][NMT];
  int b = blockIdx.x >> 4, k = blockIdx.x & 15;
  const float* xin = xs + ((size_t)b*NK + k)*NT*NC;
  for (int idx=threadIdx.x; idx<NT*NC; idx+=64) xst[idx] = xin[idx];
  __syncthreads();
  int l = threadIdx.x;
  if (l < NC){
    float ar0=0,ar1=0,ar2=0,ar3=0, ai1=0,ai2=0,ai3=0;
    for (int t=0;t<NT;t++){
      float v = xst[t*NC + l];
      float w1 = 0.31415926535897932f * (float)t;  // 2*pi*t/20
      ar0 += v;
      ar1 += v*cosf(w1);       ai1 -= v*sinf(w1);
      ar2 += v*cosf(2.f*w1);   ai2 -= v*sinf(2.f*w1);
      ar3 += v*cosf(3.f*w1);   ai3 -= v*sinf(3.f*w1);
    }
    xfr[l][0]=ar0; xfi[l][0]=0.f;
    xfr[l][1]=ar1; xfi[l][1]=ai1;
    xfr[l][2]=ar2; xfi[l][2]=ai2;
    xfr[l][3]=ar3; xfi[l][3]=ai3;
  }
  __syncthreads();
  if (l < NC){
    int o = l;
    float ofr[NMT], ofi[NMT];
    #pragma unroll
    for (int f=0; f<NMT; f++){ ofr[f]=0.f; ofi[f]=0.f; }
    for (int i=0;i<NC;i++){
      size_t wbase = ((((size_t)layer*NC + i)*NC + o)*NK + k)*NMT;
      #pragma unroll
      for (int f=0; f<NMT; f++){
        float wr = fwr[wbase+f], wi2 = fwi[wbase+f];
        float xr = xfr[i][f], xi = xfi[i][f];
        ofr[f] += xr*wr - xi*wi2;
        ofi[f] += xr*wi2 + xi*wr;
      }
    }
    float* outp = osb + ((size_t)b*NK + k)*NT*NC;
    for (int t=0;t<NT;t++){
      float w1 = 0.31415926535897932f * (float)t;
      float acc = ofr[0];
      acc += 2.f*(ofr[1]*cosf(w1)     - ofi[1]*sinf(w1));
      acc += 2.f*(ofr[2]*cosf(2.f*w1) - ofi[2]*sinf(2.f*w1));
      acc += 2.f*(ofr[3]*cosf(3.f*w1) - ofi[3]*sinf(3.f*w1));
      outp[t*NC + o] = acc * 0.05f;
    }
  }
}

// ---------------- h' = basis*os + cw*h + cb, gelu (layers 0..2) --------------
__global__ __launch_bounds__(256) void k_update(const float* __restrict__ X, const float* __restrict__ osb,
                         const float* __restrict__ h, const float* __restrict__ cw,
                         const float* __restrict__ cb, float* __restrict__ hout, int layer){
  __shared__ float os_s[NK*NT*NC];   // 40KB
  __shared__ float cwT[NC*NC];
  __shared__ float Xl[NK][32];
  __shared__ float cbs[NC];
  int b = blockIdx.x & 7;
  int n0 = (blockIdx.x >> 3)*32;
  for (int idx=threadIdx.x; idx<NK*NT*NC; idx+=256) os_s[idx] = osb[(size_t)b*NK*NT*NC + idx];
  for (int idx=threadIdx.x; idx<NC*NC; idx+=256){
    int o = idx/NC, i = idx%NC;
    cwT[i*NC + o] = cw[((size_t)layer*NC + o)*NC + i];
  }
  if (threadIdx.x < NC) cbs[threadIdx.x] = cb[layer*NC + threadIdx.x];
  for (int idx=threadIdx.x; idx<NK*32; idx+=256){
    int k = idx >> 5, nl = idx & 31;
    Xl[k][nl] = X[((size_t)b*NM + k)*NN + n0 + nl];
  }
  __syncthreads();
  for (int tsk=threadIdx.x; tsk<32*NT; tsk+=256){
    int t = tsk % NT, nl = tsk / NT;
    int n = n0 + nl;
    const float* hr = h + (((size_t)b*NN + n)*NT + t)*NC;
    float acc[NC];
    #pragma unroll
    for (int o=0;o<NC;o++) acc[o] = cbs[o];
    #pragma unroll
    for (int k=0;k<NK;k++){
      float xv = Xl[k][nl];
      const float* osr = os_s + (k*NT + t)*NC;
      #pragma unroll
      for (int o=0;o<NC;o++) acc[o] += xv*osr[o];
    }
    for (int i=0;i<NC;i++){
      float hv = hr[i];
      const float* cwr = cwT + i*NC;
      #pragma unroll
      for (int o=0;o<NC;o++) acc[o] += hv*cwr[o];
    }
    float* outp = hout + (((size_t)b*NN + n)*NT + t)*NC;
    if (layer < 3){
      #pragma unroll
      for (int o=0;o<NC;o++) outp[o] = gelu_f(acc[o]);
    } else {
      #pragma unroll
      for (int o=0;o<NC;o++) outp[o] = acc[o];
    }
  }
}

// ---------------- head: gelu(h@q1w+q1b)@q2w + q2b ----------------------------
__global__ __launch_bounds__(256) void k_head(const float* __restrict__ h, const float* __restrict__ q1w,
                       const float* __restrict__ q1b, const float* __restrict__ q2w,
                       const float* __restrict__ q2b, float* __restrict__ out){
  __shared__ float w1[NC*NQ];
  __shared__ float b1[NQ], w2[NQ];
  for (int idx=threadIdx.x; idx<NC*NQ; idx+=256) w1[idx] = q1w[idx];
  if (threadIdx.x < NQ){ b1[threadIdx.x] = q1b[threadIdx.x]; w2[threadIdx.x] = q2w[threadIdx.x]; }
  __syncthreads();
  int idx = blockIdx.x*256 + threadIdx.x;
  if (idx >= NB*NN*NT) return;
  const float* hr = h + (size_t)idx*NC;
  float hv[NC];
  #pragma unroll
  for (int i=0;i<NC;i++) hv[i] = hr[i];
  float res = q2b[0];
  for (int j=0;j<NQ;j++){
    float z = b1[j];
    #pragma unroll
    for (int i=0;i<NC;i++) z += hv[i]*w1[i*NQ + j];
    res += gelu_f(z)*w2[j];
  }
  out[idx] = res;
}

// ============================================================================
extern "C" void kernel_launch(void* const* d_in, const int* in_sizes, int n_in,
                              void* d_out, int out_size, void* d_ws, size_t ws_size,
                              hipStream_t stream){
  (void)in_sizes; (void)n_in; (void)out_size;
  const float* x   = (const float*)d_in[0];
  const float* pos = (const float*)d_in[1];
  const float* Wp  = (const float*)d_in[2];
  const float* bp  = (const float*)d_in[3];
  const float* fwr = (const float*)d_in[4];
  const float* fwi = (const float*)d_in[5];
  const float* cw  = (const float*)d_in[6];
  const float* cb  = (const float*)d_in[7];
  const float* q1w = (const float*)d_in[8];
  const float* q1b = (const float*)d_in[9];
  const float* q2w = (const float*)d_in[10];
  const float* q2b = (const float*)d_in[11];

  char* p = (char*)d_ws;
  auto take = [&](size_t bytes)->void*{
    void* r = (void*)p;
    p += (bytes + 255) & ~(size_t)255;
    return r;
  };
  float*  hA    = (float*) take(sizeof(float)*NB*NN*NT*NC);
  float*  hB    = (float*) take(sizeof(float)*NB*NN*NT*NC);
  float*  knnd  = (float*) take(sizeof(float)*NB*NN*8);
  int*    knni  = (int*)   take(sizeof(int)*NB*NN*8);
  double* sig   = (double*)take(sizeof(double)*NB);
  int*    cntb  = (int*)   take(sizeof(int)*NB*NN);
  unsigned short* ecolT = (unsigned short*) take(sizeof(unsigned short)*(size_t)GNN*WE);
  float*  evalT = (float*) take(sizeof(float)*(size_t)GNN*WE);
  float*  deg   = (float*) take(sizeof(float)*NB*NN);
  float*  dinv  = (float*) take(sizeof(float)*NB*NN);
  float*  dval  = (float*) take(sizeof(float)*NB*NN);
  float*  Xb    = (float*) take(sizeof(float)*NB*NM*NN);
  float*  Yb    = (float*) take(sizeof(float)*NB*NM*NN);
  double* Gd    = (double*)take(sizeof(double)*NB*NM*NM);
  float*  aint  = (float*) take(sizeof(float)*NB);
  float*  xs    = (float*) take(sizeof(float)*NB*NK*NT*NC);
  float*  osb   = (float*) take(sizeof(float)*NB*NK*NT*NC);
  if ((size_t)(p - (char*)d_ws) > ws_size) return;  // ws too small -> loud failure

  k_build_h0<<<(NB*NN*NT*NC+255)/256, 256, 0, stream>>>(x, pos, Wp, bp, hA);

  float* hcur = hA; float* hnext = hB;
  for (int layer=0; layer<4; layer++){
    hipMemsetAsync(sig, 0, sizeof(double)*NB, stream);
    k_dist_knn<<<NB*NN/4, 256, 0, stream>>>(hcur, knnd, knni, sig, cntb);
    k_build_ell<<<NB*NN/256, 256, 0, stream>>>(knnd, knni, sig, cntb, ecolT, evalT);
    k_degnorm<<<NB*NN/256, 256, 0, stream>>>(cntb, evalT, deg, dinv);
    k_normell<<<NB*NN/256, 256, 0, stream>>>(cntb, ecolT, evalT, deg, dinv, dval);
    k_initX<<<NB*NM*NN/256, 256, 0, stream>>>(deg, Xb, aint);
    float* cur = Xb; float* oth = Yb;
    // round 0: deg 24 on [1.0, 2.0005], then QR + interval estimate
    k_cheb<<<NB*NM, 512, 0, stream>>>(cntb, ecolT, evalT, dval, cur, aint, 24);
    k_gram<<<NB*NM, 256, 0, stream>>>(cur, cur, Gd);
    k_cholapply<<<NB*4, 256, 0, stream>>>(Gd, cur, oth, aint, 1);
    { float* t_ = cur; cur = oth; oth = t_; }
    k_spmv_gersh<<<NB*NM, 256, 0, stream>>>(cntb, ecolT, evalT, dval, cur, aint);
    // round 1: deg 32 on adapted interval, then QR
    k_cheb<<<NB*NM, 512, 0, stream>>>(cntb, ecolT, evalT, dval, cur, aint, 32);
    k_gram<<<NB*NM, 256, 0, stream>>>(cur, cur, Gd);
    k_cholapply<<<NB*4, 256, 0, stream>>>(Gd, cur, oth, aint, 0);
    { float* t_ = cur; cur = oth; oth = t_; }
    // final Rayleigh-Ritz: G = X^T L X (fused), Jacobi, apply sorted rotation
    k_spmv_gram<<<NB*NM, 256, 0, stream>>>(cntb, ecolT, evalT, dval, cur, Gd);
    k_jacobi_apply<<<NB, 256, 0, stream>>>(Gd, cur, oth, 2);
    { float* t_ = cur; cur = oth; oth = t_; }

    k_project<<<NB*40, 256, 0, stream>>>(cur, hcur, xs);
    k_timefilter<<<NB*NK, 64, 0, stream>>>(xs, fwr, fwi, osb, layer);
    k_update<<<NB*32, 256, 0, stream>>>(cur, osb, hcur, cw, cb, hnext, layer);
    { float* t_ = hcur; hcur = hnext; hnext = t_; }
  }
  k_head<<<(NB*NN*NT+255)/256, 256, 0, stream>>>(hcur, q1w, q1b, q2w, q2b, (float*)d_out);
}

// Round 7
// 3219.210 us; speedup vs baseline: 4.8847x; 1.0545x over previous
//
#include <hip/hip_runtime.h>

#define NB 8
#define NN 1024
#define NC 32
#define NT 20
#define NTI 10
#define NM 32     // iteration block size (16 wanted + 16 guard)
#define NK 16     // K_SPACE
#define NMT 4     // M_TIME
#define WE 64     // ELL width (max entries per row)
#define NQ 128
#define GNN (NB*NN)
#define RSL 24    // edge slots held in registers in k_cheb
#define PTC 16    // tc per block in k_project
#define PSEG 16   // n-segments in k_project

__device__ __forceinline__ float gelu_f(float x){
  return 0.5f * x * (1.0f + erff(x * 0.70710678118654752f));
}
__device__ __forceinline__ unsigned wanghash(unsigned s){
  s = (s ^ 61u) ^ (s >> 16); s *= 9u; s ^= s >> 4; s *= 0x27d4eb2du; s ^= s >> 15;
  return s;
}

// ---------------- initial lift: h[b][n][t][c] = concat(x,pos,t) @ Wp + bp ----
__global__ void k_build_h0(const float* __restrict__ x, const float* __restrict__ pos,
                           const float* __restrict__ Wp, const float* __restrict__ bp,
                           float* __restrict__ h){
  int idx = blockIdx.x*256 + threadIdx.x;
  if (idx >= NB*NN*NT*NC) return;
  int c = idx & (NC-1);
  int t = (idx/NC) % NT;
  int n = (idx/(NC*NT)) & (NN-1);
  int b = idx/(NC*NT*NN);
  const float* xr = x + (b*NN + n)*NTI;
  float acc = bp[c];
  #pragma unroll
  for (int i=0;i<NTI;i++) acc += xr[i]*Wp[i*NC+c];
  acc += pos[(b*NN+n)*2+0]*Wp[10*NC+c];
  acc += pos[(b*NN+n)*2+1]*Wp[11*NC+c];
  float tv = (float)(10+t) * (1.0f/29.0f);
  acc += tv*Wp[12*NC+c];
  h[idx] = acc;
}

// ---------------- fused pairwise distance + top-8 kNN + sigma sum ------------
// 8 rows per block (8 waves); candidate 128-tiles staged in LDS (stride 129:
// bank-conflict-free reads). Per-lane visit order identical to prior rounds
// (m = 128*tile + lane, then +64) -> bitwise-identical sigma/top-8.
__global__ __launch_bounds__(512) void k_dist_knn(const float* __restrict__ h,
                           float* __restrict__ knnd, int* __restrict__ knni,
                           double* __restrict__ sig, int* __restrict__ cnt){
  __shared__ float fr_s[8][NC];
  __shared__ float fT[NC][129];       // 128 candidates, transposed, stride 129
  int wave = threadIdx.x >> 6;
  int lane = threadIdx.x & 63;
  int b  = blockIdx.x & 7;            // XCD-affine batch
  int rg = blockIdx.x >> 3;           // 0..127
  int row = (b<<10) + rg*8 + wave;
  if (threadIdx.x < 8*NC){
    int w = threadIdx.x >> 5, c = threadIdx.x & 31;
    int rr = (b<<10) + rg*8 + w;
    fr_s[w][c] = h[((size_t)rr*NT)*NC + c];
  }
  __syncthreads();
  float fr[NC];
  #pragma unroll
  for (int c=0;c<NC;c++) fr[c] = fr_s[wave][c];
  float d8[8]; int i8[8];
  #pragma unroll
  for (int j=0;j<8;j++){ d8[j]=1e30f; i8[j]=0x3fffffff; }
  double ssum = 0.0;
  const float* fb = h + (size_t)b*NN*NT*NC;
  for (int tile=0; tile<8; tile++){
    int m0 = tile*128;
    __syncthreads();
    #pragma unroll
    for (int q=0;q<8;q++){
      int idx = q*512 + threadIdx.x;
      int ml = idx >> 5, c = idx & 31;
      fT[c][ml] = fb[(size_t)(m0+ml)*NT*NC + c];
    }
    __syncthreads();
    float d2a = 0.f, d2b = 0.f;
    #pragma unroll 8
    for (int c=0;c<NC;c++){
      float fc = fr[c];
      float dfa = fc - fT[c][lane];
      float dfb = fc - fT[c][lane+64];
      d2a += dfa*dfa; d2b += dfb*dfb;
    }
    int m = m0 + lane;
    float da = sqrtf(d2a);
    ssum += (double)da;
    if (da < d8[7] || (da == d8[7] && m < i8[7])){
      d8[7] = da; i8[7] = m;
      #pragma unroll
      for (int j=6;j>=0;j--){
        bool sw = (d8[j+1] < d8[j]) || (d8[j+1]==d8[j] && i8[j+1]<i8[j]);
        if (sw){ float td=d8[j]; d8[j]=d8[j+1]; d8[j+1]=td;
                 int ti=i8[j]; i8[j]=i8[j+1]; i8[j+1]=ti; }
      }
    }
    int m2 = m + 64;
    float db = sqrtf(d2b);
    ssum += (double)db;
    if (db < d8[7] || (db == d8[7] && m2 < i8[7])){
      d8[7] = db; i8[7] = m2;
      #pragma unroll
      for (int j=6;j>=0;j--){
        bool sw = (d8[j+1] < d8[j]) || (d8[j+1]==d8[j] && i8[j+1]<i8[j]);
        if (sw){ float td=d8[j]; d8[j]=d8[j+1]; d8[j+1]=td;
                 int ti=i8[j]; i8[j]=i8[j+1]; i8[j+1]=ti; }
      }
    }
  }
  #pragma unroll
  for (int off=32; off>0; off>>=1) ssum += __shfl_down(ssum, off);
  if (lane==0){ atomicAdd(&sig[b], ssum); cnt[row] = 8; }
  // merge per-lane sorted top-8 lists: 8x wave-argmin extraction
  int ptr = 0;
  for (int sel=0; sel<8; sel++){
    float dv = 1e30f; int iv = 0x3fffffff;
    #pragma unroll
    for (int j=0;j<8;j++) if (j==ptr){ dv=d8[j]; iv=i8[j]; }
    float bd = dv; int bi = iv;
    #pragma unroll
    for (int off=32; off>0; off>>=1){
      float od = __shfl_xor(bd, off);
      int oi = __shfl_xor(bi, off);
      if (od < bd || (od == bd && oi < bi)){ bd = od; bi = oi; }
    }
    if (dv == bd && iv == bi) ptr++;
    if (lane == sel){ knnd[row*8+sel] = bd; knni[row*8+sel] = bi; }
  }
}

// ---------------- symmetrized sparse A in transposed ELL form ----------------
__global__ void k_build_ell(const float* __restrict__ knnd, const int* __restrict__ knni,
                            const double* __restrict__ sig, int* __restrict__ cnt,
                            unsigned short* __restrict__ ecolT, float* __restrict__ evalT){
  int row = blockIdx.x*256 + threadIdx.x;
  if (row >= NB*NN) return;
  int b = row >> 10;
  float sigma = (float)(sig[b] * (1.0/((double)NN*(double)NN)));
  float s2 = sigma*sigma;
  int rloc = row & (NN-1);
  #pragma unroll
  for (int j=0;j<8;j++){
    float d = knnd[row*8+j];
    int m = knni[row*8+j];
    float v = 0.5f * expf(-d/s2);
    ecolT[(size_t)j*GNN + row] = (unsigned short)m;
    evalT[(size_t)j*GNN + row] = v;
    int grow = (b<<10) + m;
    int p = atomicAdd(&cnt[grow], 1);
    if (p < WE){ ecolT[(size_t)p*GNN + grow] = (unsigned short)rloc;
                 evalT[(size_t)p*GNN + grow] = v; }
  }
}

__global__ void k_degnorm(const int* __restrict__ cnt, const float* __restrict__ evalT,
                          float* __restrict__ deg, float* __restrict__ dinv){
  int row = blockIdx.x*256 + threadIdx.x;
  if (row >= NB*NN) return;
  int c = cnt[row]; if (c > WE) c = WE;
  float s = 0.f;
  for (int j=0;j<c;j++) s += evalT[(size_t)j*GNN + row];
  deg[row] = s;
  dinv[row] = 1.0f/sqrtf(s + 1e-6f);
}

__global__ void k_normell(const int* __restrict__ cnt, const unsigned short* __restrict__ ecolT,
                          float* __restrict__ evalT, const float* __restrict__ deg,
                          const float* __restrict__ dinv, float* __restrict__ dval){
  int row = blockIdx.x*256 + threadIdx.x;
  if (row >= NB*NN) return;
  int b = row >> 10;
  const float* dv = dinv + (b<<10);
  float di = dinv[row];
  int c = cnt[row]; if (c > WE) c = WE;
  for (int j=0;j<c;j++){
    int col = ecolT[(size_t)j*GNN + row];
    evalT[(size_t)j*GNN + row] = evalT[(size_t)j*GNN + row] * (di * dv[col]);
  }
  dval[row] = di*di*deg[row];
}

// ---------------- eigensolver: init block -----------------------------------
__global__ void k_initX(const float* __restrict__ deg, float* __restrict__ X, float* __restrict__ aint){
  int idx = blockIdx.x*256+threadIdx.x;
  if (idx >= NB*NM*NN) return;
  int n = idx & (NN-1);
  int j = (idx >> 10) & (NM-1);
  int b = idx >> 15;
  float v;
  if (j == 0) v = sqrtf(deg[(b<<10)+n] + 1e-6f);   // exact 0-eigenvector of Lhat
  else {
    unsigned hsh = wanghash((unsigned)idx * 2654435761u + 12345u);
    v = ((hsh >> 8) * (1.0f/16777216.0f)) - 0.5f;
  }
  X[idx] = v;
  if (n == 0 && j == 1) aint[b] = 1.0f;
}

// ---------------- Chebyshev filter, one column per block, edges in regs ------
__global__ __launch_bounds__(512) void k_cheb(const int* __restrict__ cnt,
                        const unsigned short* __restrict__ ecolT,
                        const float* __restrict__ evalT, const float* __restrict__ dval,
                        float* __restrict__ X, const float* __restrict__ aint, int ndeg){
  __shared__ float bufA[NN];
  __shared__ float bufB[NN];
  int b = blockIdx.x & 7;
  int col = blockIdx.x >> 3;
  float a = aint[b];
  const float bhi = 2.0005f;
  float e  = 0.5f*(bhi - a);
  float cc = 0.5f*(bhi + a);
  float inv_e = 1.0f/e;
  const int rowbase = b << 10;
  float* Xc = X + ((size_t)b*NM + col)*NN;
  for (int n=threadIdx.x; n<NN; n+=512) bufA[n] = Xc[n];
  int r0 = threadIdx.x, r1 = threadIdx.x + 512;
  int c0 = cnt[rowbase+r0]; if (c0 > WE) c0 = WE;
  int c1 = cnt[rowbase+r1]; if (c1 > WE) c1 = WE;
  float dv0 = dval[rowbase+r0];
  float dv1 = dval[rowbase+r1];
  float ev0[RSL], ev1[RSL];
  int   ic0[RSL], ic1[RSL];
  #pragma unroll
  for (int j=0;j<RSL;j++){
    ic0[j] = (j<c0)? (int)ecolT[(size_t)j*GNN + rowbase + r0] : 0;
    ev0[j] = (j<c0)? evalT[(size_t)j*GNN + rowbase + r0] : 0.f;
    ic1[j] = (j<c1)? (int)ecolT[(size_t)j*GNN + rowbase + r1] : 0;
    ev1[j] = (j<c1)? evalT[(size_t)j*GNN + rowbase + r1] : 0.f;
  }
  int e0 = c0 - RSL; if (e0 < 0) e0 = 0;
  int e1 = c1 - RSL; if (e1 < 0) e1 = 0;
  int emax = (e0 > e1)? e0 : e1;
  const unsigned short* pe0 = ecolT + (size_t)RSL*GNN + rowbase + r0;
  const unsigned short* pe1 = ecolT + (size_t)RSL*GNN + rowbase + r1;
  const float* pv0 = evalT + (size_t)RSL*GNN + rowbase + r0;
  const float* pv1 = evalT + (size_t)RSL*GNN + rowbase + r1;
  __syncthreads();
  float* cur = bufA; float* prv = bufB;
  for (int k=0;k<ndeg;k++){
    float f = (k==0)? inv_e : 2.0f*inv_e;
    float x0 = cur[r0], x1 = cur[r1];
    float acc0 = dv0*x0, acc1 = dv1*x1;
    #pragma unroll
    for (int j=0;j<RSL;j++){
      acc0 -= ev0[j]*cur[ic0[j]];
      acc1 -= ev1[j]*cur[ic1[j]];
    }
    for (int j=0;j<emax;j++){   // rare overflow rows
      if (j < e0) acc0 -= pv0[(size_t)j*GNN] * cur[pe0[(size_t)j*GNN]];
      if (j < e1) acc1 -= pv1[(size_t)j*GNN] * cur[pe1[(size_t)j*GNN]];
    }
    float n0 = f*(acc0 - cc*x0);
    float n1 = f*(acc1 - cc*x1);
    if (k > 0){ n0 -= prv[r0]; n1 -= prv[r1]; }
    prv[r0] = n0; prv[r1] = n1;
    float* t_ = cur; cur = prv; prv = t_;
    __syncthreads();
  }
  for (int n=threadIdx.x; n<NN; n+=512) Xc[n] = cur[n];
}

// ---------------- G = A^T B (f64 accumulate), one row of G per wg ------------
__global__ void k_gram(const float* __restrict__ A, const float* __restrict__ Bm,
                       double* __restrict__ G){
  __shared__ float ai[NN];
  __shared__ double pd[NM][8];
  int b = blockIdx.x & 7, i = blockIdx.x >> 3;
  const float* Ac = A + ((size_t)b*NM + i)*NN;
  for (int n=threadIdx.x; n<NN; n+=256) ai[n] = Ac[n];
  __syncthreads();
  int j = threadIdx.x & 31, seg = threadIdx.x >> 5;
  const float* Bc = Bm + ((size_t)b*NM + j)*NN + seg*128;
  const float* as = ai + seg*128;
  double s = 0.0;
  for (int n=0;n<128;n++) s += (double)as[n]*(double)Bc[n];
  pd[j][seg] = s;
  __syncthreads();
  if (threadIdx.x < NM){
    double t = 0.0;
    #pragma unroll
    for (int q=0;q<8;q++) t += pd[threadIdx.x][q];
    G[((size_t)b*NM + i)*NM + threadIdx.x] = t;
  }
}

// ---------------- fused chol(G)->R^{-1}->apply quarter of nodes --------------
__global__ __launch_bounds__(256) void k_cholapply(const double* __restrict__ G,
                        const float* __restrict__ Xin, float* __restrict__ Xout,
                        float* __restrict__ aint, int reset){
  __shared__ double L[NM][NM];
  __shared__ double Ri[NM][NM];
  int b = blockIdx.x >> 2;
  int quarter = blockIdx.x & 3;
  int tid = threadIdx.x;
  for (int idx=tid; idx<NM*NM; idx+=256) L[idx>>5][idx&31] = G[(size_t)b*NM*NM + idx];
  __syncthreads();
  for (int k=0;k<NM;k++){
    if (tid == 0){
      double orig = L[k][k];
      double s = orig;
      for (int p=0;p<k;p++) s -= L[k][p]*L[k][p];
      double floorv = orig*1e-15; if (floorv < 1e-30) floorv = 1e-30;
      if (s < floorv) s = floorv;
      L[k][k] = sqrt(s);
    }
    __syncthreads();
    if (tid > k && tid < NM){
      double s = L[tid][k];
      for (int p=0;p<k;p++) s -= L[tid][p]*L[k][p];
      L[tid][k] = s / L[k][k];
    }
    __syncthreads();
  }
  if (tid < NM){
    int j = tid;
    Ri[j][j] = 1.0 / L[j][j];
    for (int i=j-1;i>=0;i--){
      double s = 0.0;
      for (int k2=i+1;k2<=j;k2++) s += L[k2][i]*Ri[k2][j];
      Ri[i][j] = -s / L[i][i];
    }
  }
  __syncthreads();
  int n = quarter*256 + tid;
  float xv[NM];
  #pragma unroll
  for (int j=0;j<NM;j++) xv[j] = Xin[((size_t)b*NM + j)*NN + n];
  for (int jn=0;jn<NM;jn++){
    double acc = 0.0;
    for (int j=0;j<=jn;j++) acc += (double)xv[j] * Ri[j][jn];
    Xout[((size_t)b*NM + jn)*NN + n] = (float)acc;
  }
  if (reset && quarter==0 && tid==0) aint[b] = 0.02f;
}

// ---------------- fused spmv + Gram row + Gershgorin interval bound ----------
__global__ __launch_bounds__(256) void k_spmv_gersh(const int* __restrict__ cnt,
                        const unsigned short* __restrict__ ecolT,
                        const float* __restrict__ evalT, const float* __restrict__ dval,
                        const float* __restrict__ X, float* __restrict__ aint){
  __shared__ float xc[NN];
  __shared__ float yc[NN];
  __shared__ double pd[NM][8];
  int b = blockIdx.x & 7, j = blockIdx.x >> 3;
  const float* Xc = X + ((size_t)b*NM + j)*NN;
  for (int n=threadIdx.x; n<NN; n+=256) xc[n] = Xc[n];
  __syncthreads();
  int rowbase = b << 10;
  for (int r=threadIdx.x; r<NN; r+=256){
    int c = cnt[rowbase+r]; if (c > WE) c = WE;
    float acc = dval[rowbase+r]*xc[r];
    const unsigned short* pe = ecolT + rowbase + r;
    const float* pv = evalT + rowbase + r;
    for (int jj=0;jj<c;jj++){
      acc -= pv[0]*xc[pe[0]];
      pe += GNN; pv += GNN;
    }
    yc[r] = acc;
  }
  __syncthreads();
  int i = threadIdx.x >> 3, seg = threadIdx.x & 7;
  const float* Xi = X + ((size_t)b*NM + i)*NN + seg*128;
  const float* ys = yc + seg*128;
  double s = 0.0;
  for (int k=0;k<128;k++) s += (double)Xi[k]*(double)ys[k];
  pd[i][seg] = s;
  __syncthreads();
  if (threadIdx.x < NM){
    double g = 0.0;
    #pragma unroll
    for (int q=0;q<8;q++) g += pd[threadIdx.x][q];
    double contrib = (threadIdx.x==j)? g : fabs(g);
    #pragma unroll
    for (int off=16; off>0; off>>=1) contrib += __shfl_down(contrib, off, 32);
    if (threadIdx.x == 0){
      float av = (float)contrib*1.02f + 1e-4f;
      av = fminf(fmaxf(av, 0.02f), 1.5f);
      atomicMax((unsigned int*)&aint[b], __float_as_uint(av));
    }
  }
}

// ---------------- fused spmv + Gram row write (final RR) ---------------------
__global__ __launch_bounds__(256) void k_spmv_gram(const int* __restrict__ cnt,
                        const unsigned short* __restrict__ ecolT,
                        const float* __restrict__ evalT, const float* __restrict__ dval,
                        const float* __restrict__ X, double* __restrict__ G){
  __shared__ float xc[NN];
  __shared__ float yc[NN];
  __shared__ double pd[NM][8];
  int b = blockIdx.x & 7, j = blockIdx.x >> 3;
  const float* Xc = X + ((size_t)b*NM + j)*NN;
  for (int n=threadIdx.x; n<NN; n+=256) xc[n] = Xc[n];
  __syncthreads();
  int rowbase = b << 10;
  for (int r=threadIdx.x; r<NN; r+=256){
    int c = cnt[rowbase+r]; if (c > WE) c = WE;
    float acc = dval[rowbase+r]*xc[r];
    const unsigned short* pe = ecolT + rowbase + r;
    const float* pv = evalT + rowbase + r;
    for (int jj=0;jj<c;jj++){
      acc -= pv[0]*xc[pe[0]];
      pe += GNN; pv += GNN;
    }
    yc[r] = acc;
  }
  __syncthreads();
  int i = threadIdx.x >> 3, seg = threadIdx.x & 7;
  const float* Xi = X + ((size_t)b*NM + i)*NN + seg*128;
  const float* ys = yc + seg*128;
  double s = 0.0;
  for (int k=0;k<128;k++) s += (double)Xi[k]*(double)ys[k];
  pd[i][seg] = s;
  __syncthreads();
  if (threadIdx.x < NM){
    double g = 0.0;
    #pragma unroll
    for (int q=0;q<8;q++) g += pd[threadIdx.x][q];
    G[((size_t)b*NM + j)*NM + threadIdx.x] = g;   // G[j][i]; jacobi symmetrizes
  }
}

// ---------------- fused 32x32 Jacobi + sorted rotation apply -----------------
__global__ __launch_bounds__(256) void k_jacobi_apply(const double* __restrict__ Gd,
                        const float* __restrict__ Xin, float* __restrict__ Xout, int sweeps){
  __shared__ float S[NM][NM];
  __shared__ float V[NM][NM];
  __shared__ float Vp[NM][NM];
  __shared__ float cs_[16], sn_[16];
  __shared__ int pp_[16], qq_[16];
  __shared__ int perm[NM];
  int b = blockIdx.x, l = threadIdx.x;
  for (int idx=l; idx<NM*NM; idx+=256){
    int i = idx>>5, j = idx&31;
    S[i][j] = (float)(0.5*(Gd[(size_t)b*NM*NM + i*NM + j] + Gd[(size_t)b*NM*NM + j*NM + i]));
    V[i][j] = (i==j)? 1.0f : 0.0f;
  }
  __syncthreads();
  for (int sw=0; sw<sweeps; sw++){
    for (int r=0; r<31; r++){
      if (l < 16){
        int p, q;
        if (l == 0){ p = r; q = 31; }
        else { p = (r + l) % 31; q = (r + 31 - l) % 31; }
        if (p > q){ int t_=p; p=q; q=t_; }
        float apq = S[p][q];
        float c = 1.0f, s = 0.0f;
        if (fabsf(apq) > 1e-30f){
          float tau = (S[q][q] - S[p][p]) / (2.0f*apq);
          float tt = (tau >= 0.f ? 1.0f : -1.0f) / (fabsf(tau) + sqrtf(1.0f + tau*tau));
          c = 1.0f/sqrtf(1.0f + tt*tt); s = tt*c;
        }
        cs_[l]=c; sn_[l]=s; pp_[l]=p; qq_[l]=q;
      }
      __syncthreads();
      for (int tsk=l; tsk<512; tsk+=256){
        int i = tsk >> 4, kk = tsk & 15;
        int p = pp_[kk], q = qq_[kk];
        float c = cs_[kk], s = sn_[kk];
        float sp = S[i][p], sq = S[i][q];
        S[i][p] = c*sp - s*sq; S[i][q] = s*sp + c*sq;
        float vp = V[i][p], vq = V[i][q];
        V[i][p] = c*vp - s*vq; V[i][q] = s*vp + c*vq;
      }
      __syncthreads();
      for (int tsk=l; tsk<512; tsk+=256){
        int jc = tsk >> 4, kk = tsk & 15;
        int p = pp_[kk], q = qq_[kk];
        float c = cs_[kk], s = sn_[kk];
        float sp = S[p][jc], sq = S[q][jc];
        S[p][jc] = c*sp - s*sq; S[q][jc] = s*sp + c*sq;
      }
      __syncthreads();
    }
  }
  // parallel rank sort of diag(S) ascending (tie-break by index, matches old)
  if (l < NM){
    float v = S[l][l];
    int rank = 0;
    #pragma unroll
    for (int i=0;i<NM;i++){
      float vi = S[i][i];
      rank += (vi < v || (vi == v && i < l)) ? 1 : 0;
    }
    perm[rank] = l;
  }
  __syncthreads();
  for (int idx=l; idx<NM*NM; idx+=256){
    int i = idx>>5, j = idx&31;
    Vp[i][j] = V[i][perm[j]];
  }
  __syncthreads();
  for (int nl=l; nl<NN; nl+=256){
    float xv[NM];
    #pragma unroll
    for (int j=0;j<NM;j++) xv[j] = Xin[((size_t)b*NM + j)*NN + nl];
    #pragma unroll
    for (int jn=0;jn<NM;jn++){
      float acc = 0.f;
      #pragma unroll
      for (int j=0;j<NM;j++) acc += xv[j]*Vp[j][jn];
      Xout[((size_t)b*NM + jn)*NN + nl] = acc;
    }
  }
}

// ---------------- xs[b][k][tc] = sum_n X[b][k][n] * h[b][n][tc] --------------
__global__ __launch_bounds__(256) void k_project(const float* __restrict__ X, const float* __restrict__ h,
                          float* __restrict__ xs){
  __shared__ float Xs[NK][NN];             // 64KB
  __shared__ float red[PSEG][NK][PTC+1];   // ~17KB
  int b = blockIdx.x & 7;
  int chunk = blockIdx.x >> 3;             // 0..39
  int tc0 = chunk * PTC;
  for (int idx=threadIdx.x; idx<NK*NN; idx+=256){
    int k = idx >> 10, n = idx & (NN-1);
    Xs[k][n] = X[((size_t)b*NM + k)*NN + n];
  }
  __syncthreads();
  int tcl = threadIdx.x & (PTC-1);
  int seg = threadIdx.x >> 4;              // 0..15
  const float* hb = h + (size_t)b*NN*NT*NC + tc0 + tcl;
  float acc[NK];
  #pragma unroll
  for (int k=0;k<NK;k++) acc[k]=0.f;
  int n0 = seg*(NN/PSEG);
  for (int n=n0; n<n0+(NN/PSEG); n++){
    float v = hb[(size_t)n*NT*NC];
    #pragma unroll
    for (int k=0;k<NK;k++) acc[k] += Xs[k][n]*v;
  }
  #pragma unroll
  for (int k=0;k<NK;k++) red[seg][k][tcl] = acc[k];
  __syncthreads();
  int k = threadIdx.x >> 4;
  int t2 = threadIdx.x & (PTC-1);
  float s = 0.f;
  #pragma unroll
  for (int q=0;q<PSEG;q++) s += red[q][k][t2];
  xs[((size_t)b*NK + k)*NT*NC + tc0 + t2] = s;
}

// ---------------- rfft(:4) -> complex channel mix -> irfft -------------------
__global__ __launch_bounds__(64) void k_timefilter(const float* __restrict__ xs, const float* __restrict__ fwr,
                             const float* __restrict__ fwi, float* __restrict__ osb, int layer){
  __shared__ float xst[NT*NC];
  __shared__ float xfr[NC][NMT];
  __shared__ float xfi[NC][NMT];
  int b = blockIdx.x >> 4, k = blockIdx.x & 15;
  const float* xin = xs + ((size_t)b*NK + k)*NT*NC;
  for (int idx=threadIdx.x; idx<NT*NC; idx+=64) xst[idx] = xin[idx];
  __syncthreads();
  int l = threadIdx.x;
  if (l < NC){
    float ar0=0,ar1=0,ar2=0,ar3=0, ai1=0,ai2=0,ai3=0;
    for (int t=0;t<NT;t++){
      float v = xst[t*NC + l];
      float w1 = 0.31415926535897932f * (float)t;  // 2*pi*t/20
      ar0 += v;
      ar1 += v*cosf(w1);       ai1 -= v*sinf(w1);
      ar2 += v*cosf(2.f*w1);   ai2 -= v*sinf(2.f*w1);
      ar3 += v*cosf(3.f*w1);   ai3 -= v*sinf(3.f*w1);
    }
    xfr[l][0]=ar0; xfi[l][0]=0.f;
    xfr[l][1]=ar1; xfi[l][1]=ai1;
    xfr[l][2]=ar2; xfi[l][2]=ai2;
    xfr[l][3]=ar3; xfi[l][3]=ai3;
  }
  __syncthreads();
  if (l < NC){
    int o = l;
    float ofr[NMT], ofi[NMT];
    #pragma unroll
    for (int f=0; f<NMT; f++){ ofr[f]=0.f; ofi[f]=0.f; }
    for (int i=0;i<NC;i++){
      size_t wbase = ((((size_t)layer*NC + i)*NC + o)*NK + k)*NMT;
      #pragma unroll
      for (int f=0; f<NMT; f++){
        float wr = fwr[wbase+f], wi2 = fwi[wbase+f];
        float xr = xfr[i][f], xi = xfi[i][f];
        ofr[f] += xr*wr - xi*wi2;
        ofi[f] += xr*wi2 + xi*wr;
      }
    }
    float* outp = osb + ((size_t)b*NK + k)*NT*NC;
    for (int t=0;t<NT;t++){
      float w1 = 0.31415926535897932f * (float)t;
      float acc = ofr[0];
      acc += 2.f*(ofr[1]*cosf(w1)     - ofi[1]*sinf(w1));
      acc += 2.f*(ofr[2]*cosf(2.f*w1) - ofi[2]*sinf(2.f*w1));
      acc += 2.f*(ofr[3]*cosf(3.f*w1) - ofi[3]*sinf(3.f*w1));
      outp[t*NC + o] = acc * 0.05f;
    }
  }
}

// ---------------- h' = basis*os + cw*h + cb, gelu (layers 0..2) --------------
__global__ __launch_bounds__(256) void k_update(const float* __restrict__ X, const float* __restrict__ osb,
                         const float* __restrict__ h, const float* __restrict__ cw,
                         const float* __restrict__ cb, float* __restrict__ hout, int layer){
  __shared__ float os_s[NK*NT*NC];   // 40KB
  __shared__ float cwT[NC*NC];
  __shared__ float Xl[NK][32];
  __shared__ float cbs[NC];
  int b = blockIdx.x & 7;
  int n0 = (blockIdx.x >> 3)*32;
  for (int idx=threadIdx.x; idx<NK*NT*NC; idx+=256) os_s[idx] = osb[(size_t)b*NK*NT*NC + idx];
  for (int idx=threadIdx.x; idx<NC*NC; idx+=256){
    int o = idx/NC, i = idx%NC;
    cwT[i*NC + o] = cw[((size_t)layer*NC + o)*NC + i];
  }
  if (threadIdx.x < NC) cbs[threadIdx.x] = cb[layer*NC + threadIdx.x];
  for (int idx=threadIdx.x; idx<NK*32; idx+=256){
    int k = idx >> 5, nl = idx & 31;
    Xl[k][nl] = X[((size_t)b*NM + k)*NN + n0 + nl];
  }
  __syncthreads();
  for (int tsk=threadIdx.x; tsk<32*NT; tsk+=256){
    int t = tsk % NT, nl = tsk / NT;
    int n = n0 + nl;
    const float* hr = h + (((size_t)b*NN + n)*NT + t)*NC;
    float acc[NC];
    #pragma unroll
    for (int o=0;o<NC;o++) acc[o] = cbs[o];
    #pragma unroll
    for (int k=0;k<NK;k++){
      float xv = Xl[k][nl];
      const float* osr = os_s + (k*NT + t)*NC;
      #pragma unroll
      for (int o=0;o<NC;o++) acc[o] += xv*osr[o];
    }
    for (int i=0;i<NC;i++){
      float hv = hr[i];
      const float* cwr = cwT + i*NC;
      #pragma unroll
      for (int o=0;o<NC;o++) acc[o] += hv*cwr[o];
    }
    float* outp = hout + (((size_t)b*NN + n)*NT + t)*NC;
    if (layer < 3){
      #pragma unroll
      for (int o=0;o<NC;o++) outp[o] = gelu_f(acc[o]);
    } else {
      #pragma unroll
      for (int o=0;o<NC;o++) outp[o] = acc[o];
    }
  }
}

// ---------------- head: gelu(h@q1w+q1b)@q2w + q2b ----------------------------
__global__ __launch_bounds__(256) void k_head(const float* __restrict__ h, const float* __restrict__ q1w,
                       const float* __restrict__ q1b, const float* __restrict__ q2w,
                       const float* __restrict__ q2b, float* __restrict__ out){
  __shared__ float w1[NC*NQ];
  __shared__ float b1[NQ], w2[NQ];
  for (int idx=threadIdx.x; idx<NC*NQ; idx+=256) w1[idx] = q1w[idx];
  if (threadIdx.x < NQ){ b1[threadIdx.x] = q1b[threadIdx.x]; w2[threadIdx.x] = q2w[threadIdx.x]; }
  __syncthreads();
  int idx = blockIdx.x*256 + threadIdx.x;
  if (idx >= NB*NN*NT) return;
  const float* hr = h + (size_t)idx*NC;
  float hv[NC];
  #pragma unroll
  for (int i=0;i<NC;i++) hv[i] = hr[i];
  float res = q2b[0];
  for (int j=0;j<NQ;j++){
    float z = b1[j];
    #pragma unroll
    for (int i=0;i<NC;i++) z += hv[i]*w1[i*NQ + j];
    res += gelu_f(z)*w2[j];
  }
  out[idx] = res;
}

// ============================================================================
extern "C" void kernel_launch(void* const* d_in, const int* in_sizes, int n_in,
                              void* d_out, int out_size, void* d_ws, size_t ws_size,
                              hipStream_t stream){
  (void)in_sizes; (void)n_in; (void)out_size;
  const float* x   = (const float*)d_in[0];
  const float* pos = (const float*)d_in[1];
  const float* Wp  = (const float*)d_in[2];
  const float* bp  = (const float*)d_in[3];
  const float* fwr = (const float*)d_in[4];
  const float* fwi = (const float*)d_in[5];
  const float* cw  = (const float*)d_in[6];
  const float* cb  = (const float*)d_in[7];
  const float* q1w = (const float*)d_in[8];
  const float* q1b = (const float*)d_in[9];
  const float* q2w = (const float*)d_in[10];
  const float* q2b = (const float*)d_in[11];

  char* p = (char*)d_ws;
  auto take = [&](size_t bytes)->void*{
    void* r = (void*)p;
    p += (bytes + 255) & ~(size_t)255;
    return r;
  };
  float*  hA    = (float*) take(sizeof(float)*NB*NN*NT*NC);
  float*  hB    = (float*) take(sizeof(float)*NB*NN*NT*NC);
  float*  knnd  = (float*) take(sizeof(float)*NB*NN*8);
  int*    knni  = (int*)   take(sizeof(int)*NB*NN*8);
  double* sig   = (double*)take(sizeof(double)*NB);
  int*    cntb  = (int*)   take(sizeof(int)*NB*NN);
  unsigned short* ecolT = (unsigned short*) take(sizeof(unsigned short)*(size_t)GNN*WE);
  float*  evalT = (float*) take(sizeof(float)*(size_t)GNN*WE);
  float*  deg   = (float*) take(sizeof(float)*NB*NN);
  float*  dinv  = (float*) take(sizeof(float)*NB*NN);
  float*  dval  = (float*) take(sizeof(float)*NB*NN);
  float*  Xb    = (float*) take(sizeof(float)*NB*NM*NN);
  float*  Yb    = (float*) take(sizeof(float)*NB*NM*NN);
  double* Gd    = (double*)take(sizeof(double)*NB*NM*NM);
  float*  aint  = (float*) take(sizeof(float)*NB);
  float*  xs    = (float*) take(sizeof(float)*NB*NK*NT*NC);
  float*  osb   = (float*) take(sizeof(float)*NB*NK*NT*NC);
  if ((size_t)(p - (char*)d_ws) > ws_size) return;  // ws too small -> loud failure

  k_build_h0<<<(NB*NN*NT*NC+255)/256, 256, 0, stream>>>(x, pos, Wp, bp, hA);

  float* hcur = hA; float* hnext = hB;
  for (int layer=0; layer<4; layer++){
    hipMemsetAsync(sig, 0, sizeof(double)*NB, stream);
    k_dist_knn<<<NB*NN/8, 512, 0, stream>>>(hcur, knnd, knni, sig, cntb);
    k_build_ell<<<NB*NN/256, 256, 0, stream>>>(knnd, knni, sig, cntb, ecolT, evalT);
    k_degnorm<<<NB*NN/256, 256, 0, stream>>>(cntb, evalT, deg, dinv);
    k_normell<<<NB*NN/256, 256, 0, stream>>>(cntb, ecolT, evalT, deg, dinv, dval);
    k_initX<<<NB*NM*NN/256, 256, 0, stream>>>(deg, Xb, aint);
    float* cur = Xb; float* oth = Yb;
    // round 0: deg 24 on [1.0, 2.0005], then QR + interval estimate
    k_cheb<<<NB*NM, 512, 0, stream>>>(cntb, ecolT, evalT, dval, cur, aint, 24);
    k_gram<<<NB*NM, 256, 0, stream>>>(cur, cur, Gd);
    k_cholapply<<<NB*4, 256, 0, stream>>>(Gd, cur, oth, aint, 1);
    { float* t_ = cur; cur = oth; oth = t_; }
    k_spmv_gersh<<<NB*NM, 256, 0, stream>>>(cntb, ecolT, evalT, dval, cur, aint);
    // round 1: deg 32 on adapted interval, then QR
    k_cheb<<<NB*NM, 512, 0, stream>>>(cntb, ecolT, evalT, dval, cur, aint, 32);
    k_gram<<<NB*NM, 256, 0, stream>>>(cur, cur, Gd);
    k_cholapply<<<NB*4, 256, 0, stream>>>(Gd, cur, oth, aint, 0);
    { float* t_ = cur; cur = oth; oth = t_; }
    // final Rayleigh-Ritz: G = X^T L X (fused), Jacobi (1 sweep), apply
    k_spmv_gram<<<NB*NM, 256, 0, stream>>>(cntb, ecolT, evalT, dval, cur, Gd);
    k_jacobi_apply<<<NB, 256, 0, stream>>>(Gd, cur, oth, 1);
    { float* t_ = cur; cur = oth; oth = t_; }

    k_project<<<NB*40, 256, 0, stream>>>(cur, hcur, xs);
    k_timefilter<<<NB*NK, 64, 0, stream>>>(xs, fwr, fwi, osb, layer);
    k_update<<<NB*32, 256, 0, stream>>>(cur, osb, hcur, cw, cb, hnext, layer);
    { float* t_ = hcur; hcur = hnext; hnext = t_; }
  }
  k_head<<<(NB*NN*NT+255)/256, 256, 0, stream>>>(hcur, q1w, q1b, q2w, q2b, (float*)d_out);
}

// Round 9
// 3044.801 us; speedup vs baseline: 5.1645x; 1.0573x over previous
//
#include <hip/hip_runtime.h>

#define NB 8
#define NN 1024
#define NC 32
#define NT 20
#define NTI 10
#define NM 32     // iteration block size (16 wanted + 16 guard)
#define NK 16     // K_SPACE
#define NMT 4     // M_TIME
#define WE 64     // ELL width (max entries per row)
#define NQ 128
#define GNN (NB*NN)
#define RSL 24    // edge slots held in registers in k_cheb
#define PTC 16    // tc per block in k_project
#define PSEG 16   // n-segments in k_project

__device__ __forceinline__ float gelu_f(float x){
  return 0.5f * x * (1.0f + erff(x * 0.70710678118654752f));
}
__device__ __forceinline__ unsigned wanghash(unsigned s){
  s = (s ^ 61u) ^ (s >> 16); s *= 9u; s ^= s >> 4; s *= 0x27d4eb2du; s ^= s >> 15;
  return s;
}

// ---------------- initial lift; also writes channel-major feat[b][c][n] ------
__global__ void k_build_h0(const float* __restrict__ x, const float* __restrict__ pos,
                           const float* __restrict__ Wp, const float* __restrict__ bp,
                           float* __restrict__ h, float* __restrict__ feat){
  int idx = blockIdx.x*256 + threadIdx.x;
  if (idx >= NB*NN*NT*NC) return;
  int c = idx & (NC-1);
  int t = (idx/NC) % NT;
  int n = (idx/(NC*NT)) & (NN-1);
  int b = idx/(NC*NT*NN);
  const float* xr = x + (b*NN + n)*NTI;
  float acc = bp[c];
  #pragma unroll
  for (int i=0;i<NTI;i++) acc += xr[i]*Wp[i*NC+c];
  acc += pos[(b*NN+n)*2+0]*Wp[10*NC+c];
  acc += pos[(b*NN+n)*2+1]*Wp[11*NC+c];
  float tv = (float)(10+t) * (1.0f/29.0f);
  acc += tv*Wp[12*NC+c];
  h[idx] = acc;
  if (t == 0) feat[(((size_t)b*NC + c)<<10) + n] = acc;
}

// ---------------- fused pairwise distance + top-8 kNN + sigma sum ------------
// one wave per row, 4 rows/block; candidates read from channel-major feat
// (coalesced 256B/wave per channel); query row broadcast from LDS.
// Per-lane visit order and FP order identical to prior rounds.
__global__ __launch_bounds__(256) void k_dist_knn(const float* __restrict__ h,
                           const float* __restrict__ feat,
                           float* __restrict__ knnd, int* __restrict__ knni,
                           double* __restrict__ sig, int* __restrict__ cnt){
  __shared__ float fr_s[4][NC];
  int wave = threadIdx.x >> 6;
  int lane = threadIdx.x & 63;
  int b  = blockIdx.x & 7;             // XCD-affine batch
  int rg = blockIdx.x >> 3;            // 0..255
  int row = (b<<10) + rg*4 + wave;
  if (threadIdx.x < 4*NC){
    int w = threadIdx.x >> 5, c = threadIdx.x & 31;
    int rr = (b<<10) + rg*4 + w;
    fr_s[w][c] = h[((size_t)rr*NT)*NC + c];
  }
  __syncthreads();
  float d8[8]; int i8[8];
  #pragma unroll
  for (int j=0;j<8;j++){ d8[j]=1e30f; i8[j]=0x3fffffff; }
  double ssum = 0.0;
  const float* fc_b = feat + (((size_t)b*NC)<<10);
  for (int tile=0; tile<8; tile++){
    int m = tile*128 + lane;
    float d2a = 0.f, d2b = 0.f;
    #pragma unroll 8
    for (int c=0;c<NC;c++){
      float fc = fr_s[wave][c];
      const float* fp = fc_b + ((size_t)c<<10) + m;
      float dfa = fc - fp[0];
      float dfb = fc - fp[64];
      d2a += dfa*dfa; d2b += dfb*dfb;
    }
    float da = sqrtf(d2a);
    ssum += (double)da;
    if (da < d8[7] || (da == d8[7] && m < i8[7])){
      d8[7] = da; i8[7] = m;
      #pragma unroll
      for (int j=6;j>=0;j--){
        bool sw = (d8[j+1] < d8[j]) || (d8[j+1]==d8[j] && i8[j+1]<i8[j]);
        if (sw){ float td=d8[j]; d8[j]=d8[j+1]; d8[j+1]=td;
                 int ti=i8[j]; i8[j]=i8[j+1]; i8[j+1]=ti; }
      }
    }
    int m2 = m + 64;
    float db = sqrtf(d2b);
    ssum += (double)db;
    if (db < d8[7] || (db == d8[7] && m2 < i8[7])){
      d8[7] = db; i8[7] = m2;
      #pragma unroll
      for (int j=6;j>=0;j--){
        bool sw = (d8[j+1] < d8[j]) || (d8[j+1]==d8[j] && i8[j+1]<i8[j]);
        if (sw){ float td=d8[j]; d8[j]=d8[j+1]; d8[j+1]=td;
                 int ti=i8[j]; i8[j]=i8[j+1]; i8[j+1]=ti; }
      }
    }
  }
  #pragma unroll
  for (int off=32; off>0; off>>=1) ssum += __shfl_down(ssum, off);
  if (lane==0){ atomicAdd(&sig[b], ssum); cnt[row] = 8; }
  // merge per-lane sorted top-8 lists: 8x wave-argmin extraction
  int ptr = 0;
  for (int sel=0; sel<8; sel++){
    float dv = 1e30f; int iv = 0x3fffffff;
    #pragma unroll
    for (int j=0;j<8;j++) if (j==ptr){ dv=d8[j]; iv=i8[j]; }
    float bd = dv; int bi = iv;
    #pragma unroll
    for (int off=32; off>0; off>>=1){
      float od = __shfl_xor(bd, off);
      int oi = __shfl_xor(bi, off);
      if (od < bd || (od == bd && oi < bi)){ bd = od; bi = oi; }
    }
    if (dv == bd && iv == bi) ptr++;
    if (lane == sel){ knnd[row*8+sel] = bd; knni[row*8+sel] = bi; }
  }
}

// ---------------- symmetrized sparse A in transposed ELL form ----------------
__global__ void k_build_ell(const float* __restrict__ knnd, const int* __restrict__ knni,
                            const double* __restrict__ sig, int* __restrict__ cnt,
                            unsigned short* __restrict__ ecolT, float* __restrict__ evalT){
  int row = blockIdx.x*256 + threadIdx.x;
  if (row >= NB*NN) return;
  int b = row >> 10;
  float sigma = (float)(sig[b] * (1.0/((double)NN*(double)NN)));
  float s2 = sigma*sigma;
  int rloc = row & (NN-1);
  #pragma unroll
  for (int j=0;j<8;j++){
    float d = knnd[row*8+j];
    int m = knni[row*8+j];
    float v = 0.5f * expf(-d/s2);
    ecolT[(size_t)j*GNN + row] = (unsigned short)m;
    evalT[(size_t)j*GNN + row] = v;
    int grow = (b<<10) + m;
    int p = atomicAdd(&cnt[grow], 1);
    if (p < WE){ ecolT[(size_t)p*GNN + grow] = (unsigned short)rloc;
                 evalT[(size_t)p*GNN + grow] = v; }
  }
}

__global__ void k_degnorm(const int* __restrict__ cnt, const float* __restrict__ evalT,
                          float* __restrict__ deg, float* __restrict__ dinv){
  int row = blockIdx.x*256 + threadIdx.x;
  if (row >= NB*NN) return;
  int c = cnt[row]; if (c > WE) c = WE;
  float s = 0.f;
  for (int j=0;j<c;j++) s += evalT[(size_t)j*GNN + row];
  deg[row] = s;
  dinv[row] = 1.0f/sqrtf(s + 1e-6f);
}

__global__ void k_normell(const int* __restrict__ cnt, const unsigned short* __restrict__ ecolT,
                          float* __restrict__ evalT, const float* __restrict__ deg,
                          const float* __restrict__ dinv, float* __restrict__ dval){
  int row = blockIdx.x*256 + threadIdx.x;
  if (row >= NB*NN) return;
  int b = row >> 10;
  const float* dv = dinv + (b<<10);
  float di = dinv[row];
  int c = cnt[row]; if (c > WE) c = WE;
  for (int j=0;j<c;j++){
    int col = ecolT[(size_t)j*GNN + row];
    evalT[(size_t)j*GNN + row] = evalT[(size_t)j*GNN + row] * (di * dv[col]);
  }
  dval[row] = di*di*deg[row];
}

// ---------------- eigensolver: init block -----------------------------------
__global__ void k_initX(const float* __restrict__ deg, float* __restrict__ X, float* __restrict__ aint){
  int idx = blockIdx.x*256+threadIdx.x;
  if (idx >= NB*NM*NN) return;
  int n = idx & (NN-1);
  int j = (idx >> 10) & (NM-1);
  int b = idx >> 15;
  float v;
  if (j == 0) v = sqrtf(deg[(b<<10)+n] + 1e-6f);   // exact 0-eigenvector of Lhat
  else {
    unsigned hsh = wanghash((unsigned)idx * 2654435761u + 12345u);
    v = ((hsh >> 8) * (1.0f/16777216.0f)) - 0.5f;
  }
  X[idx] = v;
  if (n == 0 && j == 1) aint[b] = 1.0f;
}

// ---------------- Chebyshev filter, one column per block, edges in regs ------
__global__ __launch_bounds__(512) void k_cheb(const int* __restrict__ cnt,
                        const unsigned short* __restrict__ ecolT,
                        const float* __restrict__ evalT, const float* __restrict__ dval,
                        float* __restrict__ X, const float* __restrict__ aint, int ndeg){
  __shared__ float bufA[NN];
  __shared__ float bufB[NN];
  int b = blockIdx.x & 7;
  int col = blockIdx.x >> 3;
  float a = aint[b];
  const float bhi = 2.0005f;
  float e  = 0.5f*(bhi - a);
  float cc = 0.5f*(bhi + a);
  float inv_e = 1.0f/e;
  const int rowbase = b << 10;
  float* Xc = X + ((size_t)b*NM + col)*NN;
  for (int n=threadIdx.x; n<NN; n+=512) bufA[n] = Xc[n];
  int r0 = threadIdx.x, r1 = threadIdx.x + 512;
  int c0 = cnt[rowbase+r0]; if (c0 > WE) c0 = WE;
  int c1 = cnt[rowbase+r1]; if (c1 > WE) c1 = WE;
  float dv0 = dval[rowbase+r0];
  float dv1 = dval[rowbase+r1];
  float ev0[RSL], ev1[RSL];
  int   ic0[RSL], ic1[RSL];
  #pragma unroll
  for (int j=0;j<RSL;j++){
    ic0[j] = (j<c0)? (int)ecolT[(size_t)j*GNN + rowbase + r0] : 0;
    ev0[j] = (j<c0)? evalT[(size_t)j*GNN + rowbase + r0] : 0.f;
    ic1[j] = (j<c1)? (int)ecolT[(size_t)j*GNN + rowbase + r1] : 0;
    ev1[j] = (j<c1)? evalT[(size_t)j*GNN + rowbase + r1] : 0.f;
  }
  int e0 = c0 - RSL; if (e0 < 0) e0 = 0;
  int e1 = c1 - RSL; if (e1 < 0) e1 = 0;
  int emax = (e0 > e1)? e0 : e1;
  const unsigned short* pe0 = ecolT + (size_t)RSL*GNN + rowbase + r0;
  const unsigned short* pe1 = ecolT + (size_t)RSL*GNN + rowbase + r1;
  const float* pv0 = evalT + (size_t)RSL*GNN + rowbase + r0;
  const float* pv1 = evalT + (size_t)RSL*GNN + rowbase + r1;
  __syncthreads();
  float* cur = bufA; float* prv = bufB;
  for (int k=0;k<ndeg;k++){
    float f = (k==0)? inv_e : 2.0f*inv_e;
    float x0 = cur[r0], x1 = cur[r1];
    float acc0 = dv0*x0, acc1 = dv1*x1;
    #pragma unroll
    for (int j=0;j<RSL;j++){
      acc0 -= ev0[j]*cur[ic0[j]];
      acc1 -= ev1[j]*cur[ic1[j]];
    }
    for (int j=0;j<emax;j++){   // rare overflow rows
      if (j < e0) acc0 -= pv0[(size_t)j*GNN] * cur[pe0[(size_t)j*GNN]];
      if (j < e1) acc1 -= pv1[(size_t)j*GNN] * cur[pe1[(size_t)j*GNN]];
    }
    float n0 = f*(acc0 - cc*x0);
    float n1 = f*(acc1 - cc*x1);
    if (k > 0){ n0 -= prv[r0]; n1 -= prv[r1]; }
    prv[r0] = n0; prv[r1] = n1;
    float* t_ = cur; cur = prv; prv = t_;
    __syncthreads();
  }
  for (int n=threadIdx.x; n<NN; n+=512) Xc[n] = cur[n];
}

// ---------------- G = A^T B (f64 accumulate), one row of G per wg ------------
__global__ void k_gram(const float* __restrict__ A, const float* __restrict__ Bm,
                       double* __restrict__ G){
  __shared__ float ai[NN];
  __shared__ double pd[NM][8];
  int b = blockIdx.x & 7, i = blockIdx.x >> 3;
  const float* Ac = A + ((size_t)b*NM + i)*NN;
  for (int n=threadIdx.x; n<NN; n+=256) ai[n] = Ac[n];
  __syncthreads();
  int j = threadIdx.x & 31, seg = threadIdx.x >> 5;
  const float* Bc = Bm + ((size_t)b*NM + j)*NN + seg*128;
  const float* as = ai + seg*128;
  double s = 0.0;
  for (int n=0;n<128;n++) s += (double)as[n]*(double)Bc[n];
  pd[j][seg] = s;
  __syncthreads();
  if (threadIdx.x < NM){
    double t = 0.0;
    #pragma unroll
    for (int q=0;q<8;q++) t += pd[threadIdx.x][q];
    G[((size_t)b*NM + i)*NM + threadIdx.x] = t;
  }
}

// ---------------- fused chol(G)->R^{-1}->apply quarter of nodes --------------
__global__ __launch_bounds__(256) void k_cholapply(const double* __restrict__ G,
                        const float* __restrict__ Xin, float* __restrict__ Xout,
                        float* __restrict__ aint, int reset){
  __shared__ double L[NM][NM];
  __shared__ double Ri[NM][NM];
  int b = blockIdx.x >> 2;
  int quarter = blockIdx.x & 3;
  int tid = threadIdx.x;
  for (int idx=tid; idx<NM*NM; idx+=256) L[idx>>5][idx&31] = G[(size_t)b*NM*NM + idx];
  __syncthreads();
  for (int k=0;k<NM;k++){
    if (tid == 0){
      double orig = L[k][k];
      double s = orig;
      for (int p=0;p<k;p++) s -= L[k][p]*L[k][p];
      double floorv = orig*1e-15; if (floorv < 1e-30) floorv = 1e-30;
      if (s < floorv) s = floorv;
      L[k][k] = sqrt(s);
    }
    __syncthreads();
    if (tid > k && tid < NM){
      double s = L[tid][k];
      for (int p=0;p<k;p++) s -= L[tid][p]*L[k][p];
      L[tid][k] = s / L[k][k];
    }
    __syncthreads();
  }
  if (tid < NM){
    int j = tid;
    Ri[j][j] = 1.0 / L[j][j];
    for (int i=j-1;i>=0;i--){
      double s = 0.0;
      for (int k2=i+1;k2<=j;k2++) s += L[k2][i]*Ri[k2][j];
      Ri[i][j] = -s / L[i][i];
    }
  }
  __syncthreads();
  int n = quarter*256 + tid;
  float xv[NM];
  #pragma unroll
  for (int j=0;j<NM;j++) xv[j] = Xin[((size_t)b*NM + j)*NN + n];
  for (int jn=0;jn<NM;jn++){
    double acc = 0.0;
    for (int j=0;j<=jn;j++) acc += (double)xv[j] * Ri[j][jn];
    Xout[((size_t)b*NM + jn)*NN + n] = (float)acc;
  }
  if (reset && quarter==0 && tid==0) aint[b] = 0.02f;
}

// ---------------- fused spmv + Gram row + Gershgorin interval bound ----------
__global__ __launch_bounds__(256) void k_spmv_gersh(const int* __restrict__ cnt,
                        const unsigned short* __restrict__ ecolT,
                        const float* __restrict__ evalT, const float* __restrict__ dval,
                        const float* __restrict__ X, float* __restrict__ aint){
  __shared__ float xc[NN];
  __shared__ float yc[NN];
  __shared__ double pd[NM][8];
  int b = blockIdx.x & 7, j = blockIdx.x >> 3;
  const float* Xc = X + ((size_t)b*NM + j)*NN;
  for (int n=threadIdx.x; n<NN; n+=256) xc[n] = Xc[n];
  __syncthreads();
  int rowbase = b << 10;
  for (int r=threadIdx.x; r<NN; r+=256){
    int c = cnt[rowbase+r]; if (c > WE) c = WE;
    float acc = dval[rowbase+r]*xc[r];
    const unsigned short* pe = ecolT + rowbase + r;
    const float* pv = evalT + rowbase + r;
    for (int jj=0;jj<c;jj++){
      acc -= pv[0]*xc[pe[0]];
      pe += GNN; pv += GNN;
    }
    yc[r] = acc;
  }
  __syncthreads();
  int i = threadIdx.x >> 3, seg = threadIdx.x & 7;
  const float* Xi = X + ((size_t)b*NM + i)*NN + seg*128;
  const float* ys = yc + seg*128;
  double s = 0.0;
  for (int k=0;k<128;k++) s += (double)Xi[k]*(double)ys[k];
  pd[i][seg] = s;
  __syncthreads();
  if (threadIdx.x < NM){
    double g = 0.0;
    #pragma unroll
    for (int q=0;q<8;q++) g += pd[threadIdx.x][q];
    double contrib = (threadIdx.x==j)? g : fabs(g);
    #pragma unroll
    for (int off=16; off>0; off>>=1) contrib += __shfl_down(contrib, off, 32);
    if (threadIdx.x == 0){
      float av = (float)contrib*1.02f + 1e-4f;
      av = fminf(fmaxf(av, 0.02f), 1.5f);
      atomicMax((unsigned int*)&aint[b], __float_as_uint(av));
    }
  }
}

// ---------------- fused spmv + Gram row write (final RR) ---------------------
__global__ __launch_bounds__(256) void k_spmv_gram(const int* __restrict__ cnt,
                        const unsigned short* __restrict__ ecolT,
                        const float* __restrict__ evalT, const float* __restrict__ dval,
                        const float* __restrict__ X, double* __restrict__ G){
  __shared__ float xc[NN];
  __shared__ float yc[NN];
  __shared__ double pd[NM][8];
  int b = blockIdx.x & 7, j = blockIdx.x >> 3;
  const float* Xc = X + ((size_t)b*NM + j)*NN;
  for (int n=threadIdx.x; n<NN; n+=256) xc[n] = Xc[n];
  __syncthreads();
  int rowbase = b << 10;
  for (int r=threadIdx.x; r<NN; r+=256){
    int c = cnt[rowbase+r]; if (c > WE) c = WE;
    float acc = dval[rowbase+r]*xc[r];
    const unsigned short* pe = ecolT + rowbase + r;
    const float* pv = evalT + rowbase + r;
    for (int jj=0;jj<c;jj++){
      acc -= pv[0]*xc[pe[0]];
      pe += GNN; pv += GNN;
    }
    yc[r] = acc;
  }
  __syncthreads();
  int i = threadIdx.x >> 3, seg = threadIdx.x & 7;
  const float* Xi = X + ((size_t)b*NM + i)*NN + seg*128;
  const float* ys = yc + seg*128;
  double s = 0.0;
  for (int k=0;k<128;k++) s += (double)Xi[k]*(double)ys[k];
  pd[i][seg] = s;
  __syncthreads();
  if (threadIdx.x < NM){
    double g = 0.0;
    #pragma unroll
    for (int q=0;q<8;q++) g += pd[threadIdx.x][q];
    G[((size_t)b*NM + j)*NM + threadIdx.x] = g;   // G[j][i]; jacobi symmetrizes
  }
}

// ---------------- 32x32 Jacobi (rotations + rank sort), Vp out (f32) ---------
__global__ __launch_bounds__(256) void k_jacobi(const double* __restrict__ Gd,
                        float* __restrict__ Vpf, int sweeps){
  __shared__ float S[NM][NM];
  __shared__ float V[NM][NM];
  __shared__ float cs_[16], sn_[16];
  __shared__ int pp_[16], qq_[16];
  __shared__ int perm[NM];
  int b = blockIdx.x, l = threadIdx.x;
  for (int idx=l; idx<NM*NM; idx+=256){
    int i = idx>>5, j = idx&31;
    S[i][j] = (float)(0.5*(Gd[(size_t)b*NM*NM + i*NM + j] + Gd[(size_t)b*NM*NM + j*NM + i]));
    V[i][j] = (i==j)? 1.0f : 0.0f;
  }
  __syncthreads();
  for (int sw=0; sw<sweeps; sw++){
    for (int r=0; r<31; r++){
      if (l < 16){
        int p, q;
        if (l == 0){ p = r; q = 31; }
        else { p = (r + l) % 31; q = (r + 31 - l) % 31; }
        if (p > q){ int t_=p; p=q; q=t_; }
        float apq = S[p][q];
        float c = 1.0f, s = 0.0f;
        if (fabsf(apq) > 1e-30f){
          float tau = (S[q][q] - S[p][p]) / (2.0f*apq);
          float tt = (tau >= 0.f ? 1.0f : -1.0f) / (fabsf(tau) + sqrtf(1.0f + tau*tau));
          c = 1.0f/sqrtf(1.0f + tt*tt); s = tt*c;
        }
        cs_[l]=c; sn_[l]=s; pp_[l]=p; qq_[l]=q;
      }
      __syncthreads();
      for (int tsk=l; tsk<512; tsk+=256){
        int i = tsk >> 4, kk = tsk & 15;
        int p = pp_[kk], q = qq_[kk];
        float c = cs_[kk], s = sn_[kk];
        float sp = S[i][p], sq = S[i][q];
        S[i][p] = c*sp - s*sq; S[i][q] = s*sp + c*sq;
        float vp = V[i][p], vq = V[i][q];
        V[i][p] = c*vp - s*vq; V[i][q] = s*vp + c*vq;
      }
      __syncthreads();
      for (int tsk=l; tsk<512; tsk+=256){
        int jc = tsk >> 4, kk = tsk & 15;
        int p = pp_[kk], q = qq_[kk];
        float c = cs_[kk], s = sn_[kk];
        float sp = S[p][jc], sq = S[q][jc];
        S[p][jc] = c*sp - s*sq; S[q][jc] = s*sp + c*sq;
      }
      __syncthreads();
    }
  }
  // parallel rank sort of diag(S) ascending (tie-break by index)
  if (l < NM){
    float v = S[l][l];
    int rank = 0;
    #pragma unroll
    for (int i=0;i<NM;i++){
      float vi = S[i][i];
      rank += (vi < v || (vi == v && i < l)) ? 1 : 0;
    }
    perm[rank] = l;
  }
  __syncthreads();
  for (int idx=l; idx<NM*NM; idx+=256){
    int i = idx>>5, j = idx&31;
    Vpf[(size_t)b*NM*NM + i*NM + j] = V[i][perm[j]];
  }
}

// ---------------- Xout = Xin * Vp (f32), quarter of nodes per block ----------
__global__ __launch_bounds__(256) void k_applyVf(const float* __restrict__ Xin,
                        const float* __restrict__ Vpf, float* __restrict__ Xout){
  __shared__ float Ms[NM*NM];
  int b = blockIdx.x >> 2;
  int n = (blockIdx.x & 3)*256 + threadIdx.x;
  for (int idx=threadIdx.x; idx<NM*NM; idx+=256) Ms[idx] = Vpf[(size_t)b*NM*NM + idx];
  __syncthreads();
  float xv[NM];
  #pragma unroll
  for (int j=0;j<NM;j++) xv[j] = Xin[((size_t)b*NM + j)*NN + n];
  #pragma unroll
  for (int jn=0;jn<NM;jn++){
    float acc = 0.f;
    #pragma unroll
    for (int j=0;j<NM;j++) acc += xv[j]*Ms[j*NM + jn];
    Xout[((size_t)b*NM + jn)*NN + n] = acc;
  }
}

// ---------------- xs[b][k][tc] = sum_n X[b][k][n] * h[b][n][tc] --------------
__global__ __launch_bounds__(256) void k_project(const float* __restrict__ X, const float* __restrict__ h,
                          float* __restrict__ xs){
  __shared__ float Xs[NK][NN];             // 64KB
  __shared__ float red[PSEG][NK][PTC+1];   // ~17KB
  int b = blockIdx.x & 7;
  int chunk = blockIdx.x >> 3;             // 0..39
  int tc0 = chunk * PTC;
  for (int idx=threadIdx.x; idx<NK*NN; idx+=256){
    int k = idx >> 10, n = idx & (NN-1);
    Xs[k][n] = X[((size_t)b*NM + k)*NN + n];
  }
  __syncthreads();
  int tcl = threadIdx.x & (PTC-1);
  int seg = threadIdx.x >> 4;              // 0..15
  const float* hb = h + (size_t)b*NN*NT*NC + tc0 + tcl;
  float acc[NK];
  #pragma unroll
  for (int k=0;k<NK;k++) acc[k]=0.f;
  int n0 = seg*(NN/PSEG);
  for (int n=n0; n<n0+(NN/PSEG); n++){
    float v = hb[(size_t)n*NT*NC];
    #pragma unroll
    for (int k=0;k<NK;k++) acc[k] += Xs[k][n]*v;
  }
  #pragma unroll
  for (int k=0;k<NK;k++) red[seg][k][tcl] = acc[k];
  __syncthreads();
  int k = threadIdx.x >> 4;
  int t2 = threadIdx.x & (PTC-1);
  float s = 0.f;
  #pragma unroll
  for (int q=0;q<PSEG;q++) s += red[q][k][t2];
  xs[((size_t)b*NK + k)*NT*NC + tc0 + t2] = s;
}

// ---------------- rfft(:4) -> complex channel mix -> irfft -------------------
__global__ __launch_bounds__(64) void k_timefilter(const float* __restrict__ xs, const float* __restrict__ fwr,
                             const float* __restrict__ fwi, float* __restrict__ osb, int layer){
  __shared__ float xst[NT*NC];
  __shared__ float xfr[NC][NMT];
  __shared__ float xfi[NC][NMT];
  int b = blockIdx.x >> 4, k = blockIdx.x & 15;
  const float* xin = xs + ((size_t)b*NK + k)*NT*NC;
  for (int idx=threadIdx.x; idx<NT*NC; idx+=64) xst[idx] = xin[idx];
  __syncthreads();
  int l = threadIdx.x;
  if (l < NC){
    float ar0=0,ar1=0,ar2=0,ar3=0, ai1=0,ai2=0,ai3=0;
    for (int t=0;t<NT;t++){
      float v = xst[t*NC + l];
      float w1 = 0.31415926535897932f * (float)t;  // 2*pi*t/20
      ar0 += v;
      ar1 += v*cosf(w1);       ai1 -= v*sinf(w1);
      ar2 += v*cosf(2.f*w1);   ai2 -= v*sinf(2.f*w1);
      ar3 += v*cosf(3.f*w1);   ai3 -= v*sinf(3.f*w1);
    }
    xfr[l][0]=ar0; xfi[l][0]=0.f;
    xfr[l][1]=ar1; xfi[l][1]=ai1;
    xfr[l][2]=ar2; xfi[l][2]=ai2;
    xfr[l][3]=ar3; xfi[l][3]=ai3;
  }
  __syncthreads();
  if (l < NC){
    int o = l;
    float ofr[NMT], ofi[NMT];
    #pragma unroll
    for (int f=0; f<NMT; f++){ ofr[f]=0.f; ofi[f]=0.f; }
    for (int i=0;i<NC;i++){
      size_t wbase = ((((size_t)layer*NC + i)*NC + o)*NK + k)*NMT;
      #pragma unroll
      for (int f=0; f<NMT; f++){
        float wr = fwr[wbase+f], wi2 = fwi[wbase+f];
        float xr = xfr[i][f], xi = xfi[i][f];
        ofr[f] += xr*wr - xi*wi2;
        ofi[f] += xr*wi2 + xi*wr;
      }
    }
    float* outp = osb + ((size_t)b*NK + k)*NT*NC;
    for (int t=0;t<NT;t++){
      float w1 = 0.31415926535897932f * (float)t;
      float acc = ofr[0];
      acc += 2.f*(ofr[1]*cosf(w1)     - ofi[1]*sinf(w1));
      acc += 2.f*(ofr[2]*cosf(2.f*w1) - ofi[2]*sinf(2.f*w1));
      acc += 2.f*(ofr[3]*cosf(3.f*w1) - ofi[3]*sinf(3.f*w1));
      outp[t*NC + o] = acc * 0.05f;
    }
  }
}

// ---------------- h' = basis*os + cw*h + cb, gelu; also writes feat ----------
__global__ __launch_bounds__(256) void k_update(const float* __restrict__ X, const float* __restrict__ osb,
                         const float* __restrict__ h, const float* __restrict__ cw,
                         const float* __restrict__ cb, float* __restrict__ hout,
                         float* __restrict__ feat, int layer){
  __shared__ float os_s[NK*NT*NC];   // 40KB
  __shared__ float cwT[NC*NC];
  __shared__ float Xl[NK][32];
  __shared__ float cbs[NC];
  int b = blockIdx.x & 7;
  int n0 = (blockIdx.x >> 3)*32;
  for (int idx=threadIdx.x; idx<NK*NT*NC; idx+=256) os_s[idx] = osb[(size_t)b*NK*NT*NC + idx];
  for (int idx=threadIdx.x; idx<NC*NC; idx+=256){
    int o = idx/NC, i = idx%NC;
    cwT[i*NC + o] = cw[((size_t)layer*NC + o)*NC + i];
  }
  if (threadIdx.x < NC) cbs[threadIdx.x] = cb[layer*NC + threadIdx.x];
  for (int idx=threadIdx.x; idx<NK*32; idx+=256){
    int k = idx >> 5, nl = idx & 31;
    Xl[k][nl] = X[((size_t)b*NM + k)*NN + n0 + nl];
  }
  __syncthreads();
  for (int tsk=threadIdx.x; tsk<32*NT; tsk+=256){
    int t = tsk % NT, nl = tsk / NT;
    int n = n0 + nl;
    const float* hr = h + (((size_t)b*NN + n)*NT + t)*NC;
    float acc[NC];
    #pragma unroll
    for (int o=0;o<NC;o++) acc[o] = cbs[o];
    #pragma unroll
    for (int k=0;k<NK;k++){
      float xv = Xl[k][nl];
      const float* osr = os_s + (k*NT + t)*NC;
      #pragma unroll
      for (int o=0;o<NC;o++) acc[o] += xv*osr[o];
    }
    for (int i=0;i<NC;i++){
      float hv = hr[i];
      const float* cwr = cwT + i*NC;
      #pragma unroll
      for (int o=0;o<NC;o++) acc[o] += hv*cwr[o];
    }
    float* outp = hout + (((size_t)b*NN + n)*NT + t)*NC;
    if (layer < 3){
      #pragma unroll
      for (int o=0;o<NC;o++){
        float v = gelu_f(acc[o]);
        outp[o] = v;
        if (t == 0) feat[(((size_t)b*NC + o)<<10) + n] = v;
      }
    } else {
      #pragma unroll
      for (int o=0;o<NC;o++){
        outp[o] = acc[o];
        if (t == 0) feat[(((size_t)b*NC + o)<<10) + n] = acc[o];
      }
    }
  }
}

// ---------------- head: gelu(h@q1w+q1b)@q2w + q2b ----------------------------
__global__ __launch_bounds__(256) void k_head(const float* __restrict__ h, const float* __restrict__ q1w,
                       const float* __restrict__ q1b, const float* __restrict__ q2w,
                       const float* __restrict__ q2b, float* __restrict__ out){
  __shared__ float w1[NC*NQ];
  __shared__ float b1[NQ], w2[NQ];
  for (int idx=threadIdx.x; idx<NC*NQ; idx+=256) w1[idx] = q1w[idx];
  if (threadIdx.x < NQ){ b1[threadIdx.x] = q1b[threadIdx.x]; w2[threadIdx.x] = q2w[threadIdx.x]; }
  __syncthreads();
  int idx = blockIdx.x*256 + threadIdx.x;
  if (idx >= NB*NN*NT) return;
  const float* hr = h + (size_t)idx*NC;
  float hv[NC];
  #pragma unroll
  for (int i=0;i<NC;i++) hv[i] = hr[i];
  float res = q2b[0];
  for (int j=0;j<NQ;j++){
    float z = b1[j];
    #pragma unroll
    for (int i=0;i<NC;i++) z += hv[i]*w1[i*NQ + j];
    res += gelu_f(z)*w2[j];
  }
  out[idx] = res;
}

// ============================================================================
extern "C" void kernel_launch(void* const* d_in, const int* in_sizes, int n_in,
                              void* d_out, int out_size, void* d_ws, size_t ws_size,
                              hipStream_t stream){
  (void)in_sizes; (void)n_in; (void)out_size;
  const float* x   = (const float*)d_in[0];
  const float* pos = (const float*)d_in[1];
  const float* Wp  = (const float*)d_in[2];
  const float* bp  = (const float*)d_in[3];
  const float* fwr = (const float*)d_in[4];
  const float* fwi = (const float*)d_in[5];
  const float* cw  = (const float*)d_in[6];
  const float* cb  = (const float*)d_in[7];
  const float* q1w = (const float*)d_in[8];
  const float* q1b = (const float*)d_in[9];
  const float* q2w = (const float*)d_in[10];
  const float* q2b = (const float*)d_in[11];

  char* p = (char*)d_ws;
  auto take = [&](size_t bytes)->void*{
    void* r = (void*)p;
    p += (bytes + 255) & ~(size_t)255;
    return r;
  };
  float*  hA    = (float*) take(sizeof(float)*NB*NN*NT*NC);
  float*  hB    = (float*) take(sizeof(float)*NB*NN*NT*NC);
  float*  featb = (float*) take(sizeof(float)*NB*NC*NN);
  float*  knnd  = (float*) take(sizeof(float)*NB*NN*8);
  int*    knni  = (int*)   take(sizeof(int)*NB*NN*8);
  double* sig   = (double*)take(sizeof(double)*NB);
  int*    cntb  = (int*)   take(sizeof(int)*NB*NN);
  unsigned short* ecolT = (unsigned short*) take(sizeof(unsigned short)*(size_t)GNN*WE);
  float*  evalT = (float*) take(sizeof(float)*(size_t)GNN*WE);
  float*  deg   = (float*) take(sizeof(float)*NB*NN);
  float*  dinv  = (float*) take(sizeof(float)*NB*NN);
  float*  dval  = (float*) take(sizeof(float)*NB*NN);
  float*  Xb    = (float*) take(sizeof(float)*NB*NM*NN);
  float*  Yb    = (float*) take(sizeof(float)*NB*NM*NN);
  double* Gd    = (double*)take(sizeof(double)*NB*NM*NM);
  float*  Vpf   = (float*) take(sizeof(float)*NB*NM*NM);
  float*  aint  = (float*) take(sizeof(float)*NB);
  float*  xs    = (float*) take(sizeof(float)*NB*NK*NT*NC);
  float*  osb   = (float*) take(sizeof(float)*NB*NK*NT*NC);
  if ((size_t)(p - (char*)d_ws) > ws_size) return;  // ws too small -> loud failure

  k_build_h0<<<(NB*NN*NT*NC+255)/256, 256, 0, stream>>>(x, pos, Wp, bp, hA, featb);

  float* hcur = hA; float* hnext = hB;
  for (int layer=0; layer<4; layer++){
    hipMemsetAsync(sig, 0, sizeof(double)*NB, stream);
    k_dist_knn<<<NB*NN/4, 256, 0, stream>>>(hcur, featb, knnd, knni, sig, cntb);
    k_build_ell<<<NB*NN/256, 256, 0, stream>>>(knnd, knni, sig, cntb, ecolT, evalT);
    k_degnorm<<<NB*NN/256, 256, 0, stream>>>(cntb, evalT, deg, dinv);
    k_normell<<<NB*NN/256, 256, 0, stream>>>(cntb, ecolT, evalT, deg, dinv, dval);
    k_initX<<<NB*NM*NN/256, 256, 0, stream>>>(deg, Xb, aint);
    float* cur = Xb; float* oth = Yb;
    // round 0: deg 24 on [1.0, 2.0005], then QR + interval estimate
    k_cheb<<<NB*NM, 512, 0, stream>>>(cntb, ecolT, evalT, dval, cur, aint, 24);
    k_gram<<<NB*NM, 256, 0, stream>>>(cur, cur, Gd);
    k_cholapply<<<NB*4, 256, 0, stream>>>(Gd, cur, oth, aint, 1);
    { float* t_ = cur; cur = oth; oth = t_; }
    k_spmv_gersh<<<NB*NM, 256, 0, stream>>>(cntb, ecolT, evalT, dval, cur, aint);
    // round 1: deg 32 on adapted interval, then QR
    k_cheb<<<NB*NM, 512, 0, stream>>>(cntb, ecolT, evalT, dval, cur, aint, 32);
    k_gram<<<NB*NM, 256, 0, stream>>>(cur, cur, Gd);
    k_cholapply<<<NB*4, 256, 0, stream>>>(Gd, cur, oth, aint, 0);
    { float* t_ = cur; cur = oth; oth = t_; }
    // final Rayleigh-Ritz: G = X^T L X (fused), Jacobi (1 sweep), apply
    k_spmv_gram<<<NB*NM, 256, 0, stream>>>(cntb, ecolT, evalT, dval, cur, Gd);
    k_jacobi<<<NB, 256, 0, stream>>>(Gd, Vpf, 1);
    k_applyVf<<<NB*4, 256, 0, stream>>>(cur, Vpf, oth);
    { float* t_ = cur; cur = oth; oth = t_; }

    k_project<<<NB*40, 256, 0, stream>>>(cur, hcur, xs);
    k_timefilter<<<NB*NK, 64, 0, stream>>>(xs, fwr, fwi, osb, layer);
    k_update<<<NB*32, 256, 0, stream>>>(cur, osb, hcur, cw, cb, hnext, featb, layer);
    { float* t_ = hcur; hcur = hnext; hnext = t_; }
  }
  k_head<<<(NB*NN*NT+255)/256, 256, 0, stream>>>(hcur, q1w, q1b, q2w, q2b, (float*)d_out);
}